// Round 1
// baseline (21579.819 us; speedup 1.0000x reference)
//
#include <hip/hip_runtime.h>
#include <stdint.h>

// ---------------- problem constants ----------------
constexpr int N_GRAPH = 100000;
constexpr int N_CANDS = 10;
constexpr int NT      = N_GRAPH + N_CANDS;   // 100010
constexpr int F_IN    = 128;
constexpr int NTYPES  = 10;
constexpr int NE      = 6400000;

// RNG variant: 0 = partitionable threefry, 32-bit = o0^o1 (JAX >= 0.5 default)
//              1 = partitionable, 32-bit = o1 (lo word)
//              2 = original (non-partitionable) iota pairing
#define RNG_VARIANT 0

// ---------------- threefry2x32 (matches jax._src.prng) ----------------
__device__ __forceinline__ void tf2x32(uint32_t k0, uint32_t k1, uint32_t x0, uint32_t x1,
                                       uint32_t& o0, uint32_t& o1) {
  const uint32_t ks2 = k0 ^ k1 ^ 0x1BD11BDAu;
  uint32_t v0 = x0 + k0, v1 = x1 + k1;
#define TFR(r) { v0 += v1; v1 = (v1 << (r)) | (v1 >> (32 - (r))); v1 ^= v0; }
  TFR(13) TFR(15) TFR(26) TFR(6)
  v0 += k1;  v1 += ks2 + 1u;
  TFR(17) TFR(29) TFR(16) TFR(24)
  v0 += ks2; v1 += k0 + 2u;
  TFR(13) TFR(15) TFR(26) TFR(6)
  v0 += k0;  v1 += k1 + 3u;
  TFR(17) TFR(29) TFR(16) TFR(24)
  v0 += k1;  v1 += ks2 + 4u;
  TFR(13) TFR(15) TFR(26) TFR(6)
  v0 += ks2; v1 += k0 + 5u;
#undef TFR
  o0 = v0; o1 = v1;
}

// keys from jax.random.split(jax.random.key(42))  (key data = [0, 42])
__device__ __forceinline__ void derive_keys(uint32_t& a0, uint32_t& a1,
                                            uint32_t& b0, uint32_t& b1) {
#if RNG_VARIANT == 2
  uint32_t c0, c1, d0, d1;
  tf2x32(0u, 42u, 0u, 2u, c0, c1);
  tf2x32(0u, 42u, 1u, 3u, d0, d1);
  a0 = c0; a1 = d0; b0 = c1; b1 = d1;
#else
  tf2x32(0u, 42u, 0u, 0u, a0, a1);
  tf2x32(0u, 42u, 0u, 1u, b0, b1);
#endif
}

__device__ __forceinline__ uint32_t rng_bits(uint32_t k0, uint32_t k1,
                                             uint32_t idx, uint32_t total) {
#if RNG_VARIANT == 0
  uint32_t o0, o1; tf2x32(k0, k1, 0u, idx, o0, o1); return o0 ^ o1;
#elif RNG_VARIANT == 1
  uint32_t o0, o1; tf2x32(k0, k1, 0u, idx, o0, o1); return o1;
#else
  uint32_t half = total >> 1; uint32_t o0, o1;
  if (idx < half) { tf2x32(k0, k1, idx, idx + half, o0, o1); return o0; }
  tf2x32(k0, k1, idx - half, idx, o0, o1); return o1;
#endif
}

// jax.random.uniform(minval=tiny,maxval=1) -> gumbel, computed in f64 from exact f32 uniform
__device__ __forceinline__ double gumbel_from_bits(uint32_t bits) {
  float uf = __uint_as_float((bits >> 9) | 0x3f800000u) - 1.0f;  // [0,1)
  uf = fmaxf(1.17549435e-38f, uf + 1.17549435e-38f);            // jax: u*(max-min)+min, max(min,.)
  return -log(-log((double)uf));
}

// float <-> monotonic uint encoding for atomicMax on floats
__device__ __forceinline__ uint32_t encf(float f) {
  uint32_t u = __float_as_uint(f);
  return u ^ ((u & 0x80000000u) ? 0xFFFFFFFFu : 0x80000000u);
}
__device__ __forceinline__ float decf(uint32_t e) {
  uint32_t u = (e & 0x80000000u) ? (e ^ 0x80000000u) : ~e;
  return __uint_as_float(u);
}

// ---------------- kernels ----------------
__global__ __launch_bounds__(256) void k_deg(const int* __restrict__ dst, int* __restrict__ deg) {
  int e = blockIdx.x * 256 + threadIdx.x;
  if (e < NE) atomicAdd(&deg[dst[e]], 1);
}

__global__ __launch_bounds__(256) void k_dinv(const int* __restrict__ deg, float* __restrict__ dinv) {
  int i = blockIdx.x * 256 + threadIdx.x;
  if (i < NT) dinv[i] = (float)(1.0 / sqrt((double)(deg[i] + 1)));
}

// g = (concat(x,cand) @ W1) * dinv   [NT,16]
__global__ __launch_bounds__(256) void k_mm1(const float* __restrict__ x, const float* __restrict__ cand,
                                             const float* __restrict__ W, const float* __restrict__ dinv,
                                             float* __restrict__ g) {
  int gid = blockIdx.x * 256 + threadIdx.x;
  if (gid >= NT * 16) return;
  int i = gid >> 4, f = gid & 15;
  const float* hr = (i < N_GRAPH) ? (x + (size_t)i * F_IN)
                                  : (cand + (size_t)(i - N_GRAPH) * F_IN);
  double a = 0.0;
  #pragma unroll 8
  for (int k = 0; k < F_IN; ++k) a += (double)hr[k] * (double)W[k * 16 + f];
  g[gid] = (float)(a * (double)dinv[i]);
}

template <int FI, int FO>
__global__ __launch_bounds__(256) void k_mm(const float* __restrict__ H, const float* __restrict__ W,
                                            const float* __restrict__ dinv, float* __restrict__ g) {
  int gid = blockIdx.x * 256 + threadIdx.x;
  if (gid >= NT * FO) return;
  int i = gid / FO, f = gid - i * FO;
  const float* hr = H + (size_t)i * FI;
  double a = 0.0;
  #pragma unroll
  for (int k = 0; k < FI; ++k) a += (double)hr[k] * (double)W[k * FO + f];
  g[gid] = (float)(a * (double)dinv[i]);
}

template <int F>
__global__ __launch_bounds__(256) void k_edge(const int* __restrict__ src, const int* __restrict__ dst,
                                              const float* __restrict__ g, double* __restrict__ acc) {
  int e = blockIdx.x * 256 + threadIdx.x;
  if (e >= NE) return;
  int s = src[e], d = dst[e];
  const float4* g4 = reinterpret_cast<const float4*>(g + (size_t)s * F);
  double* ar = acc + (size_t)d * F;
  #pragma unroll
  for (int q = 0; q < F / 4; ++q) {
    float4 v = g4[q];
    atomicAdd(&ar[4 * q + 0], (double)v.x);
    atomicAdd(&ar[4 * q + 1], (double)v.y);
    atomicAdd(&ar[4 * q + 2], (double)v.z);
    atomicAdd(&ar[4 * q + 3], (double)v.w);
  }
}

// H_next = dinv * (acc + g) + b
template <int F>
__global__ __launch_bounds__(256) void k_combine(const double* __restrict__ acc, const float* __restrict__ g,
                                                 const float* __restrict__ dinv, const float* __restrict__ b,
                                                 float* __restrict__ Hn) {
  int gid = blockIdx.x * 256 + threadIdx.x;
  if (gid >= NT * F) return;
  int i = gid / F, f = gid - i * F;
  Hn[gid] = (float)((double)dinv[i] * (acc[gid] + (double)g[gid]) + (double)b[f]);
}

// logits = relu6(H @ Wa + ba) @ Wb + bb ; row source: i<NT -> H3[i], else H3[sn[i-NT]]
template <int HID>
__global__ __launch_bounds__(256) void k_head(const float* __restrict__ H, const int* __restrict__ sn,
                                              int nrows,
                                              const float* __restrict__ Wa, const float* __restrict__ ba,
                                              const float* __restrict__ Wb, const float* __restrict__ bb,
                                              float* __restrict__ logits) {
  int i = blockIdx.x * 256 + threadIdx.x;
  if (i >= nrows) return;
  int row = (i < NT) ? i : sn[i - NT];
  const float* hr = H + (size_t)row * 32;
  float h[32];
  #pragma unroll
  for (int k = 0; k < 32; ++k) h[k] = hr[k];
  double hid[HID];
  for (int j = 0; j < HID; ++j) {
    double a = (double)ba[j];
    #pragma unroll
    for (int k = 0; k < 32; ++k) a += (double)h[k] * (double)Wa[k * HID + j];
    hid[j] = fmin(fmax(a, 0.0), 6.0);  // relu6
  }
  for (int t = 0; t < NTYPES; ++t) {
    double l = (double)bb[t];
    #pragma unroll
    for (int j = 0; j < HID; ++j) l += hid[j] * (double)Wb[j * NTYPES + t];
    logits[(size_t)i * NTYPES + t] = (float)l;
  }
}

__global__ __launch_bounds__(256) void k_colmax(const float* __restrict__ L, int nrows,
                                                uint32_t* __restrict__ mb) {
  __shared__ float sm[256][NTYPES];
  float m[NTYPES];
  #pragma unroll
  for (int t = 0; t < NTYPES; ++t) m[t] = -3.402823466e38f;
  for (int r = blockIdx.x * 256 + threadIdx.x; r < nrows; r += gridDim.x * 256) {
    #pragma unroll
    for (int t = 0; t < NTYPES; ++t) m[t] = fmaxf(m[t], L[(size_t)r * NTYPES + t]);
  }
  #pragma unroll
  for (int t = 0; t < NTYPES; ++t) sm[threadIdx.x][t] = m[t];
  __syncthreads();
  for (int s = 128; s > 0; s >>= 1) {
    if (threadIdx.x < s)
      for (int t = 0; t < NTYPES; ++t)
        sm[threadIdx.x][t] = fmaxf(sm[threadIdx.x][t], sm[threadIdx.x + s][t]);
    __syncthreads();
  }
  if (threadIdx.x < NTYPES) atomicMax(&mb[threadIdx.x], encf(sm[0][threadIdx.x]));
}

__global__ __launch_bounds__(256) void k_colsum(const float* __restrict__ L, int nrows,
                                                const uint32_t* __restrict__ mb,
                                                double* __restrict__ sums) {
  __shared__ double sm[256][NTYPES];
  float mx[NTYPES];
  #pragma unroll
  for (int t = 0; t < NTYPES; ++t) mx[t] = decf(mb[t]);
  double s[NTYPES];
  #pragma unroll
  for (int t = 0; t < NTYPES; ++t) s[t] = 0.0;
  for (int r = blockIdx.x * 256 + threadIdx.x; r < nrows; r += gridDim.x * 256) {
    #pragma unroll
    for (int t = 0; t < NTYPES; ++t)
      s[t] += exp((double)L[(size_t)r * NTYPES + t] - (double)mx[t]);
  }
  #pragma unroll
  for (int t = 0; t < NTYPES; ++t) sm[threadIdx.x][t] = s[t];
  __syncthreads();
  for (int st = 128; st > 0; st >>= 1) {
    if (threadIdx.x < st)
      for (int t = 0; t < NTYPES; ++t)
        sm[threadIdx.x][t] += sm[threadIdx.x + st][t];
    __syncthreads();
  }
  if (threadIdx.x < NTYPES) atomicAdd(&sums[threadIdx.x], sm[0][threadIdx.x]);
}

__global__ __launch_bounds__(256) void k_probs_start(const float* __restrict__ L,
                                                     const uint32_t* __restrict__ mb,
                                                     const double* __restrict__ sums,
                                                     float* __restrict__ P) {
  int gid = blockIdx.x * 256 + threadIdx.x;
  if (gid >= NT * NTYPES) return;
  int i = gid / NTYPES, t = gid - i * NTYPES;
  double p = exp((double)L[gid] - (double)decf(mb[t])) / sums[t];
  float pf = (float)p;
  if (i >= N_GRAPH || pf == 0.0f) pf = 1e-10f;
  P[gid] = pf;
}

__global__ __launch_bounds__(256) void k_probs_end(const float* __restrict__ L,
                                                   const uint32_t* __restrict__ mb,
                                                   const double* __restrict__ sums,
                                                   const int* __restrict__ flags,
                                                   float* __restrict__ P) {
  int gid = blockIdx.x * 256 + threadIdx.x;
  if (gid >= 2 * NT * NTYPES) return;
  int j = gid / NTYPES, t = gid - j * NTYPES;
  double p = exp((double)L[gid] - (double)decf(mb[t])) / sums[t];
  float pf = (float)p;
  if ((j < NTYPES && flags[j]) || pf == 0.0f) pf = 1e-10f;
  P[gid] = pf;
}

__global__ __launch_bounds__(256) void k_sample_start(const float* __restrict__ probs,
                                                      float* __restrict__ outSN,
                                                      int* __restrict__ sn, int* __restrict__ flags) {
  int i = blockIdx.x * 256 + threadIdx.x;
  if (i >= NT) return;
  uint32_t a0, a1, b0, b1; derive_keys(a0, a1, b0, b1);
  double best = -1e300; int bi = 0;
  #pragma unroll
  for (int t = 0; t < NTYPES; ++t) {
    uint32_t bits = rng_bits(a0, a1, (uint32_t)(i * NTYPES + t), (uint32_t)(NT * NTYPES));
    double v = log((double)probs[(size_t)i * NTYPES + t]) + gumbel_from_bits(bits);
    if (v > best) { best = v; bi = t; }
  }
  sn[i] = bi;
  outSN[i] = (float)bi;
  flags[bi] = 1;   // benign race: all writers store 1
}

__global__ __launch_bounds__(256) void k_sample_end(const float* __restrict__ probs,
                                                    float* __restrict__ outEN) {
  int j = blockIdx.x * 256 + threadIdx.x;
  if (j >= 2 * NT) return;
  uint32_t a0, a1, b0, b1; derive_keys(a0, a1, b0, b1);
  double best = -1e300; int bi = 0;
  #pragma unroll
  for (int t = 0; t < NTYPES; ++t) {
    uint32_t bits = rng_bits(b0, b1, (uint32_t)(j * NTYPES + t), (uint32_t)(2 * NT * NTYPES));
    double v = log((double)probs[(size_t)j * NTYPES + t]) + gumbel_from_bits(bits);
    if (v > best) { best = v; bi = t; }
  }
  outEN[j] = (float)bi;
}

// ---------------- host ----------------
extern "C" void kernel_launch(void* const* d_in, const int* in_sizes, int n_in,
                              void* d_out, int out_size, void* d_ws, size_t ws_size,
                              hipStream_t stream) {
  const float* x    = (const float*)d_in[0];
  const float* cand = (const float*)d_in[1];
  const int*   ei   = (const int*)d_in[2];
  // d_in[3] = candidate_idx (always N_GRAPH..NT-1, hardcoded)
  const float* W1 = (const float*)d_in[4];  const float* b1 = (const float*)d_in[5];
  const float* W2 = (const float*)d_in[6];  const float* b2 = (const float*)d_in[7];
  const float* W3 = (const float*)d_in[8];  const float* b3 = (const float*)d_in[9];
  const float* Ws1 = (const float*)d_in[10]; const float* bs1 = (const float*)d_in[11];
  const float* Ws2 = (const float*)d_in[12]; const float* bs2 = (const float*)d_in[13];
  const float* We1 = (const float*)d_in[14]; const float* be1 = (const float*)d_in[15];
  const float* We2 = (const float*)d_in[16]; const float* be2 = (const float*)d_in[17];
  float* out = (float*)d_out;
  // output layout: [start_node NT][end_node 2NT][start_probs NT*10][end_probs 2NT*10]
  float* outSN = out;
  float* outEN = out + NT;
  float* outPS = out + 3 * NT;
  float* outPE = out + 13 * NT;

  char* ws = (char*)d_ws;
  size_t off = 0;
  auto alloc = [&](size_t bytes) -> void* {
    void* p = ws + off;
    off += (bytes + 511) & ~(size_t)511;
    return p;
  };
  int*      deg     = (int*)alloc((size_t)NT * 4);
  float*    dinv    = (float*)alloc((size_t)NT * 4);
  float*    g       = (float*)alloc((size_t)NT * 32 * 4);
  double*   accd    = (double*)alloc((size_t)NT * 32 * 8);
  float*    Ha      = (float*)alloc((size_t)NT * 32 * 4);
  float*    Hb      = (float*)alloc((size_t)NT * 32 * 4);
  float*    logitsS = (float*)alloc((size_t)NT * NTYPES * 4);
  float*    logitsE = (float*)alloc((size_t)2 * NT * NTYPES * 4);
  int*      sn      = (int*)alloc((size_t)NT * 4);
  uint32_t* maxS    = (uint32_t*)alloc(64);
  double*   sumS    = (double*)alloc(128);
  uint32_t* maxE    = (uint32_t*)alloc(64);
  double*   sumE    = (double*)alloc(128);
  int*      flags   = (int*)alloc(64);
  (void)ws_size; (void)in_sizes; (void)n_in; (void)out_size;

  const int* srcA = ei;
  const int* dstA = ei + NE;

  const int B = 256;
  auto blocks = [](long long nthreads) { return (int)((nthreads + 255) / 256); };

  // degrees + dinv
  hipMemsetAsync(deg, 0, (size_t)NT * 4, stream);
  k_deg<<<blocks(NE), B, 0, stream>>>(dstA, deg);
  k_dinv<<<blocks(NT), B, 0, stream>>>(deg, dinv);

  // layer 1: 128 -> 16
  k_mm1<<<blocks((long long)NT * 16), B, 0, stream>>>(x, cand, W1, dinv, g);
  hipMemsetAsync(accd, 0, (size_t)NT * 16 * 8, stream);
  k_edge<16><<<blocks(NE), B, 0, stream>>>(srcA, dstA, g, accd);
  k_combine<16><<<blocks((long long)NT * 16), B, 0, stream>>>(accd, g, dinv, b1, Ha);

  // layer 2: 16 -> 24
  k_mm<16, 24><<<blocks((long long)NT * 24), B, 0, stream>>>(Ha, W2, dinv, g);
  hipMemsetAsync(accd, 0, (size_t)NT * 24 * 8, stream);
  k_edge<24><<<blocks(NE), B, 0, stream>>>(srcA, dstA, g, accd);
  k_combine<24><<<blocks((long long)NT * 24), B, 0, stream>>>(accd, g, dinv, b2, Hb);

  // layer 3: 24 -> 32
  k_mm<24, 32><<<blocks((long long)NT * 32), B, 0, stream>>>(Hb, W3, dinv, g);
  hipMemsetAsync(accd, 0, (size_t)NT * 32 * 8, stream);
  k_edge<32><<<blocks(NE), B, 0, stream>>>(srcA, dstA, g, accd);
  k_combine<32><<<blocks((long long)NT * 32), B, 0, stream>>>(accd, g, dinv, b3, Ha);
  // H3 = Ha

  // start head
  k_head<16><<<blocks(NT), B, 0, stream>>>(Ha, sn, NT, Ws1, bs1, Ws2, bs2, logitsS);
  hipMemsetAsync(maxS, 0, (size_t)((char*)flags - (char*)maxS) + 64, stream);  // maxS..flags
  k_colmax<<<512, B, 0, stream>>>(logitsS, NT, maxS);
  k_colsum<<<512, B, 0, stream>>>(logitsS, NT, maxS, sumS);
  k_probs_start<<<blocks((long long)NT * NTYPES), B, 0, stream>>>(logitsS, maxS, sumS, outPS);
  k_sample_start<<<blocks(NT), B, 0, stream>>>(outPS, outSN, sn, flags);

  // end head (rows: [H3; H3[sn]])
  k_head<24><<<blocks(2 * NT), B, 0, stream>>>(Ha, sn, 2 * NT, We1, be1, We2, be2, logitsE);
  k_colmax<<<512, B, 0, stream>>>(logitsE, 2 * NT, maxE);
  k_colsum<<<512, B, 0, stream>>>(logitsE, 2 * NT, maxE, sumE);
  k_probs_end<<<blocks((long long)2 * NT * NTYPES), B, 0, stream>>>(logitsE, maxE, sumE, flags, outPE);
  k_sample_end<<<blocks(2 * NT), B, 0, stream>>>(outPE, outEN);
}

// Round 2
// 1442.018 us; speedup vs baseline: 14.9650x; 14.9650x over previous
//
#include <hip/hip_runtime.h>
#include <stdint.h>

// ---------------- problem constants ----------------
constexpr int N_GRAPH = 100000;
constexpr int N_CANDS = 10;
constexpr int NT      = N_GRAPH + N_CANDS;   // 100010
constexpr int F_IN    = 128;
constexpr int NTYPES  = 10;
constexpr int NE      = 6400000;
constexpr int NB_SCAN = (NT + 255) / 256;    // 391

#define RNG_VARIANT 0

// ---------------- threefry2x32 (matches jax._src.prng) ----------------
__device__ __forceinline__ void tf2x32(uint32_t k0, uint32_t k1, uint32_t x0, uint32_t x1,
                                       uint32_t& o0, uint32_t& o1) {
  const uint32_t ks2 = k0 ^ k1 ^ 0x1BD11BDAu;
  uint32_t v0 = x0 + k0, v1 = x1 + k1;
#define TFR(r) { v0 += v1; v1 = (v1 << (r)) | (v1 >> (32 - (r))); v1 ^= v0; }
  TFR(13) TFR(15) TFR(26) TFR(6)
  v0 += k1;  v1 += ks2 + 1u;
  TFR(17) TFR(29) TFR(16) TFR(24)
  v0 += ks2; v1 += k0 + 2u;
  TFR(13) TFR(15) TFR(26) TFR(6)
  v0 += k0;  v1 += k1 + 3u;
  TFR(17) TFR(29) TFR(16) TFR(24)
  v0 += k1;  v1 += ks2 + 4u;
  TFR(13) TFR(15) TFR(26) TFR(6)
  v0 += ks2; v1 += k0 + 5u;
#undef TFR
  o0 = v0; o1 = v1;
}

__device__ __forceinline__ void derive_keys(uint32_t& a0, uint32_t& a1,
                                            uint32_t& b0, uint32_t& b1) {
#if RNG_VARIANT == 2
  uint32_t c0, c1, d0, d1;
  tf2x32(0u, 42u, 0u, 2u, c0, c1);
  tf2x32(0u, 42u, 1u, 3u, d0, d1);
  a0 = c0; a1 = d0; b0 = c1; b1 = d1;
#else
  tf2x32(0u, 42u, 0u, 0u, a0, a1);
  tf2x32(0u, 42u, 0u, 1u, b0, b1);
#endif
}

__device__ __forceinline__ uint32_t rng_bits(uint32_t k0, uint32_t k1,
                                             uint32_t idx, uint32_t total) {
#if RNG_VARIANT == 0
  uint32_t o0, o1; tf2x32(k0, k1, 0u, idx, o0, o1); return o0 ^ o1;
#elif RNG_VARIANT == 1
  uint32_t o0, o1; tf2x32(k0, k1, 0u, idx, o0, o1); return o1;
#else
  uint32_t half = total >> 1; uint32_t o0, o1;
  if (idx < half) { tf2x32(k0, k1, idx, idx + half, o0, o1); return o0; }
  tf2x32(k0, k1, idx - half, idx, o0, o1); return o1;
#endif
}

__device__ __forceinline__ double gumbel_from_bits(uint32_t bits) {
  float uf = __uint_as_float((bits >> 9) | 0x3f800000u) - 1.0f;  // [0,1)
  uf = fmaxf(1.17549435e-38f, uf + 1.17549435e-38f);
  return -log(-log((double)uf));
}

__device__ __forceinline__ uint32_t encf(float f) {
  uint32_t u = __float_as_uint(f);
  return u ^ ((u & 0x80000000u) ? 0xFFFFFFFFu : 0x80000000u);
}
__device__ __forceinline__ float decf(uint32_t e) {
  uint32_t u = (e & 0x80000000u) ? (e ^ 0x80000000u) : ~e;
  return __uint_as_float(u);
}

// ---------------- degree / CSR build ----------------
__global__ __launch_bounds__(256) void k_deg(const int* __restrict__ dst, int* __restrict__ deg) {
  int e = blockIdx.x * 256 + threadIdx.x;
  if (e < NE) atomicAdd(&deg[dst[e]], 1);
}

__global__ __launch_bounds__(256) void k_dinv(const int* __restrict__ deg, float* __restrict__ dinv) {
  int i = blockIdx.x * 256 + threadIdx.x;
  if (i < NT) dinv[i] = (float)(1.0 / sqrt((double)(deg[i] + 1)));
}

// block-local inclusive scan of deg -> tmp; per-block totals -> partial
__global__ __launch_bounds__(256) void k_scan_blocks(const int* __restrict__ deg,
                                                     int* __restrict__ tmp,
                                                     int* __restrict__ partial) {
  __shared__ int sm[256];
  int i = blockIdx.x * 256 + threadIdx.x;
  int v = (i < NT) ? deg[i] : 0;
  sm[threadIdx.x] = v;
  __syncthreads();
  #pragma unroll
  for (int s = 1; s < 256; s <<= 1) {
    int add = (threadIdx.x >= s) ? sm[threadIdx.x - s] : 0;
    __syncthreads();
    sm[threadIdx.x] += add;
    __syncthreads();
  }
  if (i < NT) tmp[i] = sm[threadIdx.x];
  if (threadIdx.x == 255) partial[blockIdx.x] = sm[255];
}

// single-block exclusive scan of partials (NB_SCAN=391 <= 512)
__global__ __launch_bounds__(512) void k_scan_partials(int* __restrict__ partial) {
  __shared__ int sm[512];
  int v = (threadIdx.x < NB_SCAN) ? partial[threadIdx.x] : 0;
  sm[threadIdx.x] = v;
  __syncthreads();
  #pragma unroll
  for (int s = 1; s < 512; s <<= 1) {
    int add = (threadIdx.x >= s) ? sm[threadIdx.x - s] : 0;
    __syncthreads();
    sm[threadIdx.x] += add;
    __syncthreads();
  }
  if (threadIdx.x < NB_SCAN) partial[threadIdx.x] = sm[threadIdx.x] - v;  // exclusive
}

// rowptr[i+1] = partial[b] + tmp[i]; cursor[i] = rowptr[i]
__global__ __launch_bounds__(256) void k_scan_final(const int* __restrict__ deg,
                                                    const int* __restrict__ tmp,
                                                    const int* __restrict__ partial,
                                                    int* __restrict__ rowptr,
                                                    int* __restrict__ cursor) {
  int i = blockIdx.x * 256 + threadIdx.x;
  if (i >= NT) return;
  int incl = partial[blockIdx.x] + tmp[i];
  rowptr[i + 1] = incl;
  cursor[i] = incl - deg[i];
  if (i == 0) rowptr[0] = 0;
}

__global__ __launch_bounds__(256) void k_scatter(const int* __restrict__ src,
                                                 const int* __restrict__ dst,
                                                 int* __restrict__ cursor,
                                                 int* __restrict__ col) {
  int e = blockIdx.x * 256 + threadIdx.x;
  if (e >= NE) return;
  int p = atomicAdd(&cursor[dst[e]], 1);
  col[p] = src[e];
}

// ---------------- dense per-node matmuls ----------------
// g = (concat(x,cand) @ W1) * dinv   [NT,16]
__global__ __launch_bounds__(256) void k_mm1(const float* __restrict__ x, const float* __restrict__ cand,
                                             const float* __restrict__ W, const float* __restrict__ dinv,
                                             float* __restrict__ g) {
  int gid = blockIdx.x * 256 + threadIdx.x;
  if (gid >= NT * 16) return;
  int i = gid >> 4, f = gid & 15;
  const float* hr = (i < N_GRAPH) ? (x + (size_t)i * F_IN)
                                  : (cand + (size_t)(i - N_GRAPH) * F_IN);
  double a = 0.0;
  #pragma unroll 8
  for (int k = 0; k < F_IN; ++k) a += (double)hr[k] * (double)W[k * 16 + f];
  g[gid] = (float)(a * (double)dinv[i]);
}

template <int FI, int FO>
__global__ __launch_bounds__(256) void k_mm(const float* __restrict__ H, const float* __restrict__ W,
                                            const float* __restrict__ dinv, float* __restrict__ g) {
  int gid = blockIdx.x * 256 + threadIdx.x;
  if (gid >= NT * FO) return;
  int i = gid / FO, f = gid - i * FO;
  const float* hr = H + (size_t)i * FI;
  double a = 0.0;
  #pragma unroll
  for (int k = 0; k < FI; ++k) a += (double)hr[k] * (double)W[k * FO + f];
  g[gid] = (float)(a * (double)dinv[i]);
}

// ---------------- fused CSR gather + self-loop + bias ----------------
// Hn[i][f] = dinv[i] * (sum_{e in row i} g[col[e]][f] + g[i][f]) + b[f]
template <int F, int R>
__global__ __launch_bounds__(F * R) void k_gcn(const int* __restrict__ rowptr,
                                               const int* __restrict__ col,
                                               const float* __restrict__ g,
                                               const float* __restrict__ dinv,
                                               const float* __restrict__ b,
                                               float* __restrict__ Hn) {
  int i = blockIdx.x * R + threadIdx.y;
  if (i >= NT) return;
  int f = threadIdx.x;
  int e0 = rowptr[i], e1 = rowptr[i + 1];
  double acc = 0.0;
  int e = e0;
  for (; e + 4 <= e1; e += 4) {
    int c0 = col[e], c1 = col[e + 1], c2 = col[e + 2], c3 = col[e + 3];
    float v0 = g[(size_t)c0 * F + f];
    float v1 = g[(size_t)c1 * F + f];
    float v2 = g[(size_t)c2 * F + f];
    float v3 = g[(size_t)c3 * F + f];
    acc += (double)v0 + (double)v1 + (double)v2 + (double)v3;
  }
  for (; e < e1; ++e) acc += (double)g[(size_t)col[e] * F + f];
  acc += (double)g[(size_t)i * F + f];
  Hn[(size_t)i * F + f] = (float)((double)dinv[i] * acc + (double)b[f]);
}

// ---------------- heads / softmax / sampling ----------------
template <int HID>
__global__ __launch_bounds__(256) void k_head(const float* __restrict__ H, const int* __restrict__ sn,
                                              int nrows,
                                              const float* __restrict__ Wa, const float* __restrict__ ba,
                                              const float* __restrict__ Wb, const float* __restrict__ bb,
                                              float* __restrict__ logits) {
  int i = blockIdx.x * 256 + threadIdx.x;
  if (i >= nrows) return;
  int row = (i < NT) ? i : sn[i - NT];
  const float* hr = H + (size_t)row * 32;
  float h[32];
  #pragma unroll
  for (int k = 0; k < 32; ++k) h[k] = hr[k];
  double hid[HID];
  for (int j = 0; j < HID; ++j) {
    double a = (double)ba[j];
    #pragma unroll
    for (int k = 0; k < 32; ++k) a += (double)h[k] * (double)Wa[k * HID + j];
    hid[j] = fmin(fmax(a, 0.0), 6.0);  // relu6
  }
  for (int t = 0; t < NTYPES; ++t) {
    double l = (double)bb[t];
    #pragma unroll
    for (int j = 0; j < HID; ++j) l += hid[j] * (double)Wb[j * NTYPES + t];
    logits[(size_t)i * NTYPES + t] = (float)l;
  }
}

__global__ __launch_bounds__(256) void k_colmax(const float* __restrict__ L, int nrows,
                                                uint32_t* __restrict__ mb) {
  __shared__ float sm[256][NTYPES];
  float m[NTYPES];
  #pragma unroll
  for (int t = 0; t < NTYPES; ++t) m[t] = -3.402823466e38f;
  for (int r = blockIdx.x * 256 + threadIdx.x; r < nrows; r += gridDim.x * 256) {
    #pragma unroll
    for (int t = 0; t < NTYPES; ++t) m[t] = fmaxf(m[t], L[(size_t)r * NTYPES + t]);
  }
  #pragma unroll
  for (int t = 0; t < NTYPES; ++t) sm[threadIdx.x][t] = m[t];
  __syncthreads();
  for (int s = 128; s > 0; s >>= 1) {
    if (threadIdx.x < s)
      for (int t = 0; t < NTYPES; ++t)
        sm[threadIdx.x][t] = fmaxf(sm[threadIdx.x][t], sm[threadIdx.x + s][t]);
    __syncthreads();
  }
  if (threadIdx.x < NTYPES) atomicMax(&mb[threadIdx.x], encf(sm[0][threadIdx.x]));
}

__global__ __launch_bounds__(256) void k_colsum(const float* __restrict__ L, int nrows,
                                                const uint32_t* __restrict__ mb,
                                                double* __restrict__ sums) {
  __shared__ double sm[256][NTYPES];
  float mx[NTYPES];
  #pragma unroll
  for (int t = 0; t < NTYPES; ++t) mx[t] = decf(mb[t]);
  double s[NTYPES];
  #pragma unroll
  for (int t = 0; t < NTYPES; ++t) s[t] = 0.0;
  for (int r = blockIdx.x * 256 + threadIdx.x; r < nrows; r += gridDim.x * 256) {
    #pragma unroll
    for (int t = 0; t < NTYPES; ++t)
      s[t] += exp((double)L[(size_t)r * NTYPES + t] - (double)mx[t]);
  }
  #pragma unroll
  for (int t = 0; t < NTYPES; ++t) sm[threadIdx.x][t] = s[t];
  __syncthreads();
  for (int st = 128; st > 0; st >>= 1) {
    if (threadIdx.x < st)
      for (int t = 0; t < NTYPES; ++t)
        sm[threadIdx.x][t] += sm[threadIdx.x + st][t];
    __syncthreads();
  }
  if (threadIdx.x < NTYPES) atomicAdd(&sums[threadIdx.x], sm[0][threadIdx.x]);
}

__global__ __launch_bounds__(256) void k_probs_start(const float* __restrict__ L,
                                                     const uint32_t* __restrict__ mb,
                                                     const double* __restrict__ sums,
                                                     float* __restrict__ P) {
  int gid = blockIdx.x * 256 + threadIdx.x;
  if (gid >= NT * NTYPES) return;
  int i = gid / NTYPES, t = gid - i * NTYPES;
  double p = exp((double)L[gid] - (double)decf(mb[t])) / sums[t];
  float pf = (float)p;
  if (i >= N_GRAPH || pf == 0.0f) pf = 1e-10f;
  P[gid] = pf;
}

__global__ __launch_bounds__(256) void k_probs_end(const float* __restrict__ L,
                                                   const uint32_t* __restrict__ mb,
                                                   const double* __restrict__ sums,
                                                   const int* __restrict__ flags,
                                                   float* __restrict__ P) {
  int gid = blockIdx.x * 256 + threadIdx.x;
  if (gid >= 2 * NT * NTYPES) return;
  int j = gid / NTYPES, t = gid - j * NTYPES;
  double p = exp((double)L[gid] - (double)decf(mb[t])) / sums[t];
  float pf = (float)p;
  if ((j < NTYPES && flags[j]) || pf == 0.0f) pf = 1e-10f;
  P[gid] = pf;
}

__global__ __launch_bounds__(256) void k_sample_start(const float* __restrict__ probs,
                                                      float* __restrict__ outSN,
                                                      int* __restrict__ sn, int* __restrict__ flags) {
  int i = blockIdx.x * 256 + threadIdx.x;
  if (i >= NT) return;
  uint32_t a0, a1, b0, b1; derive_keys(a0, a1, b0, b1);
  double best = -1e300; int bi = 0;
  #pragma unroll
  for (int t = 0; t < NTYPES; ++t) {
    uint32_t bits = rng_bits(a0, a1, (uint32_t)(i * NTYPES + t), (uint32_t)(NT * NTYPES));
    double v = log((double)probs[(size_t)i * NTYPES + t]) + gumbel_from_bits(bits);
    if (v > best) { best = v; bi = t; }
  }
  sn[i] = bi;
  outSN[i] = (float)bi;
  flags[bi] = 1;   // benign race: all writers store 1
}

__global__ __launch_bounds__(256) void k_sample_end(const float* __restrict__ probs,
                                                    float* __restrict__ outEN) {
  int j = blockIdx.x * 256 + threadIdx.x;
  if (j >= 2 * NT) return;
  uint32_t a0, a1, b0, b1; derive_keys(a0, a1, b0, b1);
  double best = -1e300; int bi = 0;
  #pragma unroll
  for (int t = 0; t < NTYPES; ++t) {
    uint32_t bits = rng_bits(b0, b1, (uint32_t)(j * NTYPES + t), (uint32_t)(2 * NT * NTYPES));
    double v = log((double)probs[(size_t)j * NTYPES + t]) + gumbel_from_bits(bits);
    if (v > best) { best = v; bi = t; }
  }
  outEN[j] = (float)bi;
}

// ---------------- host ----------------
extern "C" void kernel_launch(void* const* d_in, const int* in_sizes, int n_in,
                              void* d_out, int out_size, void* d_ws, size_t ws_size,
                              hipStream_t stream) {
  const float* x    = (const float*)d_in[0];
  const float* cand = (const float*)d_in[1];
  const int*   ei   = (const int*)d_in[2];
  const float* W1 = (const float*)d_in[4];  const float* b1 = (const float*)d_in[5];
  const float* W2 = (const float*)d_in[6];  const float* b2 = (const float*)d_in[7];
  const float* W3 = (const float*)d_in[8];  const float* b3 = (const float*)d_in[9];
  const float* Ws1 = (const float*)d_in[10]; const float* bs1 = (const float*)d_in[11];
  const float* Ws2 = (const float*)d_in[12]; const float* bs2 = (const float*)d_in[13];
  const float* We1 = (const float*)d_in[14]; const float* be1 = (const float*)d_in[15];
  const float* We2 = (const float*)d_in[16]; const float* be2 = (const float*)d_in[17];
  float* out = (float*)d_out;
  float* outSN = out;
  float* outEN = out + NT;
  float* outPS = out + 3 * NT;
  float* outPE = out + 13 * NT;

  char* ws = (char*)d_ws;
  size_t off = 0;
  auto alloc = [&](size_t bytes) -> void* {
    void* p = ws + off;
    off += (bytes + 511) & ~(size_t)511;
    return p;
  };
  int*      deg     = (int*)alloc((size_t)NT * 4);
  float*    dinv    = (float*)alloc((size_t)NT * 4);
  float*    g       = (float*)alloc((size_t)NT * 32 * 4);
  float*    Ha      = (float*)alloc((size_t)NT * 32 * 4);
  float*    Hb      = (float*)alloc((size_t)NT * 32 * 4);
  int*      rowptr  = (int*)alloc((size_t)(NT + 1) * 4);
  int*      tmp     = (int*)alloc((size_t)NT * 4);
  int*      partial = (int*)alloc(512 * 4);
  int*      cursor  = (int*)alloc((size_t)NT * 4);
  int*      col     = (int*)alloc((size_t)NE * 4);
  float*    logitsS = (float*)alloc((size_t)NT * NTYPES * 4);
  float*    logitsE = (float*)alloc((size_t)2 * NT * NTYPES * 4);
  int*      sn      = (int*)alloc((size_t)NT * 4);
  uint32_t* maxS    = (uint32_t*)alloc(64);
  double*   sumS    = (double*)alloc(128);
  uint32_t* maxE    = (uint32_t*)alloc(64);
  double*   sumE    = (double*)alloc(128);
  int*      flags   = (int*)alloc(64);
  (void)ws_size; (void)in_sizes; (void)n_in; (void)out_size;

  const int* srcA = ei;
  const int* dstA = ei + NE;

  const int B = 256;
  auto blocks = [](long long nthreads) { return (int)((nthreads + 255) / 256); };

  // degrees + dinv + CSR
  hipMemsetAsync(deg, 0, (size_t)NT * 4, stream);
  k_deg<<<blocks(NE), B, 0, stream>>>(dstA, deg);
  k_dinv<<<blocks(NT), B, 0, stream>>>(deg, dinv);
  k_scan_blocks<<<NB_SCAN, 256, 0, stream>>>(deg, tmp, partial);
  k_scan_partials<<<1, 512, 0, stream>>>(partial);
  k_scan_final<<<NB_SCAN, 256, 0, stream>>>(deg, tmp, partial, rowptr, cursor);
  k_scatter<<<blocks(NE), B, 0, stream>>>(srcA, dstA, cursor, col);

  // layer 1: 128 -> 16
  k_mm1<<<blocks((long long)NT * 16), B, 0, stream>>>(x, cand, W1, dinv, g);
  k_gcn<16, 16><<<(NT + 15) / 16, dim3(16, 16), 0, stream>>>(rowptr, col, g, dinv, b1, Ha);

  // layer 2: 16 -> 24
  k_mm<16, 24><<<blocks((long long)NT * 24), B, 0, stream>>>(Ha, W2, dinv, g);
  k_gcn<24, 10><<<(NT + 9) / 10, dim3(24, 10), 0, stream>>>(rowptr, col, g, dinv, b2, Hb);

  // layer 3: 24 -> 32
  k_mm<24, 32><<<blocks((long long)NT * 32), B, 0, stream>>>(Hb, W3, dinv, g);
  k_gcn<32, 8><<<(NT + 7) / 8, dim3(32, 8), 0, stream>>>(rowptr, col, g, dinv, b3, Ha);
  // H3 = Ha

  // start head
  k_head<16><<<blocks(NT), B, 0, stream>>>(Ha, sn, NT, Ws1, bs1, Ws2, bs2, logitsS);
  hipMemsetAsync(maxS, 0, (size_t)((char*)flags - (char*)maxS) + 64, stream);
  k_colmax<<<512, B, 0, stream>>>(logitsS, NT, maxS);
  k_colsum<<<512, B, 0, stream>>>(logitsS, NT, maxS, sumS);
  k_probs_start<<<blocks((long long)NT * NTYPES), B, 0, stream>>>(logitsS, maxS, sumS, outPS);
  k_sample_start<<<blocks(NT), B, 0, stream>>>(outPS, outSN, sn, flags);

  // end head (rows: [H3; H3[sn]])
  k_head<24><<<blocks(2 * NT), B, 0, stream>>>(Ha, sn, 2 * NT, We1, be1, We2, be2, logitsE);
  k_colmax<<<512, B, 0, stream>>>(logitsE, 2 * NT, maxE);
  k_colsum<<<512, B, 0, stream>>>(logitsE, 2 * NT, maxE, sumE);
  k_probs_end<<<blocks((long long)2 * NT * NTYPES), B, 0, stream>>>(logitsE, maxE, sumE, flags, outPE);
  k_sample_end<<<blocks(2 * NT), B, 0, stream>>>(outPE, outEN);
}

// Round 3
// 1241.833 us; speedup vs baseline: 17.3774x; 1.1612x over previous
//
#include <hip/hip_runtime.h>
#include <stdint.h>

// ---------------- problem constants ----------------
constexpr int N_GRAPH = 100000;
constexpr int N_CANDS = 10;
constexpr int NT      = N_GRAPH + N_CANDS;   // 100010
constexpr int F_IN    = 128;
constexpr int NTYPES  = 10;
constexpr int NE      = 6400000;
constexpr int NB_SCAN = (NT + 255) / 256;    // 391
constexpr int NPB     = 16;                  // nodes per bucket
constexpr int NBK     = (NT + NPB - 1) / NPB; // 6251 buckets

#define RNG_VARIANT 0

// ---------------- threefry2x32 (matches jax._src.prng) ----------------
__device__ __forceinline__ void tf2x32(uint32_t k0, uint32_t k1, uint32_t x0, uint32_t x1,
                                       uint32_t& o0, uint32_t& o1) {
  const uint32_t ks2 = k0 ^ k1 ^ 0x1BD11BDAu;
  uint32_t v0 = x0 + k0, v1 = x1 + k1;
#define TFR(r) { v0 += v1; v1 = (v1 << (r)) | (v1 >> (32 - (r))); v1 ^= v0; }
  TFR(13) TFR(15) TFR(26) TFR(6)
  v0 += k1;  v1 += ks2 + 1u;
  TFR(17) TFR(29) TFR(16) TFR(24)
  v0 += ks2; v1 += k0 + 2u;
  TFR(13) TFR(15) TFR(26) TFR(6)
  v0 += k0;  v1 += k1 + 3u;
  TFR(17) TFR(29) TFR(16) TFR(24)
  v0 += k1;  v1 += ks2 + 4u;
  TFR(13) TFR(15) TFR(26) TFR(6)
  v0 += ks2; v1 += k0 + 5u;
#undef TFR
  o0 = v0; o1 = v1;
}

__device__ __forceinline__ void derive_keys(uint32_t& a0, uint32_t& a1,
                                            uint32_t& b0, uint32_t& b1) {
#if RNG_VARIANT == 2
  uint32_t c0, c1, d0, d1;
  tf2x32(0u, 42u, 0u, 2u, c0, c1);
  tf2x32(0u, 42u, 1u, 3u, d0, d1);
  a0 = c0; a1 = d0; b0 = c1; b1 = d1;
#else
  tf2x32(0u, 42u, 0u, 0u, a0, a1);
  tf2x32(0u, 42u, 0u, 1u, b0, b1);
#endif
}

__device__ __forceinline__ uint32_t rng_bits(uint32_t k0, uint32_t k1,
                                             uint32_t idx, uint32_t total) {
#if RNG_VARIANT == 0
  uint32_t o0, o1; tf2x32(k0, k1, 0u, idx, o0, o1); return o0 ^ o1;
#elif RNG_VARIANT == 1
  uint32_t o0, o1; tf2x32(k0, k1, 0u, idx, o0, o1); return o1;
#else
  uint32_t half = total >> 1; uint32_t o0, o1;
  if (idx < half) { tf2x32(k0, k1, idx, idx + half, o0, o1); return o0; }
  tf2x32(k0, k1, idx - half, idx, o0, o1); return o1;
#endif
}

__device__ __forceinline__ double gumbel_from_bits(uint32_t bits) {
  float uf = __uint_as_float((bits >> 9) | 0x3f800000u) - 1.0f;  // [0,1)
  uf = fmaxf(1.17549435e-38f, uf + 1.17549435e-38f);
  return -log(-log((double)uf));
}

__device__ __forceinline__ uint32_t encf(float f) {
  uint32_t u = __float_as_uint(f);
  return u ^ ((u & 0x80000000u) ? 0xFFFFFFFFu : 0x80000000u);
}
__device__ __forceinline__ float decf(uint32_t e) {
  uint32_t u = (e & 0x80000000u) ? (e ^ 0x80000000u) : ~e;
  return __uint_as_float(u);
}

// ---------------- degree / CSR build ----------------
__global__ __launch_bounds__(256) void k_deg(const int* __restrict__ dst, int* __restrict__ deg) {
  int e = blockIdx.x * 256 + threadIdx.x;
  if (e < NE) atomicAdd(&deg[dst[e]], 1);
}

__global__ __launch_bounds__(256) void k_dinv(const int* __restrict__ deg, float* __restrict__ dinv) {
  int i = blockIdx.x * 256 + threadIdx.x;
  if (i < NT) dinv[i] = (float)(1.0 / sqrt((double)(deg[i] + 1)));
}

// block-local inclusive scan of deg -> tmp; per-block totals -> partial
__global__ __launch_bounds__(256) void k_scan_blocks(const int* __restrict__ deg,
                                                     int* __restrict__ tmp,
                                                     int* __restrict__ partial) {
  __shared__ int sm[256];
  int i = blockIdx.x * 256 + threadIdx.x;
  int v = (i < NT) ? deg[i] : 0;
  sm[threadIdx.x] = v;
  __syncthreads();
  #pragma unroll
  for (int s = 1; s < 256; s <<= 1) {
    int add = (threadIdx.x >= s) ? sm[threadIdx.x - s] : 0;
    __syncthreads();
    sm[threadIdx.x] += add;
    __syncthreads();
  }
  if (i < NT) tmp[i] = sm[threadIdx.x];
  if (threadIdx.x == 255) partial[blockIdx.x] = sm[255];
}

// single-block exclusive scan of partials (NB_SCAN=391 <= 512)
__global__ __launch_bounds__(512) void k_scan_partials(int* __restrict__ partial) {
  __shared__ int sm[512];
  int v = (threadIdx.x < NB_SCAN) ? partial[threadIdx.x] : 0;
  sm[threadIdx.x] = v;
  __syncthreads();
  #pragma unroll
  for (int s = 1; s < 512; s <<= 1) {
    int add = (threadIdx.x >= s) ? sm[threadIdx.x - s] : 0;
    __syncthreads();
    sm[threadIdx.x] += add;
    __syncthreads();
  }
  if (threadIdx.x < NB_SCAN) partial[threadIdx.x] = sm[threadIdx.x] - v;  // exclusive
}

// rowptr[i+1] = partial[b] + tmp[i]
__global__ __launch_bounds__(256) void k_scan_final(const int* __restrict__ tmp,
                                                    const int* __restrict__ partial,
                                                    int* __restrict__ rowptr) {
  int i = blockIdx.x * 256 + threadIdx.x;
  if (i >= NT) return;
  rowptr[i + 1] = partial[blockIdx.x] + tmp[i];
  if (i == 0) rowptr[0] = 0;
}

__global__ __launch_bounds__(256) void k_bcur_init(const int* __restrict__ rowptr,
                                                   int* __restrict__ bcur) {
  int b = blockIdx.x * 256 + threadIdx.x;
  if (b < NBK) bcur[b] = rowptr[min(b * NPB, NT)];
}

// pass B: scatter packed entries (src | local_dst<<28) into bucket regions
__global__ __launch_bounds__(256) void k_scatter_bucket(const int* __restrict__ src,
                                                        const int* __restrict__ dst,
                                                        int* __restrict__ bcur,
                                                        uint32_t* __restrict__ tmpent) {
  int e = blockIdx.x * 256 + threadIdx.x;
  if (e >= NE) return;
  int s = src[e], d = dst[e];
  int b = d >> 4;
  int p = atomicAdd(&bcur[b], 1);
  tmpent[p] = (uint32_t)s | ((uint32_t)(d & 15) << 28);
}

// pass C: within each bucket, place src into exact CSR position via LDS cursors
__global__ __launch_bounds__(256) void k_bucket_place(const int* __restrict__ rowptr,
                                                      const uint32_t* __restrict__ tmpent,
                                                      int* __restrict__ col) {
  __shared__ int cur[NPB];
  int b = blockIdx.x;
  int base = b * NPB;
  if (threadIdx.x < NPB) {
    int n = base + threadIdx.x;
    cur[threadIdx.x] = (n < NT) ? rowptr[n] : 0;
  }
  __syncthreads();
  int e0 = rowptr[min(base, NT)];
  int e1 = rowptr[min(base + NPB, NT)];
  for (int e = e0 + threadIdx.x; e < e1; e += 256) {
    uint32_t v = tmpent[e];
    int s = (int)(v & 0x1FFFFu);     // src < 2^17
    int local = (int)(v >> 28);
    int pos = atomicAdd(&cur[local], 1);
    col[pos] = s;
  }
}

// ---------------- dense per-node matmuls ----------------
__global__ __launch_bounds__(256) void k_mm1(const float* __restrict__ x, const float* __restrict__ cand,
                                             const float* __restrict__ W, const float* __restrict__ dinv,
                                             float* __restrict__ g) {
  int gid = blockIdx.x * 256 + threadIdx.x;
  if (gid >= NT * 16) return;
  int i = gid >> 4, f = gid & 15;
  const float* hr = (i < N_GRAPH) ? (x + (size_t)i * F_IN)
                                  : (cand + (size_t)(i - N_GRAPH) * F_IN);
  double a = 0.0;
  #pragma unroll 8
  for (int k = 0; k < F_IN; ++k) a += (double)hr[k] * (double)W[k * 16 + f];
  g[gid] = (float)(a * (double)dinv[i]);
}

template <int FI, int FO>
__global__ __launch_bounds__(256) void k_mm(const float* __restrict__ H, const float* __restrict__ W,
                                            const float* __restrict__ dinv, float* __restrict__ g) {
  int gid = blockIdx.x * 256 + threadIdx.x;
  if (gid >= NT * FO) return;
  int i = gid / FO, f = gid - i * FO;
  const float* hr = H + (size_t)i * FI;
  double a = 0.0;
  #pragma unroll
  for (int k = 0; k < FI; ++k) a += (double)hr[k] * (double)W[k * FO + f];
  g[gid] = (float)(a * (double)dinv[i]);
}

// ---------------- fused CSR gather + self-loop + bias ----------------
template <int F, int R>
__global__ __launch_bounds__(F * R) void k_gcn(const int* __restrict__ rowptr,
                                               const int* __restrict__ col,
                                               const float* __restrict__ g,
                                               const float* __restrict__ dinv,
                                               const float* __restrict__ b,
                                               float* __restrict__ Hn) {
  int i = blockIdx.x * R + threadIdx.y;
  if (i >= NT) return;
  int f = threadIdx.x;
  int e0 = rowptr[i], e1 = rowptr[i + 1];
  double acc = 0.0;
  int e = e0;
  for (; e + 4 <= e1; e += 4) {
    int c0 = col[e], c1 = col[e + 1], c2 = col[e + 2], c3 = col[e + 3];
    float v0 = g[(size_t)c0 * F + f];
    float v1 = g[(size_t)c1 * F + f];
    float v2 = g[(size_t)c2 * F + f];
    float v3 = g[(size_t)c3 * F + f];
    acc += (double)v0 + (double)v1 + (double)v2 + (double)v3;
  }
  for (; e < e1; ++e) acc += (double)g[(size_t)col[e] * F + f];
  acc += (double)g[(size_t)i * F + f];
  Hn[(size_t)i * F + f] = (float)((double)dinv[i] * acc + (double)b[f]);
}

// ---------------- heads / softmax / sampling ----------------
template <int HID>
__global__ __launch_bounds__(256) void k_head(const float* __restrict__ H, const int* __restrict__ sn,
                                              int nrows,
                                              const float* __restrict__ Wa, const float* __restrict__ ba,
                                              const float* __restrict__ Wb, const float* __restrict__ bb,
                                              float* __restrict__ logits) {
  int i = blockIdx.x * 256 + threadIdx.x;
  if (i >= nrows) return;
  int row = (i < NT) ? i : sn[i - NT];
  const float* hr = H + (size_t)row * 32;
  float h[32];
  #pragma unroll
  for (int k = 0; k < 32; ++k) h[k] = hr[k];
  double hid[HID];
  for (int j = 0; j < HID; ++j) {
    double a = (double)ba[j];
    #pragma unroll
    for (int k = 0; k < 32; ++k) a += (double)h[k] * (double)Wa[k * HID + j];
    hid[j] = fmin(fmax(a, 0.0), 6.0);  // relu6
  }
  for (int t = 0; t < NTYPES; ++t) {
    double l = (double)bb[t];
    #pragma unroll
    for (int j = 0; j < HID; ++j) l += hid[j] * (double)Wb[j * NTYPES + t];
    logits[(size_t)i * NTYPES + t] = (float)l;
  }
}

__global__ __launch_bounds__(256) void k_colmax(const float* __restrict__ L, int nrows,
                                                uint32_t* __restrict__ mb) {
  __shared__ float sm[256][NTYPES];
  float m[NTYPES];
  #pragma unroll
  for (int t = 0; t < NTYPES; ++t) m[t] = -3.402823466e38f;
  for (int r = blockIdx.x * 256 + threadIdx.x; r < nrows; r += gridDim.x * 256) {
    #pragma unroll
    for (int t = 0; t < NTYPES; ++t) m[t] = fmaxf(m[t], L[(size_t)r * NTYPES + t]);
  }
  #pragma unroll
  for (int t = 0; t < NTYPES; ++t) sm[threadIdx.x][t] = m[t];
  __syncthreads();
  for (int s = 128; s > 0; s >>= 1) {
    if (threadIdx.x < s)
      for (int t = 0; t < NTYPES; ++t)
        sm[threadIdx.x][t] = fmaxf(sm[threadIdx.x][t], sm[threadIdx.x + s][t]);
    __syncthreads();
  }
  if (threadIdx.x < NTYPES) atomicMax(&mb[threadIdx.x], encf(sm[0][threadIdx.x]));
}

__global__ __launch_bounds__(256) void k_colsum(const float* __restrict__ L, int nrows,
                                                const uint32_t* __restrict__ mb,
                                                double* __restrict__ sums) {
  __shared__ double sm[256][NTYPES];
  float mx[NTYPES];
  #pragma unroll
  for (int t = 0; t < NTYPES; ++t) mx[t] = decf(mb[t]);
  double s[NTYPES];
  #pragma unroll
  for (int t = 0; t < NTYPES; ++t) s[t] = 0.0;
  for (int r = blockIdx.x * 256 + threadIdx.x; r < nrows; r += gridDim.x * 256) {
    #pragma unroll
    for (int t = 0; t < NTYPES; ++t)
      s[t] += exp((double)L[(size_t)r * NTYPES + t] - (double)mx[t]);
  }
  #pragma unroll
  for (int t = 0; t < NTYPES; ++t) sm[threadIdx.x][t] = s[t];
  __syncthreads();
  for (int st = 128; st > 0; st >>= 1) {
    if (threadIdx.x < st)
      for (int t = 0; t < NTYPES; ++t)
        sm[threadIdx.x][t] += sm[threadIdx.x + st][t];
    __syncthreads();
  }
  if (threadIdx.x < NTYPES) atomicAdd(&sums[threadIdx.x], sm[0][threadIdx.x]);
}

__global__ __launch_bounds__(256) void k_probs_start(const float* __restrict__ L,
                                                     const uint32_t* __restrict__ mb,
                                                     const double* __restrict__ sums,
                                                     float* __restrict__ P) {
  int gid = blockIdx.x * 256 + threadIdx.x;
  if (gid >= NT * NTYPES) return;
  int i = gid / NTYPES, t = gid - i * NTYPES;
  double p = exp((double)L[gid] - (double)decf(mb[t])) / sums[t];
  float pf = (float)p;
  if (i >= N_GRAPH || pf == 0.0f) pf = 1e-10f;
  P[gid] = pf;
}

__global__ __launch_bounds__(256) void k_probs_end(const float* __restrict__ L,
                                                   const uint32_t* __restrict__ mb,
                                                   const double* __restrict__ sums,
                                                   const int* __restrict__ flags,
                                                   float* __restrict__ P) {
  int gid = blockIdx.x * 256 + threadIdx.x;
  if (gid >= 2 * NT * NTYPES) return;
  int j = gid / NTYPES, t = gid - j * NTYPES;
  double p = exp((double)L[gid] - (double)decf(mb[t])) / sums[t];
  float pf = (float)p;
  if ((j < NTYPES && flags[j]) || pf == 0.0f) pf = 1e-10f;
  P[gid] = pf;
}

__global__ __launch_bounds__(256) void k_sample_start(const float* __restrict__ probs,
                                                      float* __restrict__ outSN,
                                                      int* __restrict__ sn, int* __restrict__ flags) {
  int i = blockIdx.x * 256 + threadIdx.x;
  if (i >= NT) return;
  uint32_t a0, a1, b0, b1; derive_keys(a0, a1, b0, b1);
  double best = -1e300; int bi = 0;
  #pragma unroll
  for (int t = 0; t < NTYPES; ++t) {
    uint32_t bits = rng_bits(a0, a1, (uint32_t)(i * NTYPES + t), (uint32_t)(NT * NTYPES));
    double v = log((double)probs[(size_t)i * NTYPES + t]) + gumbel_from_bits(bits);
    if (v > best) { best = v; bi = t; }
  }
  sn[i] = bi;
  outSN[i] = (float)bi;
  flags[bi] = 1;   // benign race: all writers store 1
}

__global__ __launch_bounds__(256) void k_sample_end(const float* __restrict__ probs,
                                                    float* __restrict__ outEN) {
  int j = blockIdx.x * 256 + threadIdx.x;
  if (j >= 2 * NT) return;
  uint32_t a0, a1, b0, b1; derive_keys(a0, a1, b0, b1);
  double best = -1e300; int bi = 0;
  #pragma unroll
  for (int t = 0; t < NTYPES; ++t) {
    uint32_t bits = rng_bits(b0, b1, (uint32_t)(j * NTYPES + t), (uint32_t)(2 * NT * NTYPES));
    double v = log((double)probs[(size_t)j * NTYPES + t]) + gumbel_from_bits(bits);
    if (v > best) { best = v; bi = t; }
  }
  outEN[j] = (float)bi;
}

// ---------------- host ----------------
extern "C" void kernel_launch(void* const* d_in, const int* in_sizes, int n_in,
                              void* d_out, int out_size, void* d_ws, size_t ws_size,
                              hipStream_t stream) {
  const float* x    = (const float*)d_in[0];
  const float* cand = (const float*)d_in[1];
  const int*   ei   = (const int*)d_in[2];
  const float* W1 = (const float*)d_in[4];  const float* b1 = (const float*)d_in[5];
  const float* W2 = (const float*)d_in[6];  const float* b2 = (const float*)d_in[7];
  const float* W3 = (const float*)d_in[8];  const float* b3 = (const float*)d_in[9];
  const float* Ws1 = (const float*)d_in[10]; const float* bs1 = (const float*)d_in[11];
  const float* Ws2 = (const float*)d_in[12]; const float* bs2 = (const float*)d_in[13];
  const float* We1 = (const float*)d_in[14]; const float* be1 = (const float*)d_in[15];
  const float* We2 = (const float*)d_in[16]; const float* be2 = (const float*)d_in[17];
  float* out = (float*)d_out;
  float* outSN = out;
  float* outEN = out + NT;
  float* outPS = out + 3 * NT;
  float* outPE = out + 13 * NT;

  char* ws = (char*)d_ws;
  size_t off = 0;
  auto alloc = [&](size_t bytes) -> void* {
    void* p = ws + off;
    off += (bytes + 511) & ~(size_t)511;
    return p;
  };
  int*      deg     = (int*)alloc((size_t)NT * 4);
  float*    dinv    = (float*)alloc((size_t)NT * 4);
  float*    g       = (float*)alloc((size_t)NT * 32 * 4);
  float*    Ha      = (float*)alloc((size_t)NT * 32 * 4);
  int*      rowptr  = (int*)alloc((size_t)(NT + 1) * 4);
  int*      tmp     = (int*)alloc((size_t)NT * 4);
  int*      partial = (int*)alloc(512 * 4);
  int*      bcur    = (int*)alloc((size_t)NBK * 4);
  int*      col     = (int*)alloc((size_t)NE * 4);
  // tmpent (NE*4 = 25.6 MB) aliases Hb + logitsS + logitsE (used only before layer 2)
  char*     ublk    = (char*)alloc((size_t)NE * 4);
  uint32_t* tmpent  = (uint32_t*)ublk;
  float*    Hb      = (float*)ublk;                                   // 12.8 MB
  float*    logitsS = (float*)(ublk + (size_t)NT * 32 * 4);           // 4 MB
  float*    logitsE = (float*)(ublk + (size_t)NT * 32 * 4 + (size_t)NT * NTYPES * 4); // 8 MB
  int*      sn      = (int*)alloc((size_t)NT * 4);
  uint32_t* maxS    = (uint32_t*)alloc(64);
  double*   sumS    = (double*)alloc(128);
  uint32_t* maxE    = (uint32_t*)alloc(64);
  double*   sumE    = (double*)alloc(128);
  int*      flags   = (int*)alloc(64);
  (void)ws_size; (void)in_sizes; (void)n_in; (void)out_size;

  const int* srcA = ei;
  const int* dstA = ei + NE;

  const int B = 256;
  auto blocks = [](long long nthreads) { return (int)((nthreads + 255) / 256); };

  // degrees + dinv + CSR (bucketed two-phase scatter)
  hipMemsetAsync(deg, 0, (size_t)NT * 4, stream);
  k_deg<<<blocks(NE), B, 0, stream>>>(dstA, deg);
  k_dinv<<<blocks(NT), B, 0, stream>>>(deg, dinv);
  k_scan_blocks<<<NB_SCAN, 256, 0, stream>>>(deg, tmp, partial);
  k_scan_partials<<<1, 512, 0, stream>>>(partial);
  k_scan_final<<<NB_SCAN, 256, 0, stream>>>(tmp, partial, rowptr);
  k_bcur_init<<<blocks(NBK), B, 0, stream>>>(rowptr, bcur);
  k_scatter_bucket<<<blocks(NE), B, 0, stream>>>(srcA, dstA, bcur, tmpent);
  k_bucket_place<<<NBK, 256, 0, stream>>>(rowptr, tmpent, col);

  // layer 1: 128 -> 16
  k_mm1<<<blocks((long long)NT * 16), B, 0, stream>>>(x, cand, W1, dinv, g);
  k_gcn<16, 16><<<(NT + 15) / 16, dim3(16, 16), 0, stream>>>(rowptr, col, g, dinv, b1, Ha);

  // layer 2: 16 -> 24   (tmpent dead from here; Hb/logits reuse its space)
  k_mm<16, 24><<<blocks((long long)NT * 24), B, 0, stream>>>(Ha, W2, dinv, g);
  k_gcn<24, 10><<<(NT + 9) / 10, dim3(24, 10), 0, stream>>>(rowptr, col, g, dinv, b2, Hb);

  // layer 3: 24 -> 32
  k_mm<24, 32><<<blocks((long long)NT * 32), B, 0, stream>>>(Hb, W3, dinv, g);
  k_gcn<32, 8><<<(NT + 7) / 8, dim3(32, 8), 0, stream>>>(rowptr, col, g, dinv, b3, Ha);
  // H3 = Ha

  // start head
  k_head<16><<<blocks(NT), B, 0, stream>>>(Ha, sn, NT, Ws1, bs1, Ws2, bs2, logitsS);
  hipMemsetAsync(maxS, 0, (size_t)((char*)flags - (char*)maxS) + 512, stream);
  k_colmax<<<512, B, 0, stream>>>(logitsS, NT, maxS);
  k_colsum<<<512, B, 0, stream>>>(logitsS, NT, maxS, sumS);
  k_probs_start<<<blocks((long long)NT * NTYPES), B, 0, stream>>>(logitsS, maxS, sumS, outPS);
  k_sample_start<<<blocks(NT), B, 0, stream>>>(outPS, outSN, sn, flags);

  // end head (rows: [H3; H3[sn]])
  k_head<24><<<blocks(2 * NT), B, 0, stream>>>(Ha, sn, 2 * NT, We1, be1, We2, be2, logitsE);
  k_colmax<<<512, B, 0, stream>>>(logitsE, 2 * NT, maxE);
  k_colsum<<<512, B, 0, stream>>>(logitsE, 2 * NT, maxE, sumE);
  k_probs_end<<<blocks((long long)2 * NT * NTYPES), B, 0, stream>>>(logitsE, maxE, sumE, flags, outPE);
  k_sample_end<<<blocks(2 * NT), B, 0, stream>>>(outPE, outEN);
}

// Round 4
// 1146.907 us; speedup vs baseline: 18.8157x; 1.0828x over previous
//
#include <hip/hip_runtime.h>
#include <stdint.h>

// ---------------- problem constants ----------------
constexpr int N_GRAPH = 100000;
constexpr int N_CANDS = 10;
constexpr int NT      = N_GRAPH + N_CANDS;   // 100010
constexpr int F_IN    = 128;
constexpr int NTYPES  = 10;
constexpr int NE      = 6400000;

constexpr int CB_SHIFT = 9;                   // 512 nodes per coarse bucket
constexpr int CB       = 1 << CB_SHIFT;
constexpr int NBK2     = (NT + CB - 1) / CB;  // 196
constexpr int CAP      = 48;                  // LDS queue capacity per bucket
constexpr int SCAT_BLOCKS = 256;
constexpr int PAD_SLOTS = 4096 + 16;          // sentinel headroom per bucket
constexpr int TMPENT_CAP = NE + NBK2 * PAD_SLOTS;

#define RNG_VARIANT 0

// ---------------- threefry2x32 (matches jax._src.prng) ----------------
__device__ __forceinline__ void tf2x32(uint32_t k0, uint32_t k1, uint32_t x0, uint32_t x1,
                                       uint32_t& o0, uint32_t& o1) {
  const uint32_t ks2 = k0 ^ k1 ^ 0x1BD11BDAu;
  uint32_t v0 = x0 + k0, v1 = x1 + k1;
#define TFR(r) { v0 += v1; v1 = (v1 << (r)) | (v1 >> (32 - (r))); v1 ^= v0; }
  TFR(13) TFR(15) TFR(26) TFR(6)
  v0 += k1;  v1 += ks2 + 1u;
  TFR(17) TFR(29) TFR(16) TFR(24)
  v0 += ks2; v1 += k0 + 2u;
  TFR(13) TFR(15) TFR(26) TFR(6)
  v0 += k0;  v1 += k1 + 3u;
  TFR(17) TFR(29) TFR(16) TFR(24)
  v0 += k1;  v1 += ks2 + 4u;
  TFR(13) TFR(15) TFR(26) TFR(6)
  v0 += ks2; v1 += k0 + 5u;
#undef TFR
  o0 = v0; o1 = v1;
}

__device__ __forceinline__ void derive_keys(uint32_t& a0, uint32_t& a1,
                                            uint32_t& b0, uint32_t& b1) {
#if RNG_VARIANT == 2
  uint32_t c0, c1, d0, d1;
  tf2x32(0u, 42u, 0u, 2u, c0, c1);
  tf2x32(0u, 42u, 1u, 3u, d0, d1);
  a0 = c0; a1 = d0; b0 = c1; b1 = d1;
#else
  tf2x32(0u, 42u, 0u, 0u, a0, a1);
  tf2x32(0u, 42u, 0u, 1u, b0, b1);
#endif
}

__device__ __forceinline__ uint32_t rng_bits(uint32_t k0, uint32_t k1,
                                             uint32_t idx, uint32_t total) {
#if RNG_VARIANT == 0
  uint32_t o0, o1; tf2x32(k0, k1, 0u, idx, o0, o1); return o0 ^ o1;
#elif RNG_VARIANT == 1
  uint32_t o0, o1; tf2x32(k0, k1, 0u, idx, o0, o1); return o1;
#else
  uint32_t half = total >> 1; uint32_t o0, o1;
  if (idx < half) { tf2x32(k0, k1, idx, idx + half, o0, o1); return o0; }
  tf2x32(k0, k1, idx - half, idx, o0, o1); return o1;
#endif
}

__device__ __forceinline__ double gumbel_from_bits(uint32_t bits) {
  float uf = __uint_as_float((bits >> 9) | 0x3f800000u) - 1.0f;  // [0,1)
  uf = fmaxf(1.17549435e-38f, uf + 1.17549435e-38f);
  return -log(-log((double)uf));
}

__device__ __forceinline__ uint32_t encf(float f) {
  uint32_t u = __float_as_uint(f);
  return u ^ ((u & 0x80000000u) ? 0xFFFFFFFFu : 0x80000000u);
}
__device__ __forceinline__ float decf(uint32_t e) {
  uint32_t u = (e & 0x80000000u) ? (e ^ 0x80000000u) : ~e;
  return __uint_as_float(u);
}

// ---------------- CSR build: coarse histogram -> scan -> LDS-staged scatter -> place ----------------
__global__ __launch_bounds__(256) void k_ccount(const int* __restrict__ dst, int* __restrict__ cnt) {
  __shared__ int h[NBK2];
  for (int b = threadIdx.x; b < NBK2; b += 256) h[b] = 0;
  __syncthreads();
  int per = (NE + gridDim.x - 1) / gridDim.x;
  int e0 = blockIdx.x * per, e1 = min(e0 + per, NE);
  for (int e = e0 + threadIdx.x; e < e1; e += 256) atomicAdd(&h[dst[e] >> CB_SHIFT], 1);
  __syncthreads();
  for (int b = threadIdx.x; b < NBK2; b += 256) if (h[b]) atomicAdd(&cnt[b], h[b]);
}

// single block: exclusive scans of cnt (exact, -> rowbase) and padded cap (-> cbase, ccur)
__global__ __launch_bounds__(256) void k_cscan(const int* __restrict__ cnt,
                                               int* __restrict__ cbase, int* __restrict__ ccur,
                                               int* __restrict__ rowbase) {
  __shared__ int sa[256], sb[256];
  int t = threadIdx.x;
  int c   = (t < NBK2) ? cnt[t] : 0;
  int cap = (t < NBK2) ? ((c + PAD_SLOTS + 15) & ~15) : 0;
  sa[t] = c; sb[t] = cap;
  __syncthreads();
  for (int s = 1; s < 256; s <<= 1) {
    int va = (t >= s) ? sa[t - s] : 0;
    int vb = (t >= s) ? sb[t - s] : 0;
    __syncthreads();
    sa[t] += va; sb[t] += vb;
    __syncthreads();
  }
  if (t < NBK2) {
    rowbase[t] = sa[t] - c;          // exclusive scan of exact counts
    int cb = sb[t] - cap;            // exclusive scan of padded capacities (16-aligned)
    cbase[t] = cb; ccur[t] = cb;
  }
}

// LDS-staged scatter: full 64B lines flushed by a single thread -> single-XCD, fully-dirty lines
__global__ __launch_bounds__(256) void k_scatter_lds(const int* __restrict__ src,
                                                     const int* __restrict__ dst,
                                                     int* __restrict__ ccur,
                                                     uint32_t* __restrict__ tmpent) {
  __shared__ uint32_t q[NBK2][CAP];
  __shared__ int qc[NBK2];
  int tid = threadIdx.x;
  for (int b = tid; b < NBK2; b += 256) qc[b] = 0;
  __syncthreads();
  int per = (NE + SCAT_BLOCKS - 1) / SCAT_BLOCKS;
  int e0 = blockIdx.x * per, e1 = min(e0 + per, NE);
  for (int base = e0; base < e1; base += 256) {
    int e = base + tid;
    if (e < e1) {
      int s = src[e], d = dst[e];
      int b = d >> CB_SHIFT;
      uint32_t ent = (uint32_t)s | ((uint32_t)(d & (CB - 1)) << 17);
      int pos = atomicAdd(&qc[b], 1);
      if (pos < CAP) q[b][pos] = ent;
      else tmpent[atomicAdd(&ccur[b], 1)] = ent;   // rare overflow: unit reservation
    }
    __syncthreads();
    for (int b = tid; b < NBK2; b += 256) {
      int c = qc[b]; if (c > CAP) c = CAP;
      while (c >= 16) {
        int p = atomicAdd(&ccur[b], 16);           // 16-aligned chunk -> one 64B line
        uint4* dp = (uint4*)(tmpent + p);
        const uint32_t* qq = &q[b][c - 16];
        dp[0] = make_uint4(qq[0], qq[1], qq[2], qq[3]);
        dp[1] = make_uint4(qq[4], qq[5], qq[6], qq[7]);
        dp[2] = make_uint4(qq[8], qq[9], qq[10], qq[11]);
        dp[3] = make_uint4(qq[12], qq[13], qq[14], qq[15]);
        c -= 16;
      }
      qc[b] = c;
    }
    __syncthreads();
  }
  // final flush: remainder + sentinel padding to a full line
  for (int b = tid; b < NBK2; b += 256) {
    int c = qc[b]; if (c > CAP) c = CAP;
    if (c > 0) {
      int p = atomicAdd(&ccur[b], 16);
      for (int k = 0; k < 16; ++k)
        tmpent[p + k] = (k < c) ? q[b][k] : 0xFFFFFFFFu;
    }
  }
}

// per coarse bucket: degree count -> local scan -> rowptr/dinv -> place col
__global__ __launch_bounds__(256) void k_place(const uint32_t* __restrict__ tmpent,
                                               const int* __restrict__ cbase,
                                               const int* __restrict__ ccur,
                                               const int* __restrict__ rowbase,
                                               int* __restrict__ rowptr,
                                               float* __restrict__ dinv,
                                               int* __restrict__ col) {
  __shared__ int sdeg[CB];
  __shared__ int sexc[CB];
  __shared__ int spart[256];
  int b = blockIdx.x, tid = threadIdx.x;
  for (int l = tid; l < CB; l += 256) sdeg[l] = 0;
  __syncthreads();
  int r0 = cbase[b], r1 = ccur[b];
  for (int e = r0 + tid; e < r1; e += 256) {
    uint32_t v = tmpent[e];
    if (v != 0xFFFFFFFFu) atomicAdd(&sdeg[v >> 17], 1);
  }
  __syncthreads();
  int d0 = sdeg[2 * tid], d1 = sdeg[2 * tid + 1];
  spart[tid] = d0 + d1;
  __syncthreads();
  for (int s = 1; s < 256; s <<= 1) {
    int v = (tid >= s) ? spart[tid - s] : 0;
    __syncthreads();
    spart[tid] += v;
    __syncthreads();
  }
  int epp = spart[tid] - (d0 + d1);      // exclusive prefix of this thread's pair
  int rb = rowbase[b];
  sexc[2 * tid]     = rb + epp;
  sexc[2 * tid + 1] = rb + epp + d0;
  int nbase = b * CB;
  {
    int i = nbase + 2 * tid;
    if (i < NT) {
      rowptr[i + 1] = rb + epp + d0;
      dinv[i] = (float)(1.0 / sqrt((double)(d0 + 1)));
    }
  }
  {
    int i = nbase + 2 * tid + 1;
    if (i < NT) {
      rowptr[i + 1] = rb + epp + d0 + d1;
      dinv[i] = (float)(1.0 / sqrt((double)(d1 + 1)));
    }
  }
  if (b == 0 && tid == 0) rowptr[0] = 0;
  __syncthreads();
  for (int e = r0 + tid; e < r1; e += 256) {
    uint32_t v = tmpent[e];
    if (v != 0xFFFFFFFFu) {
      int pos = atomicAdd(&sexc[v >> 17], 1);
      col[pos] = (int)(v & 0x1FFFFu);
    }
  }
}

// ---------------- dense per-node matmuls ----------------
__global__ __launch_bounds__(256) void k_mm1(const float* __restrict__ x, const float* __restrict__ cand,
                                             const float* __restrict__ W, const float* __restrict__ dinv,
                                             float* __restrict__ g) {
  int gid = blockIdx.x * 256 + threadIdx.x;
  if (gid >= NT * 16) return;
  int i = gid >> 4, f = gid & 15;
  const float* hr = (i < N_GRAPH) ? (x + (size_t)i * F_IN)
                                  : (cand + (size_t)(i - N_GRAPH) * F_IN);
  double a = 0.0;
  #pragma unroll 8
  for (int k = 0; k < F_IN; ++k) a += (double)hr[k] * (double)W[k * 16 + f];
  g[gid] = (float)(a * (double)dinv[i]);
}

template <int FI, int FO>
__global__ __launch_bounds__(256) void k_mm(const float* __restrict__ H, const float* __restrict__ W,
                                            const float* __restrict__ dinv, float* __restrict__ g) {
  int gid = blockIdx.x * 256 + threadIdx.x;
  if (gid >= NT * FO) return;
  int i = gid / FO, f = gid - i * FO;
  const float* hr = H + (size_t)i * FI;
  double a = 0.0;
  #pragma unroll
  for (int k = 0; k < FI; ++k) a += (double)hr[k] * (double)W[k * FO + f];
  g[gid] = (float)(a * (double)dinv[i]);
}

// ---------------- fused CSR gather + self-loop + bias ----------------
template <int F, int R>
__global__ __launch_bounds__(F * R) void k_gcn(const int* __restrict__ rowptr,
                                               const int* __restrict__ col,
                                               const float* __restrict__ g,
                                               const float* __restrict__ dinv,
                                               const float* __restrict__ b,
                                               float* __restrict__ Hn) {
  int i = blockIdx.x * R + threadIdx.y;
  if (i >= NT) return;
  int f = threadIdx.x;
  int e0 = rowptr[i], e1 = rowptr[i + 1];
  double acc = 0.0;
  int e = e0;
  for (; e + 4 <= e1; e += 4) {
    int c0 = col[e], c1 = col[e + 1], c2 = col[e + 2], c3 = col[e + 3];
    float v0 = g[(size_t)c0 * F + f];
    float v1 = g[(size_t)c1 * F + f];
    float v2 = g[(size_t)c2 * F + f];
    float v3 = g[(size_t)c3 * F + f];
    acc += (double)v0 + (double)v1 + (double)v2 + (double)v3;
  }
  for (; e < e1; ++e) acc += (double)g[(size_t)col[e] * F + f];
  acc += (double)g[(size_t)i * F + f];
  Hn[(size_t)i * F + f] = (float)((double)dinv[i] * acc + (double)b[f]);
}

// ---------------- heads / softmax / sampling ----------------
template <int HID>
__global__ __launch_bounds__(256) void k_head(const float* __restrict__ H, const int* __restrict__ sn,
                                              int nrows,
                                              const float* __restrict__ Wa, const float* __restrict__ ba,
                                              const float* __restrict__ Wb, const float* __restrict__ bb,
                                              float* __restrict__ logits) {
  int i = blockIdx.x * 256 + threadIdx.x;
  if (i >= nrows) return;
  int row = (i < NT) ? i : sn[i - NT];
  const float* hr = H + (size_t)row * 32;
  float h[32];
  #pragma unroll
  for (int k = 0; k < 32; ++k) h[k] = hr[k];
  double hid[HID];
  for (int j = 0; j < HID; ++j) {
    double a = (double)ba[j];
    #pragma unroll
    for (int k = 0; k < 32; ++k) a += (double)h[k] * (double)Wa[k * HID + j];
    hid[j] = fmin(fmax(a, 0.0), 6.0);  // relu6
  }
  for (int t = 0; t < NTYPES; ++t) {
    double l = (double)bb[t];
    #pragma unroll
    for (int j = 0; j < HID; ++j) l += hid[j] * (double)Wb[j * NTYPES + t];
    logits[(size_t)i * NTYPES + t] = (float)l;
  }
}

__global__ __launch_bounds__(256) void k_colmax(const float* __restrict__ L, int nrows,
                                                uint32_t* __restrict__ mb) {
  __shared__ float sm[256][NTYPES];
  float m[NTYPES];
  #pragma unroll
  for (int t = 0; t < NTYPES; ++t) m[t] = -3.402823466e38f;
  for (int r = blockIdx.x * 256 + threadIdx.x; r < nrows; r += gridDim.x * 256) {
    #pragma unroll
    for (int t = 0; t < NTYPES; ++t) m[t] = fmaxf(m[t], L[(size_t)r * NTYPES + t]);
  }
  #pragma unroll
  for (int t = 0; t < NTYPES; ++t) sm[threadIdx.x][t] = m[t];
  __syncthreads();
  for (int s = 128; s > 0; s >>= 1) {
    if (threadIdx.x < s)
      for (int t = 0; t < NTYPES; ++t)
        sm[threadIdx.x][t] = fmaxf(sm[threadIdx.x][t], sm[threadIdx.x + s][t]);
    __syncthreads();
  }
  if (threadIdx.x < NTYPES) atomicMax(&mb[threadIdx.x], encf(sm[0][threadIdx.x]));
}

__global__ __launch_bounds__(256) void k_colsum(const float* __restrict__ L, int nrows,
                                                const uint32_t* __restrict__ mb,
                                                double* __restrict__ sums) {
  __shared__ double sm[256][NTYPES];
  float mx[NTYPES];
  #pragma unroll
  for (int t = 0; t < NTYPES; ++t) mx[t] = decf(mb[t]);
  double s[NTYPES];
  #pragma unroll
  for (int t = 0; t < NTYPES; ++t) s[t] = 0.0;
  for (int r = blockIdx.x * 256 + threadIdx.x; r < nrows; r += gridDim.x * 256) {
    #pragma unroll
    for (int t = 0; t < NTYPES; ++t)
      s[t] += exp((double)L[(size_t)r * NTYPES + t] - (double)mx[t]);
  }
  #pragma unroll
  for (int t = 0; t < NTYPES; ++t) sm[threadIdx.x][t] = s[t];
  __syncthreads();
  for (int st = 128; st > 0; st >>= 1) {
    if (threadIdx.x < st)
      for (int t = 0; t < NTYPES; ++t)
        sm[threadIdx.x][t] += sm[threadIdx.x + st][t];
    __syncthreads();
  }
  if (threadIdx.x < NTYPES) atomicAdd(&sums[threadIdx.x], sm[0][threadIdx.x]);
}

__global__ __launch_bounds__(256) void k_probs_start(const float* __restrict__ L,
                                                     const uint32_t* __restrict__ mb,
                                                     const double* __restrict__ sums,
                                                     float* __restrict__ P) {
  int gid = blockIdx.x * 256 + threadIdx.x;
  if (gid >= NT * NTYPES) return;
  int i = gid / NTYPES, t = gid - i * NTYPES;
  double p = exp((double)L[gid] - (double)decf(mb[t])) / sums[t];
  float pf = (float)p;
  if (i >= N_GRAPH || pf == 0.0f) pf = 1e-10f;
  P[gid] = pf;
}

__global__ __launch_bounds__(256) void k_probs_end(const float* __restrict__ L,
                                                   const uint32_t* __restrict__ mb,
                                                   const double* __restrict__ sums,
                                                   const int* __restrict__ flags,
                                                   float* __restrict__ P) {
  int gid = blockIdx.x * 256 + threadIdx.x;
  if (gid >= 2 * NT * NTYPES) return;
  int j = gid / NTYPES, t = gid - j * NTYPES;
  double p = exp((double)L[gid] - (double)decf(mb[t])) / sums[t];
  float pf = (float)p;
  if ((j < NTYPES && flags[j]) || pf == 0.0f) pf = 1e-10f;
  P[gid] = pf;
}

__global__ __launch_bounds__(256) void k_sample_start(const float* __restrict__ probs,
                                                      float* __restrict__ outSN,
                                                      int* __restrict__ sn, int* __restrict__ flags) {
  int i = blockIdx.x * 256 + threadIdx.x;
  if (i >= NT) return;
  uint32_t a0, a1, b0, b1; derive_keys(a0, a1, b0, b1);
  double best = -1e300; int bi = 0;
  #pragma unroll
  for (int t = 0; t < NTYPES; ++t) {
    uint32_t bits = rng_bits(a0, a1, (uint32_t)(i * NTYPES + t), (uint32_t)(NT * NTYPES));
    double v = log((double)probs[(size_t)i * NTYPES + t]) + gumbel_from_bits(bits);
    if (v > best) { best = v; bi = t; }
  }
  sn[i] = bi;
  outSN[i] = (float)bi;
  flags[bi] = 1;   // benign race: all writers store 1
}

__global__ __launch_bounds__(256) void k_sample_end(const float* __restrict__ probs,
                                                    float* __restrict__ outEN) {
  int j = blockIdx.x * 256 + threadIdx.x;
  if (j >= 2 * NT) return;
  uint32_t a0, a1, b0, b1; derive_keys(a0, a1, b0, b1);
  double best = -1e300; int bi = 0;
  #pragma unroll
  for (int t = 0; t < NTYPES; ++t) {
    uint32_t bits = rng_bits(b0, b1, (uint32_t)(j * NTYPES + t), (uint32_t)(2 * NT * NTYPES));
    double v = log((double)probs[(size_t)j * NTYPES + t]) + gumbel_from_bits(bits);
    if (v > best) { best = v; bi = t; }
  }
  outEN[j] = (float)bi;
}

// ---------------- host ----------------
extern "C" void kernel_launch(void* const* d_in, const int* in_sizes, int n_in,
                              void* d_out, int out_size, void* d_ws, size_t ws_size,
                              hipStream_t stream) {
  const float* x    = (const float*)d_in[0];
  const float* cand = (const float*)d_in[1];
  const int*   ei   = (const int*)d_in[2];
  const float* W1 = (const float*)d_in[4];  const float* b1 = (const float*)d_in[5];
  const float* W2 = (const float*)d_in[6];  const float* b2 = (const float*)d_in[7];
  const float* W3 = (const float*)d_in[8];  const float* b3 = (const float*)d_in[9];
  const float* Ws1 = (const float*)d_in[10]; const float* bs1 = (const float*)d_in[11];
  const float* Ws2 = (const float*)d_in[12]; const float* bs2 = (const float*)d_in[13];
  const float* We1 = (const float*)d_in[14]; const float* be1 = (const float*)d_in[15];
  const float* We2 = (const float*)d_in[16]; const float* be2 = (const float*)d_in[17];
  float* out = (float*)d_out;
  float* outSN = out;
  float* outEN = out + NT;
  float* outPS = out + 3 * NT;
  float* outPE = out + 13 * NT;

  char* ws = (char*)d_ws;
  size_t off = 0;
  auto alloc = [&](size_t bytes) -> void* {
    void* p = ws + off;
    off += (bytes + 511) & ~(size_t)511;
    return p;
  };
  float*    dinv    = (float*)alloc((size_t)NT * 4);
  float*    g       = (float*)alloc((size_t)NT * 32 * 4);
  float*    Ha      = (float*)alloc((size_t)NT * 32 * 4);
  int*      rowptr  = (int*)alloc((size_t)(NT + 1) * 4);
  int*      cnt     = (int*)alloc((size_t)NBK2 * 4);
  int*      cbase   = (int*)alloc((size_t)NBK2 * 4);
  int*      ccur    = (int*)alloc((size_t)NBK2 * 4);
  int*      rowbase = (int*)alloc((size_t)NBK2 * 4);
  int*      col     = (int*)alloc((size_t)NE * 4);
  // tmpent (TMPENT_CAP*4 ~= 28.8 MB) aliases Hb + logitsS + logitsE (dead until layer 2)
  char*     ublk    = (char*)alloc((size_t)TMPENT_CAP * 4);
  uint32_t* tmpent  = (uint32_t*)ublk;
  float*    Hb      = (float*)ublk;                                   // 12.8 MB
  float*    logitsS = (float*)(ublk + (size_t)NT * 32 * 4);           // 4 MB
  float*    logitsE = (float*)(ublk + (size_t)NT * 32 * 4 + (size_t)NT * NTYPES * 4); // 8 MB
  int*      sn      = (int*)alloc((size_t)NT * 4);
  uint32_t* maxS    = (uint32_t*)alloc(64);
  double*   sumS    = (double*)alloc(128);
  uint32_t* maxE    = (uint32_t*)alloc(64);
  double*   sumE    = (double*)alloc(128);
  int*      flags   = (int*)alloc(64);
  (void)ws_size; (void)in_sizes; (void)n_in; (void)out_size;

  const int* srcA = ei;
  const int* dstA = ei + NE;

  const int B = 256;
  auto blocks = [](long long nthreads) { return (int)((nthreads + 255) / 256); };

  // CSR build (line-merged two-phase scatter; also produces dinv)
  hipMemsetAsync(cnt, 0, (size_t)NBK2 * 4, stream);
  k_ccount<<<256, B, 0, stream>>>(dstA, cnt);
  k_cscan<<<1, 256, 0, stream>>>(cnt, cbase, ccur, rowbase);
  k_scatter_lds<<<SCAT_BLOCKS, B, 0, stream>>>(srcA, dstA, ccur, tmpent);
  k_place<<<NBK2, B, 0, stream>>>(tmpent, cbase, ccur, rowbase, rowptr, dinv, col);

  // layer 1: 128 -> 16
  k_mm1<<<blocks((long long)NT * 16), B, 0, stream>>>(x, cand, W1, dinv, g);
  k_gcn<16, 16><<<(NT + 15) / 16, dim3(16, 16), 0, stream>>>(rowptr, col, g, dinv, b1, Ha);

  // layer 2: 16 -> 24   (tmpent dead from here; Hb/logits reuse its space)
  k_mm<16, 24><<<blocks((long long)NT * 24), B, 0, stream>>>(Ha, W2, dinv, g);
  k_gcn<24, 10><<<(NT + 9) / 10, dim3(24, 10), 0, stream>>>(rowptr, col, g, dinv, b2, Hb);

  // layer 3: 24 -> 32
  k_mm<24, 32><<<blocks((long long)NT * 32), B, 0, stream>>>(Hb, W3, dinv, g);
  k_gcn<32, 8><<<(NT + 7) / 8, dim3(32, 8), 0, stream>>>(rowptr, col, g, dinv, b3, Ha);
  // H3 = Ha

  // start head
  k_head<16><<<blocks(NT), B, 0, stream>>>(Ha, sn, NT, Ws1, bs1, Ws2, bs2, logitsS);
  hipMemsetAsync(maxS, 0, (size_t)((char*)flags - (char*)maxS) + 512, stream);
  k_colmax<<<512, B, 0, stream>>>(logitsS, NT, maxS);
  k_colsum<<<512, B, 0, stream>>>(logitsS, NT, maxS, sumS);
  k_probs_start<<<blocks((long long)NT * NTYPES), B, 0, stream>>>(logitsS, maxS, sumS, outPS);
  k_sample_start<<<blocks(NT), B, 0, stream>>>(outPS, outSN, sn, flags);

  // end head (rows: [H3; H3[sn]])
  k_head<24><<<blocks(2 * NT), B, 0, stream>>>(Ha, sn, 2 * NT, We1, be1, We2, be2, logitsE);
  k_colmax<<<512, B, 0, stream>>>(logitsE, 2 * NT, maxE);
  k_colsum<<<512, B, 0, stream>>>(logitsE, 2 * NT, maxE, sumE);
  k_probs_end<<<blocks((long long)2 * NT * NTYPES), B, 0, stream>>>(logitsE, maxE, sumE, flags, outPE);
  k_sample_end<<<blocks(2 * NT), B, 0, stream>>>(outPE, outEN);
}

// Round 5
// 1128.845 us; speedup vs baseline: 19.1167x; 1.0160x over previous
//
#include <hip/hip_runtime.h>
#include <stdint.h>

// ---------------- problem constants ----------------
constexpr int N_GRAPH = 100000;
constexpr int N_CANDS = 10;
constexpr int NT      = N_GRAPH + N_CANDS;   // 100010
constexpr int F_IN    = 128;
constexpr int NTYPES  = 10;
constexpr int NE      = 6400000;

constexpr int CB_SHIFT = 9;                   // 512 nodes per coarse bucket
constexpr int CB       = 1 << CB_SHIFT;
constexpr int NBK2     = (NT + CB - 1) / CB;  // 196
constexpr int CAP      = 48;                  // LDS queue capacity per bucket
constexpr int QSTRIDE  = 49;                  // +1 pad: break LDS bank alignment
constexpr int SCAT_BLOCKS = 1024;             // 4 blocks/CU (LDS-limited) -> ~50% occ cap
constexpr int PAD_SLOTS = SCAT_BLOCKS * 16 + 64; // final-flush sentinel headroom per bucket
constexpr int TMPENT_CAP = NE + NBK2 * (PAD_SLOTS + 16);

#define RNG_VARIANT 0

// ---------------- threefry2x32 (matches jax._src.prng) ----------------
__device__ __forceinline__ void tf2x32(uint32_t k0, uint32_t k1, uint32_t x0, uint32_t x1,
                                       uint32_t& o0, uint32_t& o1) {
  const uint32_t ks2 = k0 ^ k1 ^ 0x1BD11BDAu;
  uint32_t v0 = x0 + k0, v1 = x1 + k1;
#define TFR(r) { v0 += v1; v1 = (v1 << (r)) | (v1 >> (32 - (r))); v1 ^= v0; }
  TFR(13) TFR(15) TFR(26) TFR(6)
  v0 += k1;  v1 += ks2 + 1u;
  TFR(17) TFR(29) TFR(16) TFR(24)
  v0 += ks2; v1 += k0 + 2u;
  TFR(13) TFR(15) TFR(26) TFR(6)
  v0 += k0;  v1 += k1 + 3u;
  TFR(17) TFR(29) TFR(16) TFR(24)
  v0 += k1;  v1 += ks2 + 4u;
  TFR(13) TFR(15) TFR(26) TFR(6)
  v0 += ks2; v1 += k0 + 5u;
#undef TFR
  o0 = v0; o1 = v1;
}

__device__ __forceinline__ void derive_keys(uint32_t& a0, uint32_t& a1,
                                            uint32_t& b0, uint32_t& b1) {
#if RNG_VARIANT == 2
  uint32_t c0, c1, d0, d1;
  tf2x32(0u, 42u, 0u, 2u, c0, c1);
  tf2x32(0u, 42u, 1u, 3u, d0, d1);
  a0 = c0; a1 = d0; b0 = c1; b1 = d1;
#else
  tf2x32(0u, 42u, 0u, 0u, a0, a1);
  tf2x32(0u, 42u, 0u, 1u, b0, b1);
#endif
}

__device__ __forceinline__ uint32_t rng_bits(uint32_t k0, uint32_t k1,
                                             uint32_t idx, uint32_t total) {
#if RNG_VARIANT == 0
  uint32_t o0, o1; tf2x32(k0, k1, 0u, idx, o0, o1); return o0 ^ o1;
#elif RNG_VARIANT == 1
  uint32_t o0, o1; tf2x32(k0, k1, 0u, idx, o0, o1); return o1;
#else
  uint32_t half = total >> 1; uint32_t o0, o1;
  if (idx < half) { tf2x32(k0, k1, idx, idx + half, o0, o1); return o0; }
  tf2x32(k0, k1, idx - half, idx, o0, o1); return o1;
#endif
}

__device__ __forceinline__ double gumbel_from_bits(uint32_t bits) {
  float uf = __uint_as_float((bits >> 9) | 0x3f800000u) - 1.0f;  // [0,1)
  uf = fmaxf(1.17549435e-38f, uf + 1.17549435e-38f);
  return -log(-log((double)uf));
}

__device__ __forceinline__ uint32_t encf(float f) {
  uint32_t u = __float_as_uint(f);
  return u ^ ((u & 0x80000000u) ? 0xFFFFFFFFu : 0x80000000u);
}
__device__ __forceinline__ float decf(uint32_t e) {
  uint32_t u = (e & 0x80000000u) ? (e ^ 0x80000000u) : ~e;
  return __uint_as_float(u);
}

// ---------------- CSR build: coarse histogram -> scan -> LDS-staged scatter -> place ----------------
__global__ __launch_bounds__(256) void k_ccount(const int* __restrict__ dst, int* __restrict__ cnt) {
  __shared__ int h[NBK2];
  for (int b = threadIdx.x; b < NBK2; b += 256) h[b] = 0;
  __syncthreads();
  int per = (NE + gridDim.x - 1) / gridDim.x;
  int e0 = blockIdx.x * per, e1 = min(e0 + per, NE);
  for (int e = e0 + threadIdx.x; e < e1; e += 256) atomicAdd(&h[dst[e] >> CB_SHIFT], 1);
  __syncthreads();
  for (int b = threadIdx.x; b < NBK2; b += 256) if (h[b]) atomicAdd(&cnt[b], h[b]);
}

// single block: exclusive scans of cnt (exact, -> rowbase) and padded cap (-> cbase, ccur)
__global__ __launch_bounds__(256) void k_cscan(const int* __restrict__ cnt,
                                               int* __restrict__ cbase, int* __restrict__ ccur,
                                               int* __restrict__ rowbase) {
  __shared__ int sa[256], sb[256];
  int t = threadIdx.x;
  int c   = (t < NBK2) ? cnt[t] : 0;
  int cap = (t < NBK2) ? ((c + PAD_SLOTS + 15) & ~15) : 0;
  sa[t] = c; sb[t] = cap;
  __syncthreads();
  for (int s = 1; s < 256; s <<= 1) {
    int va = (t >= s) ? sa[t - s] : 0;
    int vb = (t >= s) ? sb[t - s] : 0;
    __syncthreads();
    sa[t] += va; sb[t] += vb;
    __syncthreads();
  }
  if (t < NBK2) {
    rowbase[t] = sa[t] - c;          // exclusive scan of exact counts
    int cb = sb[t] - cap;            // exclusive scan of padded capacities (16-aligned)
    cbase[t] = cb; ccur[t] = cb;
  }
}

// LDS-staged scatter: full 64B lines flushed by a single thread -> single-XCD, fully-dirty lines
__global__ __launch_bounds__(256) void k_scatter_lds(const int* __restrict__ src,
                                                     const int* __restrict__ dst,
                                                     int* __restrict__ ccur,
                                                     uint32_t* __restrict__ tmpent) {
  __shared__ uint32_t q[NBK2][QSTRIDE];
  __shared__ int qc[NBK2];
  int tid = threadIdx.x;
  for (int b = tid; b < NBK2; b += 256) qc[b] = 0;
  __syncthreads();
  int per = (NE + SCAT_BLOCKS - 1) / SCAT_BLOCKS;
  int e0 = blockIdx.x * per, e1 = min(e0 + per, NE);
  for (int base = e0; base < e1; base += 256) {
    int e = base + tid;
    if (e < e1) {
      int s = src[e], d = dst[e];
      int b = d >> CB_SHIFT;
      uint32_t ent = (uint32_t)s | ((uint32_t)(d & (CB - 1)) << 17);
      int pos = atomicAdd(&qc[b], 1);
      if (pos < CAP) q[b][pos] = ent;
      else {
        // rare overflow: reserve a whole line (keeps cursor 16-aligned), pad w/ sentinels
        int p = atomicAdd(&ccur[b], 16);
        tmpent[p] = ent;
        #pragma unroll
        for (int k = 1; k < 16; ++k) tmpent[p + k] = 0xFFFFFFFFu;
      }
    }
    __syncthreads();
    for (int b = tid; b < NBK2; b += 256) {
      int c = qc[b]; if (c > CAP) c = CAP;
      while (c >= 16) {
        int p = atomicAdd(&ccur[b], 16);           // 16-aligned chunk -> one 64B line
        uint4* dp = (uint4*)(tmpent + p);
        const uint32_t* qq = &q[b][c - 16];
        dp[0] = make_uint4(qq[0], qq[1], qq[2], qq[3]);
        dp[1] = make_uint4(qq[4], qq[5], qq[6], qq[7]);
        dp[2] = make_uint4(qq[8], qq[9], qq[10], qq[11]);
        dp[3] = make_uint4(qq[12], qq[13], qq[14], qq[15]);
        c -= 16;
      }
      qc[b] = c;
    }
    __syncthreads();
  }
  // final flush: remainder + sentinel padding to a full line
  for (int b = tid; b < NBK2; b += 256) {
    int c = qc[b]; if (c > CAP) c = CAP;
    if (c > 0) {
      int p = atomicAdd(&ccur[b], 16);
      for (int k = 0; k < 16; ++k)
        tmpent[p + k] = (k < c) ? q[b][k] : 0xFFFFFFFFu;
    }
  }
}

// per coarse bucket (512 threads): degree count -> local scan -> rowptr/dinv -> place col
__global__ __launch_bounds__(512) void k_place(const uint32_t* __restrict__ tmpent,
                                               const int* __restrict__ cbase,
                                               const int* __restrict__ ccur,
                                               const int* __restrict__ rowbase,
                                               int* __restrict__ rowptr,
                                               float* __restrict__ dinv,
                                               int* __restrict__ col) {
  __shared__ int sdeg[CB];
  __shared__ int sexc[CB];
  __shared__ int sscan[CB];
  int b = blockIdx.x, tid = threadIdx.x;
  sdeg[tid] = 0;
  __syncthreads();
  int r0 = cbase[b], r1 = ccur[b];
  for (int e = r0 + tid; e < r1; e += 512) {
    uint32_t v = tmpent[e];
    if (v != 0xFFFFFFFFu) atomicAdd(&sdeg[v >> 17], 1);
  }
  __syncthreads();
  int d = sdeg[tid];
  sscan[tid] = d;
  __syncthreads();
  #pragma unroll
  for (int s = 1; s < CB; s <<= 1) {
    int v = (tid >= s) ? sscan[tid - s] : 0;
    __syncthreads();
    sscan[tid] += v;
    __syncthreads();
  }
  int rb = rowbase[b];
  int incl = rb + sscan[tid];            // inclusive
  sexc[tid] = incl - d;                  // exclusive
  int i = b * CB + tid;
  if (i < NT) {
    rowptr[i + 1] = incl;
    dinv[i] = (float)(1.0 / sqrt((double)(d + 1)));
  }
  if (b == 0 && tid == 0) rowptr[0] = 0;
  __syncthreads();
  for (int e = r0 + tid; e < r1; e += 512) {
    uint32_t v = tmpent[e];
    if (v != 0xFFFFFFFFu) {
      int pos = atomicAdd(&sexc[v >> 17], 1);
      col[pos] = (int)(v & 0x1FFFFu);
    }
  }
}

// ---------------- dense per-node matmuls ----------------
__global__ __launch_bounds__(256) void k_mm1(const float* __restrict__ x, const float* __restrict__ cand,
                                             const float* __restrict__ W, const float* __restrict__ dinv,
                                             float* __restrict__ g) {
  int gid = blockIdx.x * 256 + threadIdx.x;
  if (gid >= NT * 16) return;
  int i = gid >> 4, f = gid & 15;
  const float* hr = (i < N_GRAPH) ? (x + (size_t)i * F_IN)
                                  : (cand + (size_t)(i - N_GRAPH) * F_IN);
  double a = 0.0;
  #pragma unroll 8
  for (int k = 0; k < F_IN; ++k) a += (double)hr[k] * (double)W[k * 16 + f];
  g[gid] = (float)(a * (double)dinv[i]);
}

template <int FI, int FO>
__global__ __launch_bounds__(256) void k_mm(const float* __restrict__ H, const float* __restrict__ W,
                                            const float* __restrict__ dinv, float* __restrict__ g) {
  int gid = blockIdx.x * 256 + threadIdx.x;
  if (gid >= NT * FO) return;
  int i = gid / FO, f = gid - i * FO;
  const float* hr = H + (size_t)i * FI;
  double a = 0.0;
  #pragma unroll
  for (int k = 0; k < FI; ++k) a += (double)hr[k] * (double)W[k * FO + f];
  g[gid] = (float)(a * (double)dinv[i]);
}

// ---------------- fused CSR gather + self-loop + bias ----------------
template <int F, int R>
__global__ __launch_bounds__(F * R) void k_gcn(const int* __restrict__ rowptr,
                                               const int* __restrict__ col,
                                               const float* __restrict__ g,
                                               const float* __restrict__ dinv,
                                               const float* __restrict__ b,
                                               float* __restrict__ Hn) {
  int i = blockIdx.x * R + threadIdx.y;
  if (i >= NT) return;
  int f = threadIdx.x;
  int e0 = rowptr[i], e1 = rowptr[i + 1];
  double acc = 0.0;
  int e = e0;
  for (; e + 4 <= e1; e += 4) {
    int c0 = col[e], c1 = col[e + 1], c2 = col[e + 2], c3 = col[e + 3];
    float v0 = g[(size_t)c0 * F + f];
    float v1 = g[(size_t)c1 * F + f];
    float v2 = g[(size_t)c2 * F + f];
    float v3 = g[(size_t)c3 * F + f];
    acc += (double)v0 + (double)v1 + (double)v2 + (double)v3;
  }
  for (; e < e1; ++e) acc += (double)g[(size_t)col[e] * F + f];
  acc += (double)g[(size_t)i * F + f];
  Hn[(size_t)i * F + f] = (float)((double)dinv[i] * acc + (double)b[f]);
}

// ---------------- heads / softmax / sampling ----------------
template <int HID>
__global__ __launch_bounds__(256) void k_head(const float* __restrict__ H, const int* __restrict__ sn,
                                              int nrows,
                                              const float* __restrict__ Wa, const float* __restrict__ ba,
                                              const float* __restrict__ Wb, const float* __restrict__ bb,
                                              float* __restrict__ logits) {
  int i = blockIdx.x * 256 + threadIdx.x;
  if (i >= nrows) return;
  int row = (i < NT) ? i : sn[i - NT];
  const float* hr = H + (size_t)row * 32;
  float h[32];
  #pragma unroll
  for (int k = 0; k < 32; ++k) h[k] = hr[k];
  double hid[HID];
  for (int j = 0; j < HID; ++j) {
    double a = (double)ba[j];
    #pragma unroll
    for (int k = 0; k < 32; ++k) a += (double)h[k] * (double)Wa[k * HID + j];
    hid[j] = fmin(fmax(a, 0.0), 6.0);  // relu6
  }
  for (int t = 0; t < NTYPES; ++t) {
    double l = (double)bb[t];
    #pragma unroll
    for (int j = 0; j < HID; ++j) l += hid[j] * (double)Wb[j * NTYPES + t];
    logits[(size_t)i * NTYPES + t] = (float)l;
  }
}

__global__ __launch_bounds__(256) void k_colmax(const float* __restrict__ L, int nrows,
                                                uint32_t* __restrict__ mb) {
  __shared__ float sm[256][NTYPES];
  float m[NTYPES];
  #pragma unroll
  for (int t = 0; t < NTYPES; ++t) m[t] = -3.402823466e38f;
  for (int r = blockIdx.x * 256 + threadIdx.x; r < nrows; r += gridDim.x * 256) {
    #pragma unroll
    for (int t = 0; t < NTYPES; ++t) m[t] = fmaxf(m[t], L[(size_t)r * NTYPES + t]);
  }
  #pragma unroll
  for (int t = 0; t < NTYPES; ++t) sm[threadIdx.x][t] = m[t];
  __syncthreads();
  for (int s = 128; s > 0; s >>= 1) {
    if (threadIdx.x < s)
      for (int t = 0; t < NTYPES; ++t)
        sm[threadIdx.x][t] = fmaxf(sm[threadIdx.x][t], sm[threadIdx.x + s][t]);
    __syncthreads();
  }
  if (threadIdx.x < NTYPES) atomicMax(&mb[threadIdx.x], encf(sm[0][threadIdx.x]));
}

__global__ __launch_bounds__(256) void k_colsum(const float* __restrict__ L, int nrows,
                                                const uint32_t* __restrict__ mb,
                                                double* __restrict__ sums) {
  __shared__ double sm[256][NTYPES];
  float mx[NTYPES];
  #pragma unroll
  for (int t = 0; t < NTYPES; ++t) mx[t] = decf(mb[t]);
  double s[NTYPES];
  #pragma unroll
  for (int t = 0; t < NTYPES; ++t) s[t] = 0.0;
  for (int r = blockIdx.x * 256 + threadIdx.x; r < nrows; r += gridDim.x * 256) {
    #pragma unroll
    for (int t = 0; t < NTYPES; ++t)
      s[t] += exp((double)L[(size_t)r * NTYPES + t] - (double)mx[t]);
  }
  #pragma unroll
  for (int t = 0; t < NTYPES; ++t) sm[threadIdx.x][t] = s[t];
  __syncthreads();
  for (int st = 128; st > 0; st >>= 1) {
    if (threadIdx.x < st)
      for (int t = 0; t < NTYPES; ++t)
        sm[threadIdx.x][t] += sm[threadIdx.x + st][t];
    __syncthreads();
  }
  if (threadIdx.x < NTYPES) atomicAdd(&sums[threadIdx.x], sm[0][threadIdx.x]);
}

__global__ __launch_bounds__(256) void k_probs_start(const float* __restrict__ L,
                                                     const uint32_t* __restrict__ mb,
                                                     const double* __restrict__ sums,
                                                     float* __restrict__ P) {
  int gid = blockIdx.x * 256 + threadIdx.x;
  if (gid >= NT * NTYPES) return;
  int i = gid / NTYPES, t = gid - i * NTYPES;
  double p = exp((double)L[gid] - (double)decf(mb[t])) / sums[t];
  float pf = (float)p;
  if (i >= N_GRAPH || pf == 0.0f) pf = 1e-10f;
  P[gid] = pf;
}

__global__ __launch_bounds__(256) void k_probs_end(const float* __restrict__ L,
                                                   const uint32_t* __restrict__ mb,
                                                   const double* __restrict__ sums,
                                                   const int* __restrict__ flags,
                                                   float* __restrict__ P) {
  int gid = blockIdx.x * 256 + threadIdx.x;
  if (gid >= 2 * NT * NTYPES) return;
  int j = gid / NTYPES, t = gid - j * NTYPES;
  double p = exp((double)L[gid] - (double)decf(mb[t])) / sums[t];
  float pf = (float)p;
  if ((j < NTYPES && flags[j]) || pf == 0.0f) pf = 1e-10f;
  P[gid] = pf;
}

__global__ __launch_bounds__(256) void k_sample_start(const float* __restrict__ probs,
                                                      float* __restrict__ outSN,
                                                      int* __restrict__ sn, int* __restrict__ flags) {
  int i = blockIdx.x * 256 + threadIdx.x;
  if (i >= NT) return;
  uint32_t a0, a1, b0, b1; derive_keys(a0, a1, b0, b1);
  double best = -1e300; int bi = 0;
  #pragma unroll
  for (int t = 0; t < NTYPES; ++t) {
    uint32_t bits = rng_bits(a0, a1, (uint32_t)(i * NTYPES + t), (uint32_t)(NT * NTYPES));
    double v = log((double)probs[(size_t)i * NTYPES + t]) + gumbel_from_bits(bits);
    if (v > best) { best = v; bi = t; }
  }
  sn[i] = bi;
  outSN[i] = (float)bi;
  flags[bi] = 1;   // benign race: all writers store 1
}

__global__ __launch_bounds__(256) void k_sample_end(const float* __restrict__ probs,
                                                    float* __restrict__ outEN) {
  int j = blockIdx.x * 256 + threadIdx.x;
  if (j >= 2 * NT) return;
  uint32_t a0, a1, b0, b1; derive_keys(a0, a1, b0, b1);
  double best = -1e300; int bi = 0;
  #pragma unroll
  for (int t = 0; t < NTYPES; ++t) {
    uint32_t bits = rng_bits(b0, b1, (uint32_t)(j * NTYPES + t), (uint32_t)(2 * NT * NTYPES));
    double v = log((double)probs[(size_t)j * NTYPES + t]) + gumbel_from_bits(bits);
    if (v > best) { best = v; bi = t; }
  }
  outEN[j] = (float)bi;
}

// ---------------- host ----------------
extern "C" void kernel_launch(void* const* d_in, const int* in_sizes, int n_in,
                              void* d_out, int out_size, void* d_ws, size_t ws_size,
                              hipStream_t stream) {
  const float* x    = (const float*)d_in[0];
  const float* cand = (const float*)d_in[1];
  const int*   ei   = (const int*)d_in[2];
  const float* W1 = (const float*)d_in[4];  const float* b1 = (const float*)d_in[5];
  const float* W2 = (const float*)d_in[6];  const float* b2 = (const float*)d_in[7];
  const float* W3 = (const float*)d_in[8];  const float* b3 = (const float*)d_in[9];
  const float* Ws1 = (const float*)d_in[10]; const float* bs1 = (const float*)d_in[11];
  const float* Ws2 = (const float*)d_in[12]; const float* bs2 = (const float*)d_in[13];
  const float* We1 = (const float*)d_in[14]; const float* be1 = (const float*)d_in[15];
  const float* We2 = (const float*)d_in[16]; const float* be2 = (const float*)d_in[17];
  float* out = (float*)d_out;
  float* outSN = out;
  float* outEN = out + NT;
  float* outPS = out + 3 * NT;
  float* outPE = out + 13 * NT;

  char* ws = (char*)d_ws;
  size_t off = 0;
  auto alloc = [&](size_t bytes) -> void* {
    void* p = ws + off;
    off += (bytes + 511) & ~(size_t)511;
    return p;
  };
  float*    dinv    = (float*)alloc((size_t)NT * 4);
  float*    g       = (float*)alloc((size_t)NT * 32 * 4);
  float*    Ha      = (float*)alloc((size_t)NT * 32 * 4);
  int*      rowptr  = (int*)alloc((size_t)(NT + 1) * 4);
  int*      cnt     = (int*)alloc((size_t)NBK2 * 4);
  int*      cbase   = (int*)alloc((size_t)NBK2 * 4);
  int*      ccur    = (int*)alloc((size_t)NBK2 * 4);
  int*      rowbase = (int*)alloc((size_t)NBK2 * 4);
  int*      col     = (int*)alloc((size_t)NE * 4);
  // tmpent (~38.5 MB) aliases Hb + logitsS + logitsE (dead until layer 2)
  char*     ublk    = (char*)alloc((size_t)TMPENT_CAP * 4);
  uint32_t* tmpent  = (uint32_t*)ublk;
  float*    Hb      = (float*)ublk;                                   // 12.8 MB
  float*    logitsS = (float*)(ublk + (size_t)NT * 32 * 4);           // 4 MB
  float*    logitsE = (float*)(ublk + (size_t)NT * 32 * 4 + (size_t)NT * NTYPES * 4); // 8 MB
  int*      sn      = (int*)alloc((size_t)NT * 4);
  uint32_t* maxS    = (uint32_t*)alloc(64);
  double*   sumS    = (double*)alloc(128);
  uint32_t* maxE    = (uint32_t*)alloc(64);
  double*   sumE    = (double*)alloc(128);
  int*      flags   = (int*)alloc(64);
  (void)ws_size; (void)in_sizes; (void)n_in; (void)out_size;

  const int* srcA = ei;
  const int* dstA = ei + NE;

  const int B = 256;
  auto blocks = [](long long nthreads) { return (int)((nthreads + 255) / 256); };

  // CSR build (line-merged two-phase scatter; also produces dinv)
  hipMemsetAsync(cnt, 0, (size_t)NBK2 * 4, stream);
  k_ccount<<<512, B, 0, stream>>>(dstA, cnt);
  k_cscan<<<1, 256, 0, stream>>>(cnt, cbase, ccur, rowbase);
  k_scatter_lds<<<SCAT_BLOCKS, B, 0, stream>>>(srcA, dstA, ccur, tmpent);
  k_place<<<NBK2, 512, 0, stream>>>(tmpent, cbase, ccur, rowbase, rowptr, dinv, col);

  // layer 1: 128 -> 16
  k_mm1<<<blocks((long long)NT * 16), B, 0, stream>>>(x, cand, W1, dinv, g);
  k_gcn<16, 16><<<(NT + 15) / 16, dim3(16, 16), 0, stream>>>(rowptr, col, g, dinv, b1, Ha);

  // layer 2: 16 -> 24   (tmpent dead from here; Hb/logits reuse its space)
  k_mm<16, 24><<<blocks((long long)NT * 24), B, 0, stream>>>(Ha, W2, dinv, g);
  k_gcn<24, 10><<<(NT + 9) / 10, dim3(24, 10), 0, stream>>>(rowptr, col, g, dinv, b2, Hb);

  // layer 3: 24 -> 32
  k_mm<24, 32><<<blocks((long long)NT * 32), B, 0, stream>>>(Hb, W3, dinv, g);
  k_gcn<32, 8><<<(NT + 7) / 8, dim3(32, 8), 0, stream>>>(rowptr, col, g, dinv, b3, Ha);
  // H3 = Ha

  // start head
  k_head<16><<<blocks(NT), B, 0, stream>>>(Ha, sn, NT, Ws1, bs1, Ws2, bs2, logitsS);
  hipMemsetAsync(maxS, 0, (size_t)((char*)flags - (char*)maxS) + 512, stream);
  k_colmax<<<512, B, 0, stream>>>(logitsS, NT, maxS);
  k_colsum<<<512, B, 0, stream>>>(logitsS, NT, maxS, sumS);
  k_probs_start<<<blocks((long long)NT * NTYPES), B, 0, stream>>>(logitsS, maxS, sumS, outPS);
  k_sample_start<<<blocks(NT), B, 0, stream>>>(outPS, outSN, sn, flags);

  // end head (rows: [H3; H3[sn]])
  k_head<24><<<blocks(2 * NT), B, 0, stream>>>(Ha, sn, 2 * NT, We1, be1, We2, be2, logitsE);
  k_colmax<<<512, B, 0, stream>>>(logitsE, 2 * NT, maxE);
  k_colsum<<<512, B, 0, stream>>>(logitsE, 2 * NT, maxE, sumE);
  k_probs_end<<<blocks((long long)2 * NT * NTYPES), B, 0, stream>>>(logitsE, maxE, sumE, flags, outPE);
  k_sample_end<<<blocks(2 * NT), B, 0, stream>>>(outPE, outEN);
}

// Round 6
// 825.467 us; speedup vs baseline: 26.1426x; 1.3675x over previous
//
#include <hip/hip_runtime.h>
#include <stdint.h>

// ---------------- problem constants ----------------
constexpr int N_GRAPH = 100000;
constexpr int N_CANDS = 10;
constexpr int NT      = N_GRAPH + N_CANDS;   // 100010
constexpr int F_IN    = 128;
constexpr int NTYPES  = 10;
constexpr int NE      = 6400000;

constexpr int CB_SHIFT = 9;                   // 512 nodes per coarse bucket
constexpr int CB       = 1 << CB_SHIFT;
constexpr int NBK2     = (NT + CB - 1) / CB;  // 196
constexpr int SB       = 512;                 // scatter blocks (also bcount blocks)
constexpr int NMAT     = NBK2 * SB;           // 100352 (scan matrix size)
constexpr int NSCAN_B  = NMAT / 256;          // 392 scan blocks
constexpr int TMPENT_CAP = NE + NMAT * 15 + 16;  // all regions padded to 16 slots

#define RNG_VARIANT 0

// ---------------- threefry2x32 (matches jax._src.prng) ----------------
__device__ __forceinline__ void tf2x32(uint32_t k0, uint32_t k1, uint32_t x0, uint32_t x1,
                                       uint32_t& o0, uint32_t& o1) {
  const uint32_t ks2 = k0 ^ k1 ^ 0x1BD11BDAu;
  uint32_t v0 = x0 + k0, v1 = x1 + k1;
#define TFR(r) { v0 += v1; v1 = (v1 << (r)) | (v1 >> (32 - (r))); v1 ^= v0; }
  TFR(13) TFR(15) TFR(26) TFR(6)
  v0 += k1;  v1 += ks2 + 1u;
  TFR(17) TFR(29) TFR(16) TFR(24)
  v0 += ks2; v1 += k0 + 2u;
  TFR(13) TFR(15) TFR(26) TFR(6)
  v0 += k0;  v1 += k1 + 3u;
  TFR(17) TFR(29) TFR(16) TFR(24)
  v0 += k1;  v1 += ks2 + 4u;
  TFR(13) TFR(15) TFR(26) TFR(6)
  v0 += ks2; v1 += k0 + 5u;
#undef TFR
  o0 = v0; o1 = v1;
}

__device__ __forceinline__ void derive_keys(uint32_t& a0, uint32_t& a1,
                                            uint32_t& b0, uint32_t& b1) {
#if RNG_VARIANT == 2
  uint32_t c0, c1, d0, d1;
  tf2x32(0u, 42u, 0u, 2u, c0, c1);
  tf2x32(0u, 42u, 1u, 3u, d0, d1);
  a0 = c0; a1 = d0; b0 = c1; b1 = d1;
#else
  tf2x32(0u, 42u, 0u, 0u, a0, a1);
  tf2x32(0u, 42u, 0u, 1u, b0, b1);
#endif
}

__device__ __forceinline__ uint32_t rng_bits(uint32_t k0, uint32_t k1,
                                             uint32_t idx, uint32_t total) {
#if RNG_VARIANT == 0
  uint32_t o0, o1; tf2x32(k0, k1, 0u, idx, o0, o1); return o0 ^ o1;
#elif RNG_VARIANT == 1
  uint32_t o0, o1; tf2x32(k0, k1, 0u, idx, o0, o1); return o1;
#else
  uint32_t half = total >> 1; uint32_t o0, o1;
  if (idx < half) { tf2x32(k0, k1, idx, idx + half, o0, o1); return o0; }
  tf2x32(k0, k1, idx - half, idx, o0, o1); return o1;
#endif
}

__device__ __forceinline__ double gumbel_from_bits(uint32_t bits) {
  float uf = __uint_as_float((bits >> 9) | 0x3f800000u) - 1.0f;  // [0,1)
  uf = fmaxf(1.17549435e-38f, uf + 1.17549435e-38f);
  return -log(-log((double)uf));
}

__device__ __forceinline__ uint32_t encf(float f) {
  uint32_t u = __float_as_uint(f);
  return u ^ ((u & 0x80000000u) ? 0xFFFFFFFFu : 0x80000000u);
}
__device__ __forceinline__ float decf(uint32_t e) {
  uint32_t u = (e & 0x80000000u) ? (e ^ 0x80000000u) : ~e;
  return __uint_as_float(u);
}

// ---------------- CSR build ----------------
// pass 1: per-block coarse histogram -> padded cntmat (bucket-major) + exact cnt
__global__ __launch_bounds__(512) void k_bcount(const int* __restrict__ dst,
                                                int* __restrict__ cntmat,
                                                int* __restrict__ cnt) {
  __shared__ int h[NBK2];
  int tid = threadIdx.x, blk = blockIdx.x;
  for (int b = tid; b < NBK2; b += 512) h[b] = 0;
  __syncthreads();
  int per = (NE + SB - 1) / SB;
  int e0 = blk * per, e1 = min(e0 + per, NE);
  for (int e = e0 + tid; e < e1; e += 512) atomicAdd(&h[dst[e] >> CB_SHIFT], 1);
  __syncthreads();
  for (int b = tid; b < NBK2; b += 512) {
    int c = h[b];
    cntmat[b * SB + blk] = (c + 15) & ~15;     // 16-slot (64B) aligned region
    if (c) atomicAdd(&cnt[b], c);
  }
}

// hierarchical exclusive scan of cmat[NMAT] in place; cmat[NMAT] = total
__global__ __launch_bounds__(256) void k_s1(int* __restrict__ cmat, int* __restrict__ partial) {
  __shared__ int sm[256];
  int t = blockIdx.x * 256 + threadIdx.x;
  int v = cmat[t];
  sm[threadIdx.x] = v;
  __syncthreads();
  #pragma unroll
  for (int s = 1; s < 256; s <<= 1) {
    int a = (threadIdx.x >= s) ? sm[threadIdx.x - s] : 0;
    __syncthreads();
    sm[threadIdx.x] += a;
    __syncthreads();
  }
  cmat[t] = sm[threadIdx.x] - v;               // block-local exclusive
  if (threadIdx.x == 255) partial[blockIdx.x] = sm[255];
}

__global__ __launch_bounds__(512) void k_s2(int* __restrict__ partial, int* __restrict__ cmat) {
  __shared__ int sm[512];
  int t = threadIdx.x;
  int v = (t < NSCAN_B) ? partial[t] : 0;
  sm[t] = v;
  __syncthreads();
  #pragma unroll
  for (int s = 1; s < 512; s <<= 1) {
    int a = (t >= s) ? sm[t - s] : 0;
    __syncthreads();
    sm[t] += a;
    __syncthreads();
  }
  if (t < NSCAN_B) partial[t] = sm[t] - v;     // exclusive
  if (t == 511) cmat[NMAT] = sm[511];          // grand total
}

__global__ __launch_bounds__(256) void k_s3(int* __restrict__ cmat, const int* __restrict__ partial) {
  int t = blockIdx.x * 256 + threadIdx.x;
  cmat[t] += partial[blockIdx.x];
}

// exclusive scan of exact bucket counts -> rowbase
__global__ __launch_bounds__(256) void k_rowscan(const int* __restrict__ cnt,
                                                 int* __restrict__ rowbase) {
  __shared__ int sm[256];
  int t = threadIdx.x;
  int v = (t < NBK2) ? cnt[t] : 0;
  sm[t] = v;
  __syncthreads();
  #pragma unroll
  for (int s = 1; s < 256; s <<= 1) {
    int a = (t >= s) ? sm[t - s] : 0;
    __syncthreads();
    sm[t] += a;
    __syncthreads();
  }
  if (t < NBK2) rowbase[t] = sm[t] - v;
}

// pass 2: barrier-free scatter into block-private line-aligned regions
__global__ __launch_bounds__(512) void k_scatter2(const int* __restrict__ src,
                                                  const int* __restrict__ dst,
                                                  const int* __restrict__ cmat,
                                                  uint32_t* __restrict__ tmpent) {
  __shared__ int lcur[NBK2];
  int tid = threadIdx.x, blk = blockIdx.x;
  for (int b = tid; b < NBK2; b += 512) lcur[b] = cmat[b * SB + blk];
  __syncthreads();
  int per = (NE + SB - 1) / SB;
  int e0 = blk * per, e1 = min(e0 + per, NE);
  for (int e = e0 + tid; e < e1; e += 512) {
    int s = src[e], d = dst[e];
    int b = d >> CB_SHIFT;
    int pos = atomicAdd(&lcur[b], 1);
    tmpent[pos] = (uint32_t)s | ((uint32_t)(d & (CB - 1)) << 17);
  }
  __syncthreads();
  // sentinel-fill this block's region tails (region end = next region start)
  for (int b = tid; b < NBK2; b += 512) {
    int p = lcur[b];
    int end = cmat[b * SB + blk + 1];   // blk=SB-1 rolls into next bucket; cmat[NMAT]=total
    for (; p < end; ++p) tmpent[p] = 0xFFFFFFFFu;
  }
}

// per coarse bucket (512 threads): degree count -> local scan -> rowptr/dinv -> place col
__global__ __launch_bounds__(512) void k_place(const uint32_t* __restrict__ tmpent,
                                               const int* __restrict__ cmat,
                                               const int* __restrict__ rowbase,
                                               int* __restrict__ rowptr,
                                               float* __restrict__ dinv,
                                               int* __restrict__ col) {
  __shared__ int sdeg[CB];
  __shared__ int sexc[CB];
  __shared__ int sscan[CB];
  int b = blockIdx.x, tid = threadIdx.x;
  sdeg[tid] = 0;
  __syncthreads();
  int r0 = cmat[b * SB], r1 = cmat[(b + 1) * SB];
  for (int e = r0 + tid; e < r1; e += 512) {
    uint32_t v = tmpent[e];
    if (v != 0xFFFFFFFFu) atomicAdd(&sdeg[v >> 17], 1);
  }
  __syncthreads();
  int d = sdeg[tid];
  sscan[tid] = d;
  __syncthreads();
  #pragma unroll
  for (int s = 1; s < CB; s <<= 1) {
    int v = (tid >= s) ? sscan[tid - s] : 0;
    __syncthreads();
    sscan[tid] += v;
    __syncthreads();
  }
  int rb = rowbase[b];
  int incl = rb + sscan[tid];            // inclusive
  sexc[tid] = incl - d;                  // exclusive
  int i = b * CB + tid;
  if (i < NT) {
    rowptr[i + 1] = incl;
    dinv[i] = (float)(1.0 / sqrt((double)(d + 1)));
  }
  if (b == 0 && tid == 0) rowptr[0] = 0;
  __syncthreads();
  for (int e = r0 + tid; e < r1; e += 512) {
    uint32_t v = tmpent[e];
    if (v != 0xFFFFFFFFu) {
      int pos = atomicAdd(&sexc[v >> 17], 1);
      col[pos] = (int)(v & 0x1FFFFu);
    }
  }
}

// ---------------- dense per-node matmuls ----------------
__global__ __launch_bounds__(256) void k_mm1(const float* __restrict__ x, const float* __restrict__ cand,
                                             const float* __restrict__ W, const float* __restrict__ dinv,
                                             float* __restrict__ g) {
  int gid = blockIdx.x * 256 + threadIdx.x;
  if (gid >= NT * 16) return;
  int i = gid >> 4, f = gid & 15;
  const float* hr = (i < N_GRAPH) ? (x + (size_t)i * F_IN)
                                  : (cand + (size_t)(i - N_GRAPH) * F_IN);
  double a = 0.0;
  #pragma unroll 8
  for (int k = 0; k < F_IN; ++k) a += (double)hr[k] * (double)W[k * 16 + f];
  g[gid] = (float)(a * (double)dinv[i]);
}

template <int FI, int FO>
__global__ __launch_bounds__(256) void k_mm(const float* __restrict__ H, const float* __restrict__ W,
                                            const float* __restrict__ dinv, float* __restrict__ g) {
  int gid = blockIdx.x * 256 + threadIdx.x;
  if (gid >= NT * FO) return;
  int i = gid / FO, f = gid - i * FO;
  const float* hr = H + (size_t)i * FI;
  double a = 0.0;
  #pragma unroll
  for (int k = 0; k < FI; ++k) a += (double)hr[k] * (double)W[k * FO + f];
  g[gid] = (float)(a * (double)dinv[i]);
}

// ---------------- fused CSR gather + self-loop + bias ----------------
template <int F, int R>
__global__ __launch_bounds__(F * R) void k_gcn(const int* __restrict__ rowptr,
                                               const int* __restrict__ col,
                                               const float* __restrict__ g,
                                               const float* __restrict__ dinv,
                                               const float* __restrict__ b,
                                               float* __restrict__ Hn) {
  int i = blockIdx.x * R + threadIdx.y;
  if (i >= NT) return;
  int f = threadIdx.x;
  int e0 = rowptr[i], e1 = rowptr[i + 1];
  double acc = 0.0;
  int e = e0;
  for (; e + 4 <= e1; e += 4) {
    int c0 = col[e], c1 = col[e + 1], c2 = col[e + 2], c3 = col[e + 3];
    float v0 = g[(size_t)c0 * F + f];
    float v1 = g[(size_t)c1 * F + f];
    float v2 = g[(size_t)c2 * F + f];
    float v3 = g[(size_t)c3 * F + f];
    acc += (double)v0 + (double)v1 + (double)v2 + (double)v3;
  }
  for (; e < e1; ++e) acc += (double)g[(size_t)col[e] * F + f];
  acc += (double)g[(size_t)i * F + f];
  Hn[(size_t)i * F + f] = (float)((double)dinv[i] * acc + (double)b[f]);
}

// ---------------- heads / softmax / sampling ----------------
template <int HID>
__global__ __launch_bounds__(256) void k_head(const float* __restrict__ H, const int* __restrict__ sn,
                                              int nrows,
                                              const float* __restrict__ Wa, const float* __restrict__ ba,
                                              const float* __restrict__ Wb, const float* __restrict__ bb,
                                              float* __restrict__ logits) {
  int i = blockIdx.x * 256 + threadIdx.x;
  if (i >= nrows) return;
  int row = (i < NT) ? i : sn[i - NT];
  const float* hr = H + (size_t)row * 32;
  float h[32];
  #pragma unroll
  for (int k = 0; k < 32; ++k) h[k] = hr[k];
  double hid[HID];
  for (int j = 0; j < HID; ++j) {
    double a = (double)ba[j];
    #pragma unroll
    for (int k = 0; k < 32; ++k) a += (double)h[k] * (double)Wa[k * HID + j];
    hid[j] = fmin(fmax(a, 0.0), 6.0);  // relu6
  }
  for (int t = 0; t < NTYPES; ++t) {
    double l = (double)bb[t];
    #pragma unroll
    for (int j = 0; j < HID; ++j) l += hid[j] * (double)Wb[j * NTYPES + t];
    logits[(size_t)i * NTYPES + t] = (float)l;
  }
}

__global__ __launch_bounds__(256) void k_colmax(const float* __restrict__ L, int nrows,
                                                uint32_t* __restrict__ mb) {
  __shared__ float sm[256][NTYPES];
  float m[NTYPES];
  #pragma unroll
  for (int t = 0; t < NTYPES; ++t) m[t] = -3.402823466e38f;
  for (int r = blockIdx.x * 256 + threadIdx.x; r < nrows; r += gridDim.x * 256) {
    #pragma unroll
    for (int t = 0; t < NTYPES; ++t) m[t] = fmaxf(m[t], L[(size_t)r * NTYPES + t]);
  }
  #pragma unroll
  for (int t = 0; t < NTYPES; ++t) sm[threadIdx.x][t] = m[t];
  __syncthreads();
  for (int s = 128; s > 0; s >>= 1) {
    if (threadIdx.x < s)
      for (int t = 0; t < NTYPES; ++t)
        sm[threadIdx.x][t] = fmaxf(sm[threadIdx.x][t], sm[threadIdx.x + s][t]);
    __syncthreads();
  }
  if (threadIdx.x < NTYPES) atomicMax(&mb[threadIdx.x], encf(sm[0][threadIdx.x]));
}

__global__ __launch_bounds__(256) void k_colsum(const float* __restrict__ L, int nrows,
                                                const uint32_t* __restrict__ mb,
                                                double* __restrict__ sums) {
  __shared__ double sm[256][NTYPES];
  float mx[NTYPES];
  #pragma unroll
  for (int t = 0; t < NTYPES; ++t) mx[t] = decf(mb[t]);
  double s[NTYPES];
  #pragma unroll
  for (int t = 0; t < NTYPES; ++t) s[t] = 0.0;
  for (int r = blockIdx.x * 256 + threadIdx.x; r < nrows; r += gridDim.x * 256) {
    #pragma unroll
    for (int t = 0; t < NTYPES; ++t)
      s[t] += exp((double)L[(size_t)r * NTYPES + t] - (double)mx[t]);
  }
  #pragma unroll
  for (int t = 0; t < NTYPES; ++t) sm[threadIdx.x][t] = s[t];
  __syncthreads();
  for (int st = 128; st > 0; st >>= 1) {
    if (threadIdx.x < st)
      for (int t = 0; t < NTYPES; ++t)
        sm[threadIdx.x][t] += sm[threadIdx.x + st][t];
    __syncthreads();
  }
  if (threadIdx.x < NTYPES) atomicAdd(&sums[threadIdx.x], sm[0][threadIdx.x]);
}

__global__ __launch_bounds__(256) void k_probs_start(const float* __restrict__ L,
                                                     const uint32_t* __restrict__ mb,
                                                     const double* __restrict__ sums,
                                                     float* __restrict__ P) {
  int gid = blockIdx.x * 256 + threadIdx.x;
  if (gid >= NT * NTYPES) return;
  int i = gid / NTYPES, t = gid - i * NTYPES;
  double p = exp((double)L[gid] - (double)decf(mb[t])) / sums[t];
  float pf = (float)p;
  if (i >= N_GRAPH || pf == 0.0f) pf = 1e-10f;
  P[gid] = pf;
}

__global__ __launch_bounds__(256) void k_probs_end(const float* __restrict__ L,
                                                   const uint32_t* __restrict__ mb,
                                                   const double* __restrict__ sums,
                                                   const int* __restrict__ flags,
                                                   float* __restrict__ P) {
  int gid = blockIdx.x * 256 + threadIdx.x;
  if (gid >= 2 * NT * NTYPES) return;
  int j = gid / NTYPES, t = gid - j * NTYPES;
  double p = exp((double)L[gid] - (double)decf(mb[t])) / sums[t];
  float pf = (float)p;
  if ((j < NTYPES && flags[j]) || pf == 0.0f) pf = 1e-10f;
  P[gid] = pf;
}

__global__ __launch_bounds__(256) void k_sample_start(const float* __restrict__ probs,
                                                      float* __restrict__ outSN,
                                                      int* __restrict__ sn, int* __restrict__ flags) {
  int i = blockIdx.x * 256 + threadIdx.x;
  if (i >= NT) return;
  uint32_t a0, a1, b0, b1; derive_keys(a0, a1, b0, b1);
  double best = -1e300; int bi = 0;
  #pragma unroll
  for (int t = 0; t < NTYPES; ++t) {
    uint32_t bits = rng_bits(a0, a1, (uint32_t)(i * NTYPES + t), (uint32_t)(NT * NTYPES));
    double v = log((double)probs[(size_t)i * NTYPES + t]) + gumbel_from_bits(bits);
    if (v > best) { best = v; bi = t; }
  }
  sn[i] = bi;
  outSN[i] = (float)bi;
  flags[bi] = 1;   // benign race: all writers store 1
}

__global__ __launch_bounds__(256) void k_sample_end(const float* __restrict__ probs,
                                                    float* __restrict__ outEN) {
  int j = blockIdx.x * 256 + threadIdx.x;
  if (j >= 2 * NT) return;
  uint32_t a0, a1, b0, b1; derive_keys(a0, a1, b0, b1);
  double best = -1e300; int bi = 0;
  #pragma unroll
  for (int t = 0; t < NTYPES; ++t) {
    uint32_t bits = rng_bits(b0, b1, (uint32_t)(j * NTYPES + t), (uint32_t)(2 * NT * NTYPES));
    double v = log((double)probs[(size_t)j * NTYPES + t]) + gumbel_from_bits(bits);
    if (v > best) { best = v; bi = t; }
  }
  outEN[j] = (float)bi;
}

// ---------------- host ----------------
extern "C" void kernel_launch(void* const* d_in, const int* in_sizes, int n_in,
                              void* d_out, int out_size, void* d_ws, size_t ws_size,
                              hipStream_t stream) {
  const float* x    = (const float*)d_in[0];
  const float* cand = (const float*)d_in[1];
  const int*   ei   = (const int*)d_in[2];
  const float* W1 = (const float*)d_in[4];  const float* b1 = (const float*)d_in[5];
  const float* W2 = (const float*)d_in[6];  const float* b2 = (const float*)d_in[7];
  const float* W3 = (const float*)d_in[8];  const float* b3 = (const float*)d_in[9];
  const float* Ws1 = (const float*)d_in[10]; const float* bs1 = (const float*)d_in[11];
  const float* Ws2 = (const float*)d_in[12]; const float* bs2 = (const float*)d_in[13];
  const float* We1 = (const float*)d_in[14]; const float* be1 = (const float*)d_in[15];
  const float* We2 = (const float*)d_in[16]; const float* be2 = (const float*)d_in[17];
  float* out = (float*)d_out;
  float* outSN = out;
  float* outEN = out + NT;
  float* outPS = out + 3 * NT;
  float* outPE = out + 13 * NT;

  char* ws = (char*)d_ws;
  size_t off = 0;
  auto alloc = [&](size_t bytes) -> void* {
    void* p = ws + off;
    off += (bytes + 511) & ~(size_t)511;
    return p;
  };
  float*    dinv    = (float*)alloc((size_t)NT * 4);
  float*    g       = (float*)alloc((size_t)NT * 32 * 4);
  float*    Ha      = (float*)alloc((size_t)NT * 32 * 4);
  int*      rowptr  = (int*)alloc((size_t)(NT + 1) * 4);
  int*      cnt     = (int*)alloc((size_t)NBK2 * 4);
  int*      rowbase = (int*)alloc((size_t)NBK2 * 4);
  int*      cmat    = (int*)alloc((size_t)(NMAT + 1) * 4);
  int*      partial = (int*)alloc(512 * 4);
  int*      col     = (int*)alloc((size_t)NE * 4);
  // tmpent (~31.6 MB) aliases Hb + logitsS + logitsE (dead until layer 2)
  char*     ublk    = (char*)alloc((size_t)TMPENT_CAP * 4);
  uint32_t* tmpent  = (uint32_t*)ublk;
  float*    Hb      = (float*)ublk;                                   // 12.8 MB
  float*    logitsS = (float*)(ublk + (size_t)NT * 32 * 4);           // 4 MB
  float*    logitsE = (float*)(ublk + (size_t)NT * 32 * 4 + (size_t)NT * NTYPES * 4); // 8 MB
  int*      sn      = (int*)alloc((size_t)NT * 4);
  uint32_t* maxS    = (uint32_t*)alloc(64);
  double*   sumS    = (double*)alloc(128);
  uint32_t* maxE    = (uint32_t*)alloc(64);
  double*   sumE    = (double*)alloc(128);
  int*      flags   = (int*)alloc(64);
  (void)ws_size; (void)in_sizes; (void)n_in; (void)out_size;

  const int* srcA = ei;
  const int* dstA = ei + NE;

  const int B = 256;
  auto blocks = [](long long nthreads) { return (int)((nthreads + 255) / 256); };

  // CSR build: count -> scan -> barrier-free scatter -> place
  hipMemsetAsync(cnt, 0, (size_t)NBK2 * 4, stream);
  k_bcount<<<SB, 512, 0, stream>>>(dstA, cmat, cnt);
  k_s1<<<NSCAN_B, 256, 0, stream>>>(cmat, partial);
  k_s2<<<1, 512, 0, stream>>>(partial, cmat);
  k_s3<<<NSCAN_B, 256, 0, stream>>>(cmat, partial);
  k_rowscan<<<1, 256, 0, stream>>>(cnt, rowbase);
  k_scatter2<<<SB, 512, 0, stream>>>(srcA, dstA, cmat, tmpent);
  k_place<<<NBK2, 512, 0, stream>>>(tmpent, cmat, rowbase, rowptr, dinv, col);

  // layer 1: 128 -> 16
  k_mm1<<<blocks((long long)NT * 16), B, 0, stream>>>(x, cand, W1, dinv, g);
  k_gcn<16, 16><<<(NT + 15) / 16, dim3(16, 16), 0, stream>>>(rowptr, col, g, dinv, b1, Ha);

  // layer 2: 16 -> 24   (tmpent dead from here; Hb/logits reuse its space)
  k_mm<16, 24><<<blocks((long long)NT * 24), B, 0, stream>>>(Ha, W2, dinv, g);
  k_gcn<24, 10><<<(NT + 9) / 10, dim3(24, 10), 0, stream>>>(rowptr, col, g, dinv, b2, Hb);

  // layer 3: 24 -> 32
  k_mm<24, 32><<<blocks((long long)NT * 32), B, 0, stream>>>(Hb, W3, dinv, g);
  k_gcn<32, 8><<<(NT + 7) / 8, dim3(32, 8), 0, stream>>>(rowptr, col, g, dinv, b3, Ha);
  // H3 = Ha

  // start head
  k_head<16><<<blocks(NT), B, 0, stream>>>(Ha, sn, NT, Ws1, bs1, Ws2, bs2, logitsS);
  hipMemsetAsync(maxS, 0, (size_t)((char*)flags - (char*)maxS) + 512, stream);
  k_colmax<<<512, B, 0, stream>>>(logitsS, NT, maxS);
  k_colsum<<<512, B, 0, stream>>>(logitsS, NT, maxS, sumS);
  k_probs_start<<<blocks((long long)NT * NTYPES), B, 0, stream>>>(logitsS, maxS, sumS, outPS);
  k_sample_start<<<blocks(NT), B, 0, stream>>>(outPS, outSN, sn, flags);

  // end head (rows: [H3; H3[sn]])
  k_head<24><<<blocks(2 * NT), B, 0, stream>>>(Ha, sn, 2 * NT, We1, be1, We2, be2, logitsE);
  k_colmax<<<512, B, 0, stream>>>(logitsE, 2 * NT, maxE);
  k_colsum<<<512, B, 0, stream>>>(logitsE, 2 * NT, maxE, sumE);
  k_probs_end<<<blocks((long long)2 * NT * NTYPES), B, 0, stream>>>(logitsE, maxE, sumE, flags, outPE);
  k_sample_end<<<blocks(2 * NT), B, 0, stream>>>(outPE, outEN);
}

// Round 7
// 819.810 us; speedup vs baseline: 26.3229x; 1.0069x over previous
//
#include <hip/hip_runtime.h>
#include <stdint.h>

// ---------------- problem constants ----------------
constexpr int N_GRAPH = 100000;
constexpr int N_CANDS = 10;
constexpr int NT      = N_GRAPH + N_CANDS;   // 100010
constexpr int F_IN    = 128;
constexpr int NTYPES  = 10;
constexpr int NE      = 6400000;

constexpr int CB_SHIFT = 9;                   // 512 nodes per coarse bucket
constexpr int CB       = 1 << CB_SHIFT;
constexpr int NBK2     = (NT + CB - 1) / CB;  // 196
constexpr int SB       = 512;                 // scatter blocks (also bcount blocks)
constexpr int NMAT     = NBK2 * SB;           // 100352 (scan matrix size)
constexpr int NSCAN_B  = NMAT / 256;          // 392 scan blocks
constexpr int TMPENT_CAP = NE + NMAT * 15 + 16;  // all regions padded to 16 slots

#define RNG_VARIANT 0

// ---------------- threefry2x32 (matches jax._src.prng) ----------------
__device__ __forceinline__ void tf2x32(uint32_t k0, uint32_t k1, uint32_t x0, uint32_t x1,
                                       uint32_t& o0, uint32_t& o1) {
  const uint32_t ks2 = k0 ^ k1 ^ 0x1BD11BDAu;
  uint32_t v0 = x0 + k0, v1 = x1 + k1;
#define TFR(r) { v0 += v1; v1 = (v1 << (r)) | (v1 >> (32 - (r))); v1 ^= v0; }
  TFR(13) TFR(15) TFR(26) TFR(6)
  v0 += k1;  v1 += ks2 + 1u;
  TFR(17) TFR(29) TFR(16) TFR(24)
  v0 += ks2; v1 += k0 + 2u;
  TFR(13) TFR(15) TFR(26) TFR(6)
  v0 += k0;  v1 += k1 + 3u;
  TFR(17) TFR(29) TFR(16) TFR(24)
  v0 += k1;  v1 += ks2 + 4u;
  TFR(13) TFR(15) TFR(26) TFR(6)
  v0 += ks2; v1 += k0 + 5u;
#undef TFR
  o0 = v0; o1 = v1;
}

__device__ __forceinline__ void derive_keys(uint32_t& a0, uint32_t& a1,
                                            uint32_t& b0, uint32_t& b1) {
#if RNG_VARIANT == 2
  uint32_t c0, c1, d0, d1;
  tf2x32(0u, 42u, 0u, 2u, c0, c1);
  tf2x32(0u, 42u, 1u, 3u, d0, d1);
  a0 = c0; a1 = d0; b0 = c1; b1 = d1;
#else
  tf2x32(0u, 42u, 0u, 0u, a0, a1);
  tf2x32(0u, 42u, 0u, 1u, b0, b1);
#endif
}

__device__ __forceinline__ uint32_t rng_bits(uint32_t k0, uint32_t k1,
                                             uint32_t idx, uint32_t total) {
#if RNG_VARIANT == 0
  uint32_t o0, o1; tf2x32(k0, k1, 0u, idx, o0, o1); return o0 ^ o1;
#elif RNG_VARIANT == 1
  uint32_t o0, o1; tf2x32(k0, k1, 0u, idx, o0, o1); return o1;
#else
  uint32_t half = total >> 1; uint32_t o0, o1;
  if (idx < half) { tf2x32(k0, k1, idx, idx + half, o0, o1); return o0; }
  tf2x32(k0, k1, idx - half, idx, o0, o1); return o1;
#endif
}

__device__ __forceinline__ double gumbel_from_bits(uint32_t bits) {
  float uf = __uint_as_float((bits >> 9) | 0x3f800000u) - 1.0f;  // [0,1)
  uf = fmaxf(1.17549435e-38f, uf + 1.17549435e-38f);
  return -log(-log((double)uf));
}

__device__ __forceinline__ uint32_t encf(float f) {
  uint32_t u = __float_as_uint(f);
  return u ^ ((u & 0x80000000u) ? 0xFFFFFFFFu : 0x80000000u);
}
__device__ __forceinline__ float decf(uint32_t e) {
  uint32_t u = (e & 0x80000000u) ? (e ^ 0x80000000u) : ~e;
  return __uint_as_float(u);
}

// ---------------- CSR build ----------------
// pass 1: per-block coarse histogram -> padded cntmat (bucket-major) + exact cnt
__global__ __launch_bounds__(512) void k_bcount(const int* __restrict__ dst,
                                                int* __restrict__ cntmat,
                                                int* __restrict__ cnt) {
  __shared__ int h[NBK2];
  int tid = threadIdx.x, blk = blockIdx.x;
  for (int b = tid; b < NBK2; b += 512) h[b] = 0;
  __syncthreads();
  int per = (NE + SB - 1) / SB;
  int e0 = blk * per, e1 = min(e0 + per, NE);
  for (int e = e0 + tid; e < e1; e += 512) atomicAdd(&h[dst[e] >> CB_SHIFT], 1);
  __syncthreads();
  for (int b = tid; b < NBK2; b += 512) {
    int c = h[b];
    cntmat[b * SB + blk] = (c + 15) & ~15;     // 16-slot (64B) aligned region
    if (c) atomicAdd(&cnt[b], c);
  }
}

// hierarchical exclusive scan of cmat[NMAT] in place; cmat[NMAT] = total
__global__ __launch_bounds__(256) void k_s1(int* __restrict__ cmat, int* __restrict__ partial) {
  __shared__ int sm[256];
  int t = blockIdx.x * 256 + threadIdx.x;
  int v = cmat[t];
  sm[threadIdx.x] = v;
  __syncthreads();
  #pragma unroll
  for (int s = 1; s < 256; s <<= 1) {
    int a = (threadIdx.x >= s) ? sm[threadIdx.x - s] : 0;
    __syncthreads();
    sm[threadIdx.x] += a;
    __syncthreads();
  }
  cmat[t] = sm[threadIdx.x] - v;               // block-local exclusive
  if (threadIdx.x == 255) partial[blockIdx.x] = sm[255];
}

__global__ __launch_bounds__(512) void k_s2(int* __restrict__ partial, int* __restrict__ cmat) {
  __shared__ int sm[512];
  int t = threadIdx.x;
  int v = (t < NSCAN_B) ? partial[t] : 0;
  sm[t] = v;
  __syncthreads();
  #pragma unroll
  for (int s = 1; s < 512; s <<= 1) {
    int a = (t >= s) ? sm[t - s] : 0;
    __syncthreads();
    sm[t] += a;
    __syncthreads();
  }
  if (t < NSCAN_B) partial[t] = sm[t] - v;     // exclusive
  if (t == 511) cmat[NMAT] = sm[511];          // grand total
}

__global__ __launch_bounds__(256) void k_s3(int* __restrict__ cmat, const int* __restrict__ partial) {
  int t = blockIdx.x * 256 + threadIdx.x;
  cmat[t] += partial[blockIdx.x];
}

// exclusive scan of exact bucket counts -> rowbase
__global__ __launch_bounds__(256) void k_rowscan(const int* __restrict__ cnt,
                                                 int* __restrict__ rowbase) {
  __shared__ int sm[256];
  int t = threadIdx.x;
  int v = (t < NBK2) ? cnt[t] : 0;
  sm[t] = v;
  __syncthreads();
  #pragma unroll
  for (int s = 1; s < 256; s <<= 1) {
    int a = (t >= s) ? sm[t - s] : 0;
    __syncthreads();
    sm[t] += a;
    __syncthreads();
  }
  if (t < NBK2) rowbase[t] = sm[t] - v;
}

// pass 2: barrier-free scatter into block-private line-aligned regions
__global__ __launch_bounds__(512) void k_scatter2(const int* __restrict__ src,
                                                  const int* __restrict__ dst,
                                                  const int* __restrict__ cmat,
                                                  uint32_t* __restrict__ tmpent) {
  __shared__ int lcur[NBK2];
  int tid = threadIdx.x, blk = blockIdx.x;
  for (int b = tid; b < NBK2; b += 512) lcur[b] = cmat[b * SB + blk];
  __syncthreads();
  int per = (NE + SB - 1) / SB;
  int e0 = blk * per, e1 = min(e0 + per, NE);
  for (int e = e0 + tid; e < e1; e += 512) {
    int s = src[e], d = dst[e];
    int b = d >> CB_SHIFT;
    int pos = atomicAdd(&lcur[b], 1);
    tmpent[pos] = (uint32_t)s | ((uint32_t)(d & (CB - 1)) << 17);
  }
  __syncthreads();
  // sentinel-fill this block's region tails (region end = next region start)
  for (int b = tid; b < NBK2; b += 512) {
    int p = lcur[b];
    int end = cmat[b * SB + blk + 1];   // blk=SB-1 rolls into next bucket; cmat[NMAT]=total
    for (; p < end; ++p) tmpent[p] = 0xFFFFFFFFu;
  }
}

// per coarse bucket (512 threads): degree count -> local scan -> rowptr/dinv -> place col
__global__ __launch_bounds__(512) void k_place(const uint32_t* __restrict__ tmpent,
                                               const int* __restrict__ cmat,
                                               const int* __restrict__ rowbase,
                                               int* __restrict__ rowptr,
                                               float* __restrict__ dinv,
                                               int* __restrict__ col) {
  __shared__ int sdeg[CB];
  __shared__ int sexc[CB];
  __shared__ int sscan[CB];
  int b = blockIdx.x, tid = threadIdx.x;
  sdeg[tid] = 0;
  __syncthreads();
  int r0 = cmat[b * SB], r1 = cmat[(b + 1) * SB];
  for (int e = r0 + tid; e < r1; e += 512) {
    uint32_t v = tmpent[e];
    if (v != 0xFFFFFFFFu) atomicAdd(&sdeg[v >> 17], 1);
  }
  __syncthreads();
  int d = sdeg[tid];
  sscan[tid] = d;
  __syncthreads();
  #pragma unroll
  for (int s = 1; s < CB; s <<= 1) {
    int v = (tid >= s) ? sscan[tid - s] : 0;
    __syncthreads();
    sscan[tid] += v;
    __syncthreads();
  }
  int rb = rowbase[b];
  int incl = rb + sscan[tid];            // inclusive
  sexc[tid] = incl - d;                  // exclusive
  int i = b * CB + tid;
  if (i < NT) {
    rowptr[i + 1] = incl;
    dinv[i] = (float)(1.0 / sqrt((double)(d + 1)));
  }
  if (b == 0 && tid == 0) rowptr[0] = 0;
  __syncthreads();
  for (int e = r0 + tid; e < r1; e += 512) {
    uint32_t v = tmpent[e];
    if (v != 0xFFFFFFFFu) {
      int pos = atomicAdd(&sexc[v >> 17], 1);
      col[pos] = (int)(v & 0x1FFFFu);
    }
  }
}

// ---------------- dense per-node matmuls ----------------
__global__ __launch_bounds__(256) void k_mm1(const float* __restrict__ x, const float* __restrict__ cand,
                                             const float* __restrict__ W, const float* __restrict__ dinv,
                                             float* __restrict__ g) {
  int gid = blockIdx.x * 256 + threadIdx.x;
  if (gid >= NT * 16) return;
  int i = gid >> 4, f = gid & 15;
  const float* hr = (i < N_GRAPH) ? (x + (size_t)i * F_IN)
                                  : (cand + (size_t)(i - N_GRAPH) * F_IN);
  double a = 0.0;
  #pragma unroll 8
  for (int k = 0; k < F_IN; ++k) a += (double)hr[k] * (double)W[k * 16 + f];
  g[gid] = (float)(a * (double)dinv[i]);
}

template <int FI, int FO>
__global__ __launch_bounds__(256) void k_mm(const float* __restrict__ H, const float* __restrict__ W,
                                            const float* __restrict__ dinv, float* __restrict__ g) {
  int gid = blockIdx.x * 256 + threadIdx.x;
  if (gid >= NT * FO) return;
  int i = gid / FO, f = gid - i * FO;
  const float* hr = H + (size_t)i * FI;
  double a = 0.0;
  #pragma unroll
  for (int k = 0; k < FI; ++k) a += (double)hr[k] * (double)W[k * FO + f];
  g[gid] = (float)(a * (double)dinv[i]);
}

// ---------------- fused CSR gather + self-loop + bias (float4-vectorized) ----------------
// block = (F/4, R); lane fx covers features [4fx, 4fx+4); 8-edge unroll for MLP
template <int F, int R>
__global__ __launch_bounds__((F / 4) * R) void k_gcn(const int* __restrict__ rowptr,
                                                     const int* __restrict__ col,
                                                     const float* __restrict__ g,
                                                     const float* __restrict__ dinv,
                                                     const float* __restrict__ b,
                                                     float* __restrict__ Hn) {
  constexpr int FX = F / 4;
  int i = blockIdx.x * R + threadIdx.y;
  if (i >= NT) return;
  int fx = threadIdx.x;
  const float4* g4 = reinterpret_cast<const float4*>(g);
  int e0 = rowptr[i], e1 = rowptr[i + 1];
  double a0 = 0.0, a1 = 0.0, a2 = 0.0, a3 = 0.0;
  int e = e0;
  for (; e + 8 <= e1; e += 8) {
    int c[8];
    #pragma unroll
    for (int k = 0; k < 8; ++k) c[k] = col[e + k];
    float4 v[8];
    #pragma unroll
    for (int k = 0; k < 8; ++k) v[k] = g4[(size_t)c[k] * FX + fx];
    #pragma unroll
    for (int k = 0; k < 8; ++k) {
      a0 += (double)v[k].x; a1 += (double)v[k].y;
      a2 += (double)v[k].z; a3 += (double)v[k].w;
    }
  }
  for (; e < e1; ++e) {
    float4 v = g4[(size_t)col[e] * FX + fx];
    a0 += (double)v.x; a1 += (double)v.y; a2 += (double)v.z; a3 += (double)v.w;
  }
  float4 s = g4[(size_t)i * FX + fx];
  a0 += (double)s.x; a1 += (double)s.y; a2 += (double)s.z; a3 += (double)s.w;
  double di = (double)dinv[i];
  float4 o;
  o.x = (float)(di * a0 + (double)b[4 * fx + 0]);
  o.y = (float)(di * a1 + (double)b[4 * fx + 1]);
  o.z = (float)(di * a2 + (double)b[4 * fx + 2]);
  o.w = (float)(di * a3 + (double)b[4 * fx + 3]);
  reinterpret_cast<float4*>(Hn)[(size_t)i * FX + fx] = o;
}

// ---------------- heads / softmax / sampling ----------------
template <int HID>
__global__ __launch_bounds__(256) void k_head(const float* __restrict__ H, const int* __restrict__ sn,
                                              int nrows,
                                              const float* __restrict__ Wa, const float* __restrict__ ba,
                                              const float* __restrict__ Wb, const float* __restrict__ bb,
                                              float* __restrict__ logits) {
  int i = blockIdx.x * 256 + threadIdx.x;
  if (i >= nrows) return;
  int row = (i < NT) ? i : sn[i - NT];
  const float* hr = H + (size_t)row * 32;
  float h[32];
  #pragma unroll
  for (int k = 0; k < 32; ++k) h[k] = hr[k];
  double hid[HID];
  for (int j = 0; j < HID; ++j) {
    double a = (double)ba[j];
    #pragma unroll
    for (int k = 0; k < 32; ++k) a += (double)h[k] * (double)Wa[k * HID + j];
    hid[j] = fmin(fmax(a, 0.0), 6.0);  // relu6
  }
  for (int t = 0; t < NTYPES; ++t) {
    double l = (double)bb[t];
    #pragma unroll
    for (int j = 0; j < HID; ++j) l += hid[j] * (double)Wb[j * NTYPES + t];
    logits[(size_t)i * NTYPES + t] = (float)l;
  }
}

__global__ __launch_bounds__(256) void k_colmax(const float* __restrict__ L, int nrows,
                                                uint32_t* __restrict__ mb) {
  __shared__ float sm[256][NTYPES];
  float m[NTYPES];
  #pragma unroll
  for (int t = 0; t < NTYPES; ++t) m[t] = -3.402823466e38f;
  for (int r = blockIdx.x * 256 + threadIdx.x; r < nrows; r += gridDim.x * 256) {
    #pragma unroll
    for (int t = 0; t < NTYPES; ++t) m[t] = fmaxf(m[t], L[(size_t)r * NTYPES + t]);
  }
  #pragma unroll
  for (int t = 0; t < NTYPES; ++t) sm[threadIdx.x][t] = m[t];
  __syncthreads();
  for (int s = 128; s > 0; s >>= 1) {
    if (threadIdx.x < s)
      for (int t = 0; t < NTYPES; ++t)
        sm[threadIdx.x][t] = fmaxf(sm[threadIdx.x][t], sm[threadIdx.x + s][t]);
    __syncthreads();
  }
  if (threadIdx.x < NTYPES) atomicMax(&mb[threadIdx.x], encf(sm[0][threadIdx.x]));
}

__global__ __launch_bounds__(256) void k_colsum(const float* __restrict__ L, int nrows,
                                                const uint32_t* __restrict__ mb,
                                                double* __restrict__ sums) {
  __shared__ double sm[256][NTYPES];
  float mx[NTYPES];
  #pragma unroll
  for (int t = 0; t < NTYPES; ++t) mx[t] = decf(mb[t]);
  double s[NTYPES];
  #pragma unroll
  for (int t = 0; t < NTYPES; ++t) s[t] = 0.0;
  for (int r = blockIdx.x * 256 + threadIdx.x; r < nrows; r += gridDim.x * 256) {
    #pragma unroll
    for (int t = 0; t < NTYPES; ++t)
      s[t] += exp((double)L[(size_t)r * NTYPES + t] - (double)mx[t]);
  }
  #pragma unroll
  for (int t = 0; t < NTYPES; ++t) sm[threadIdx.x][t] = s[t];
  __syncthreads();
  for (int st = 128; st > 0; st >>= 1) {
    if (threadIdx.x < st)
      for (int t = 0; t < NTYPES; ++t)
        sm[threadIdx.x][t] += sm[threadIdx.x + st][t];
    __syncthreads();
  }
  if (threadIdx.x < NTYPES) atomicAdd(&sums[threadIdx.x], sm[0][threadIdx.x]);
}

__global__ __launch_bounds__(256) void k_probs_start(const float* __restrict__ L,
                                                     const uint32_t* __restrict__ mb,
                                                     const double* __restrict__ sums,
                                                     float* __restrict__ P) {
  int gid = blockIdx.x * 256 + threadIdx.x;
  if (gid >= NT * NTYPES) return;
  int i = gid / NTYPES, t = gid - i * NTYPES;
  double p = exp((double)L[gid] - (double)decf(mb[t])) / sums[t];
  float pf = (float)p;
  if (i >= N_GRAPH || pf == 0.0f) pf = 1e-10f;
  P[gid] = pf;
}

__global__ __launch_bounds__(256) void k_probs_end(const float* __restrict__ L,
                                                   const uint32_t* __restrict__ mb,
                                                   const double* __restrict__ sums,
                                                   const int* __restrict__ flags,
                                                   float* __restrict__ P) {
  int gid = blockIdx.x * 256 + threadIdx.x;
  if (gid >= 2 * NT * NTYPES) return;
  int j = gid / NTYPES, t = gid - j * NTYPES;
  double p = exp((double)L[gid] - (double)decf(mb[t])) / sums[t];
  float pf = (float)p;
  if ((j < NTYPES && flags[j]) || pf == 0.0f) pf = 1e-10f;
  P[gid] = pf;
}

__global__ __launch_bounds__(256) void k_sample_start(const float* __restrict__ probs,
                                                      float* __restrict__ outSN,
                                                      int* __restrict__ sn, int* __restrict__ flags) {
  int i = blockIdx.x * 256 + threadIdx.x;
  if (i >= NT) return;
  uint32_t a0, a1, b0, b1; derive_keys(a0, a1, b0, b1);
  double best = -1e300; int bi = 0;
  #pragma unroll
  for (int t = 0; t < NTYPES; ++t) {
    uint32_t bits = rng_bits(a0, a1, (uint32_t)(i * NTYPES + t), (uint32_t)(NT * NTYPES));
    double v = log((double)probs[(size_t)i * NTYPES + t]) + gumbel_from_bits(bits);
    if (v > best) { best = v; bi = t; }
  }
  sn[i] = bi;
  outSN[i] = (float)bi;
  flags[bi] = 1;   // benign race: all writers store 1
}

__global__ __launch_bounds__(256) void k_sample_end(const float* __restrict__ probs,
                                                    float* __restrict__ outEN) {
  int j = blockIdx.x * 256 + threadIdx.x;
  if (j >= 2 * NT) return;
  uint32_t a0, a1, b0, b1; derive_keys(a0, a1, b0, b1);
  double best = -1e300; int bi = 0;
  #pragma unroll
  for (int t = 0; t < NTYPES; ++t) {
    uint32_t bits = rng_bits(b0, b1, (uint32_t)(j * NTYPES + t), (uint32_t)(2 * NT * NTYPES));
    double v = log((double)probs[(size_t)j * NTYPES + t]) + gumbel_from_bits(bits);
    if (v > best) { best = v; bi = t; }
  }
  outEN[j] = (float)bi;
}

// ---------------- host ----------------
extern "C" void kernel_launch(void* const* d_in, const int* in_sizes, int n_in,
                              void* d_out, int out_size, void* d_ws, size_t ws_size,
                              hipStream_t stream) {
  const float* x    = (const float*)d_in[0];
  const float* cand = (const float*)d_in[1];
  const int*   ei   = (const int*)d_in[2];
  const float* W1 = (const float*)d_in[4];  const float* b1 = (const float*)d_in[5];
  const float* W2 = (const float*)d_in[6];  const float* b2 = (const float*)d_in[7];
  const float* W3 = (const float*)d_in[8];  const float* b3 = (const float*)d_in[9];
  const float* Ws1 = (const float*)d_in[10]; const float* bs1 = (const float*)d_in[11];
  const float* Ws2 = (const float*)d_in[12]; const float* bs2 = (const float*)d_in[13];
  const float* We1 = (const float*)d_in[14]; const float* be1 = (const float*)d_in[15];
  const float* We2 = (const float*)d_in[16]; const float* be2 = (const float*)d_in[17];
  float* out = (float*)d_out;
  float* outSN = out;
  float* outEN = out + NT;
  float* outPS = out + 3 * NT;
  float* outPE = out + 13 * NT;

  char* ws = (char*)d_ws;
  size_t off = 0;
  auto alloc = [&](size_t bytes) -> void* {
    void* p = ws + off;
    off += (bytes + 511) & ~(size_t)511;
    return p;
  };
  float*    dinv    = (float*)alloc((size_t)NT * 4);
  float*    g       = (float*)alloc((size_t)NT * 32 * 4);
  float*    Ha      = (float*)alloc((size_t)NT * 32 * 4);
  int*      rowptr  = (int*)alloc((size_t)(NT + 1) * 4);
  int*      cnt     = (int*)alloc((size_t)NBK2 * 4);
  int*      rowbase = (int*)alloc((size_t)NBK2 * 4);
  int*      cmat    = (int*)alloc((size_t)(NMAT + 1) * 4);
  int*      partial = (int*)alloc(512 * 4);
  int*      col     = (int*)alloc((size_t)NE * 4);
  // tmpent (~31.6 MB) aliases Hb + logitsS + logitsE (dead until layer 2)
  char*     ublk    = (char*)alloc((size_t)TMPENT_CAP * 4);
  uint32_t* tmpent  = (uint32_t*)ublk;
  float*    Hb      = (float*)ublk;                                   // 12.8 MB
  float*    logitsS = (float*)(ublk + (size_t)NT * 32 * 4);           // 4 MB
  float*    logitsE = (float*)(ublk + (size_t)NT * 32 * 4 + (size_t)NT * NTYPES * 4); // 8 MB
  int*      sn      = (int*)alloc((size_t)NT * 4);
  uint32_t* maxS    = (uint32_t*)alloc(64);
  double*   sumS    = (double*)alloc(128);
  uint32_t* maxE    = (uint32_t*)alloc(64);
  double*   sumE    = (double*)alloc(128);
  int*      flags   = (int*)alloc(64);
  (void)ws_size; (void)in_sizes; (void)n_in; (void)out_size;

  const int* srcA = ei;
  const int* dstA = ei + NE;

  const int B = 256;
  auto blocks = [](long long nthreads) { return (int)((nthreads + 255) / 256); };

  // CSR build: count -> scan -> barrier-free scatter -> place
  hipMemsetAsync(cnt, 0, (size_t)NBK2 * 4, stream);
  k_bcount<<<SB, 512, 0, stream>>>(dstA, cmat, cnt);
  k_s1<<<NSCAN_B, 256, 0, stream>>>(cmat, partial);
  k_s2<<<1, 512, 0, stream>>>(partial, cmat);
  k_s3<<<NSCAN_B, 256, 0, stream>>>(cmat, partial);
  k_rowscan<<<1, 256, 0, stream>>>(cnt, rowbase);
  k_scatter2<<<SB, 512, 0, stream>>>(srcA, dstA, cmat, tmpent);
  k_place<<<NBK2, 512, 0, stream>>>(tmpent, cmat, rowbase, rowptr, dinv, col);

  // layer 1: 128 -> 16
  k_mm1<<<blocks((long long)NT * 16), B, 0, stream>>>(x, cand, W1, dinv, g);
  k_gcn<16, 64><<<(NT + 63) / 64, dim3(4, 64), 0, stream>>>(rowptr, col, g, dinv, b1, Ha);

  // layer 2: 16 -> 24   (tmpent dead from here; Hb/logits reuse its space)
  k_mm<16, 24><<<blocks((long long)NT * 24), B, 0, stream>>>(Ha, W2, dinv, g);
  k_gcn<24, 42><<<(NT + 41) / 42, dim3(6, 42), 0, stream>>>(rowptr, col, g, dinv, b2, Hb);

  // layer 3: 24 -> 32
  k_mm<24, 32><<<blocks((long long)NT * 32), B, 0, stream>>>(Hb, W3, dinv, g);
  k_gcn<32, 32><<<(NT + 31) / 32, dim3(8, 32), 0, stream>>>(rowptr, col, g, dinv, b3, Ha);
  // H3 = Ha

  // start head
  k_head<16><<<blocks(NT), B, 0, stream>>>(Ha, sn, NT, Ws1, bs1, Ws2, bs2, logitsS);
  hipMemsetAsync(maxS, 0, (size_t)((char*)flags - (char*)maxS) + 512, stream);
  k_colmax<<<512, B, 0, stream>>>(logitsS, NT, maxS);
  k_colsum<<<512, B, 0, stream>>>(logitsS, NT, maxS, sumS);
  k_probs_start<<<blocks((long long)NT * NTYPES), B, 0, stream>>>(logitsS, maxS, sumS, outPS);
  k_sample_start<<<blocks(NT), B, 0, stream>>>(outPS, outSN, sn, flags);

  // end head (rows: [H3; H3[sn]])
  k_head<24><<<blocks(2 * NT), B, 0, stream>>>(Ha, sn, 2 * NT, We1, be1, We2, be2, logitsE);
  k_colmax<<<512, B, 0, stream>>>(logitsE, 2 * NT, maxE);
  k_colsum<<<512, B, 0, stream>>>(logitsE, 2 * NT, maxE, sumE);
  k_probs_end<<<blocks((long long)2 * NT * NTYPES), B, 0, stream>>>(logitsE, maxE, sumE, flags, outPE);
  k_sample_end<<<blocks(2 * NT), B, 0, stream>>>(outPE, outEN);
}

// Round 8
// 791.887 us; speedup vs baseline: 27.2511x; 1.0353x over previous
//
#include <hip/hip_runtime.h>
#include <stdint.h>

// ---------------- problem constants ----------------
constexpr int N_GRAPH = 100000;
constexpr int N_CANDS = 10;
constexpr int NT      = N_GRAPH + N_CANDS;   // 100010
constexpr int F_IN    = 128;
constexpr int NTYPES  = 10;
constexpr int NE      = 6400000;

constexpr int CB_SHIFT = 9;                   // 512 nodes per coarse bucket
constexpr int CB       = 1 << CB_SHIFT;
constexpr int NBK2     = (NT + CB - 1) / CB;  // 196
constexpr int SB       = 512;                 // scatter blocks (also bcount blocks)
constexpr int NMAT     = NBK2 * SB;           // 100352 (scan matrix size)
constexpr int NSCAN_B  = NMAT / 256;          // 392 scan blocks
constexpr int TMPENT_CAP = NE + NMAT * 15 + 16;  // all regions padded to 16 slots

#define RNG_VARIANT 0

// ---------------- threefry2x32 (matches jax._src.prng) ----------------
__device__ __forceinline__ void tf2x32(uint32_t k0, uint32_t k1, uint32_t x0, uint32_t x1,
                                       uint32_t& o0, uint32_t& o1) {
  const uint32_t ks2 = k0 ^ k1 ^ 0x1BD11BDAu;
  uint32_t v0 = x0 + k0, v1 = x1 + k1;
#define TFR(r) { v0 += v1; v1 = (v1 << (r)) | (v1 >> (32 - (r))); v1 ^= v0; }
  TFR(13) TFR(15) TFR(26) TFR(6)
  v0 += k1;  v1 += ks2 + 1u;
  TFR(17) TFR(29) TFR(16) TFR(24)
  v0 += ks2; v1 += k0 + 2u;
  TFR(13) TFR(15) TFR(26) TFR(6)
  v0 += k0;  v1 += k1 + 3u;
  TFR(17) TFR(29) TFR(16) TFR(24)
  v0 += k1;  v1 += ks2 + 4u;
  TFR(13) TFR(15) TFR(26) TFR(6)
  v0 += ks2; v1 += k0 + 5u;
#undef TFR
  o0 = v0; o1 = v1;
}

__device__ __forceinline__ void derive_keys(uint32_t& a0, uint32_t& a1,
                                            uint32_t& b0, uint32_t& b1) {
#if RNG_VARIANT == 2
  uint32_t c0, c1, d0, d1;
  tf2x32(0u, 42u, 0u, 2u, c0, c1);
  tf2x32(0u, 42u, 1u, 3u, d0, d1);
  a0 = c0; a1 = d0; b0 = c1; b1 = d1;
#else
  tf2x32(0u, 42u, 0u, 0u, a0, a1);
  tf2x32(0u, 42u, 0u, 1u, b0, b1);
#endif
}

__device__ __forceinline__ uint32_t rng_bits(uint32_t k0, uint32_t k1,
                                             uint32_t idx, uint32_t total) {
#if RNG_VARIANT == 0
  uint32_t o0, o1; tf2x32(k0, k1, 0u, idx, o0, o1); return o0 ^ o1;
#elif RNG_VARIANT == 1
  uint32_t o0, o1; tf2x32(k0, k1, 0u, idx, o0, o1); return o1;
#else
  uint32_t half = total >> 1; uint32_t o0, o1;
  if (idx < half) { tf2x32(k0, k1, idx, idx + half, o0, o1); return o0; }
  tf2x32(k0, k1, idx - half, idx, o0, o1); return o1;
#endif
}

__device__ __forceinline__ double gumbel_from_bits(uint32_t bits) {
  float uf = __uint_as_float((bits >> 9) | 0x3f800000u) - 1.0f;  // [0,1)
  uf = fmaxf(1.17549435e-38f, uf + 1.17549435e-38f);
  return -log(-log((double)uf));
}

__device__ __forceinline__ uint32_t encf(float f) {
  uint32_t u = __float_as_uint(f);
  return u ^ ((u & 0x80000000u) ? 0xFFFFFFFFu : 0x80000000u);
}
__device__ __forceinline__ float decf(uint32_t e) {
  uint32_t u = (e & 0x80000000u) ? (e ^ 0x80000000u) : ~e;
  return __uint_as_float(u);
}

// ---------------- CSR build ----------------
__global__ __launch_bounds__(512) void k_bcount(const int* __restrict__ dst,
                                                int* __restrict__ cntmat,
                                                int* __restrict__ cnt) {
  __shared__ int h[NBK2];
  int tid = threadIdx.x, blk = blockIdx.x;
  for (int b = tid; b < NBK2; b += 512) h[b] = 0;
  __syncthreads();
  int per = (NE + SB - 1) / SB;
  int e0 = blk * per, e1 = min(e0 + per, NE);
  for (int e = e0 + tid; e < e1; e += 512) atomicAdd(&h[dst[e] >> CB_SHIFT], 1);
  __syncthreads();
  for (int b = tid; b < NBK2; b += 512) {
    int c = h[b];
    cntmat[b * SB + blk] = (c + 15) & ~15;     // 16-slot (64B) aligned region
    if (c) atomicAdd(&cnt[b], c);
  }
}

__global__ __launch_bounds__(256) void k_s1(int* __restrict__ cmat, int* __restrict__ partial) {
  __shared__ int sm[256];
  int t = blockIdx.x * 256 + threadIdx.x;
  int v = cmat[t];
  sm[threadIdx.x] = v;
  __syncthreads();
  #pragma unroll
  for (int s = 1; s < 256; s <<= 1) {
    int a = (threadIdx.x >= s) ? sm[threadIdx.x - s] : 0;
    __syncthreads();
    sm[threadIdx.x] += a;
    __syncthreads();
  }
  cmat[t] = sm[threadIdx.x] - v;               // block-local exclusive
  if (threadIdx.x == 255) partial[blockIdx.x] = sm[255];
}

__global__ __launch_bounds__(512) void k_s2(int* __restrict__ partial, int* __restrict__ cmat) {
  __shared__ int sm[512];
  int t = threadIdx.x;
  int v = (t < NSCAN_B) ? partial[t] : 0;
  sm[t] = v;
  __syncthreads();
  #pragma unroll
  for (int s = 1; s < 512; s <<= 1) {
    int a = (t >= s) ? sm[t - s] : 0;
    __syncthreads();
    sm[t] += a;
    __syncthreads();
  }
  if (t < NSCAN_B) partial[t] = sm[t] - v;     // exclusive
  if (t == 511) cmat[NMAT] = sm[511];          // grand total
}

__global__ __launch_bounds__(256) void k_s3(int* __restrict__ cmat, const int* __restrict__ partial) {
  int t = blockIdx.x * 256 + threadIdx.x;
  cmat[t] += partial[blockIdx.x];
}

__global__ __launch_bounds__(256) void k_rowscan(const int* __restrict__ cnt,
                                                 int* __restrict__ rowbase) {
  __shared__ int sm[256];
  int t = threadIdx.x;
  int v = (t < NBK2) ? cnt[t] : 0;
  sm[t] = v;
  __syncthreads();
  #pragma unroll
  for (int s = 1; s < 256; s <<= 1) {
    int a = (t >= s) ? sm[t - s] : 0;
    __syncthreads();
    sm[t] += a;
    __syncthreads();
  }
  if (t < NBK2) rowbase[t] = sm[t] - v;
}

__global__ __launch_bounds__(512) void k_scatter2(const int* __restrict__ src,
                                                  const int* __restrict__ dst,
                                                  const int* __restrict__ cmat,
                                                  uint32_t* __restrict__ tmpent) {
  __shared__ int lcur[NBK2];
  int tid = threadIdx.x, blk = blockIdx.x;
  for (int b = tid; b < NBK2; b += 512) lcur[b] = cmat[b * SB + blk];
  __syncthreads();
  int per = (NE + SB - 1) / SB;
  int e0 = blk * per, e1 = min(e0 + per, NE);
  for (int e = e0 + tid; e < e1; e += 512) {
    int s = src[e], d = dst[e];
    int b = d >> CB_SHIFT;
    int pos = atomicAdd(&lcur[b], 1);
    tmpent[pos] = (uint32_t)s | ((uint32_t)(d & (CB - 1)) << 17);
  }
  __syncthreads();
  for (int b = tid; b < NBK2; b += 512) {
    int p = lcur[b];
    int end = cmat[b * SB + blk + 1];
    for (; p < end; ++p) tmpent[p] = 0xFFFFFFFFu;
  }
}

__global__ __launch_bounds__(512) void k_place(const uint32_t* __restrict__ tmpent,
                                               const int* __restrict__ cmat,
                                               const int* __restrict__ rowbase,
                                               int* __restrict__ rowptr,
                                               float* __restrict__ dinv,
                                               int* __restrict__ col) {
  __shared__ int sdeg[CB];
  __shared__ int sexc[CB];
  __shared__ int sscan[CB];
  int b = blockIdx.x, tid = threadIdx.x;
  sdeg[tid] = 0;
  __syncthreads();
  int r0 = cmat[b * SB], r1 = cmat[(b + 1) * SB];
  for (int e = r0 + tid; e < r1; e += 512) {
    uint32_t v = tmpent[e];
    if (v != 0xFFFFFFFFu) atomicAdd(&sdeg[v >> 17], 1);
  }
  __syncthreads();
  int d = sdeg[tid];
  sscan[tid] = d;
  __syncthreads();
  #pragma unroll
  for (int s = 1; s < CB; s <<= 1) {
    int v = (tid >= s) ? sscan[tid - s] : 0;
    __syncthreads();
    sscan[tid] += v;
    __syncthreads();
  }
  int rb = rowbase[b];
  int incl = rb + sscan[tid];
  sexc[tid] = incl - d;
  int i = b * CB + tid;
  if (i < NT) {
    rowptr[i + 1] = incl;
    dinv[i] = (float)(1.0 / sqrt((double)(d + 1)));
  }
  if (b == 0 && tid == 0) rowptr[0] = 0;
  __syncthreads();
  for (int e = r0 + tid; e < r1; e += 512) {
    uint32_t v = tmpent[e];
    if (v != 0xFFFFFFFFu) {
      int pos = atomicAdd(&sexc[v >> 17], 1);
      col[pos] = (int)(v & 0x1FFFFu);
    }
  }
}

// ---------------- zs0 = (concat(x,cand) @ W1) * dinv   [NT,16], 4 features/thread ----------------
__global__ __launch_bounds__(256) void k_mm1(const float* __restrict__ x, const float* __restrict__ cand,
                                             const float* __restrict__ W, const float* __restrict__ dinv,
                                             float* __restrict__ zs0) {
  int gid = blockIdx.x * 256 + threadIdx.x;
  if (gid >= NT * 4) return;
  int i = gid >> 2, f4 = gid & 3;
  const float* hr = (i < N_GRAPH) ? (x + (size_t)i * F_IN)
                                  : (cand + (size_t)(i - N_GRAPH) * F_IN);
  const float4* h4 = reinterpret_cast<const float4*>(hr);
  const float4* W4 = reinterpret_cast<const float4*>(W);   // W[k][16] -> W4[k*4 + f4]
  double a0 = 0.0, a1 = 0.0, a2 = 0.0, a3 = 0.0;
  #pragma unroll 8
  for (int q = 0; q < 32; ++q) {
    float4 hv = h4[q];
    float4 w0 = W4[(4 * q + 0) * 4 + f4];
    float4 w1 = W4[(4 * q + 1) * 4 + f4];
    float4 w2 = W4[(4 * q + 2) * 4 + f4];
    float4 w3 = W4[(4 * q + 3) * 4 + f4];
    a0 += (double)hv.x * w0.x + (double)hv.y * w1.x + (double)hv.z * w2.x + (double)hv.w * w3.x;
    a1 += (double)hv.x * w0.y + (double)hv.y * w1.y + (double)hv.z * w2.y + (double)hv.w * w3.y;
    a2 += (double)hv.x * w0.z + (double)hv.y * w1.z + (double)hv.z * w2.z + (double)hv.w * w3.z;
    a3 += (double)hv.x * w0.w + (double)hv.y * w1.w + (double)hv.z * w2.w + (double)hv.w * w3.w;
  }
  double di = (double)dinv[i];
  float4 o;
  o.x = (float)(a0 * di); o.y = (float)(a1 * di);
  o.z = (float)(a2 * di); o.w = (float)(a3 * di);
  reinterpret_cast<float4*>(zs0)[(size_t)i * 4 + f4] = o;
}

// ---------------- fused F=16 propagation:  zout = scale(i) * (sum_col zin + zin_i) ----------------
// scale = dinv^2 (pre-scaled for next prop) or dinv (final). Optionally carries scalar w-prop.
template <bool SQ, bool WITHW, int R>
__global__ __launch_bounds__(4 * R) void k_prop(const int* __restrict__ rowptr,
                                                const int* __restrict__ col,
                                                const float* __restrict__ zin,   // [NT][16]
                                                const float* __restrict__ win,   // [NT] scaled w input
                                                const float* __restrict__ dinv,
                                                float* __restrict__ zout,
                                                float* __restrict__ wout,        // unscaled w_{l}
                                                float* __restrict__ wsout) {     // dinv*w (next prop input)
  int i = blockIdx.x * R + threadIdx.y;
  if (i >= NT) return;
  int fx = threadIdx.x;                         // 0..3, 16B each -> 64B row = 1 line
  const float4* z4 = reinterpret_cast<const float4*>(zin);
  int e0 = rowptr[i], e1 = rowptr[i + 1];
  double a0 = 0.0, a1 = 0.0, a2 = 0.0, a3 = 0.0, wa = 0.0;
  int e = e0;
  for (; e + 4 <= e1; e += 4) {
    int c0 = col[e], c1 = col[e + 1], c2 = col[e + 2], c3 = col[e + 3];
    float4 v0 = z4[(size_t)c0 * 4 + fx];
    float4 v1 = z4[(size_t)c1 * 4 + fx];
    float4 v2 = z4[(size_t)c2 * 4 + fx];
    float4 v3 = z4[(size_t)c3 * 4 + fx];
    if (WITHW && fx == 0)
      wa += (double)win[c0] + (double)win[c1] + (double)win[c2] + (double)win[c3];
    a0 += (double)v0.x + (double)v1.x + (double)v2.x + (double)v3.x;
    a1 += (double)v0.y + (double)v1.y + (double)v2.y + (double)v3.y;
    a2 += (double)v0.z + (double)v1.z + (double)v2.z + (double)v3.z;
    a3 += (double)v0.w + (double)v1.w + (double)v2.w + (double)v3.w;
  }
  for (; e < e1; ++e) {
    int c = col[e];
    float4 v = z4[(size_t)c * 4 + fx];
    if (WITHW && fx == 0) wa += (double)win[c];
    a0 += (double)v.x; a1 += (double)v.y; a2 += (double)v.z; a3 += (double)v.w;
  }
  float4 s = z4[(size_t)i * 4 + fx];
  a0 += (double)s.x; a1 += (double)s.y; a2 += (double)s.z; a3 += (double)s.w;
  double di = (double)dinv[i];
  double sc = SQ ? di * di : di;
  float4 o;
  o.x = (float)(sc * a0); o.y = (float)(sc * a1);
  o.z = (float)(sc * a2); o.w = (float)(sc * a3);
  reinterpret_cast<float4*>(zout)[(size_t)i * 4 + fx] = o;
  if (WITHW && fx == 0) {
    wa += (double)win[i];
    double w = di * wa;                 // unscaled w_{l}
    wout[i]  = (float)w;
    wsout[i] = (float)(di * w);         // scaled for next prop
  }
}

// ---------------- small dense precompute: M = W2@W3, u = b1@W2@W3, v = b2@W3 ----------------
__global__ __launch_bounds__(512) void k_small(const float* __restrict__ W2, const float* __restrict__ b2p,
                                               const float* __restrict__ W3, const float* __restrict__ b1p,
                                               double* __restrict__ M, double* __restrict__ u,
                                               double* __restrict__ v) {
  __shared__ double t[24];
  int tid = threadIdx.x;
  if (tid < 24) {
    double a = 0.0;
    for (int k = 0; k < 16; ++k) a += (double)b1p[k] * (double)W2[k * 24 + tid];
    t[tid] = a;
  }
  if (tid >= 32 && tid < 64) {
    int o = tid - 32;
    double a = 0.0;
    for (int j = 0; j < 24; ++j) a += (double)b2p[j] * (double)W3[j * 32 + o];
    v[o] = a;
  }
  __syncthreads();
  if (tid < 32) {
    double a = 0.0;
    for (int j = 0; j < 24; ++j) a += t[j] * (double)W3[j * 32 + tid];
    u[tid] = a;
  }
  {
    int k = tid >> 5, o = tid & 31;
    double a = 0.0;
    for (int j = 0; j < 24; ++j) a += (double)W2[k * 24 + j] * (double)W3[j * 32 + o];
    M[tid] = a;
  }
}

// ---------------- epilogue: h3 = z3@M + w2 (x) u + w1 (x) v + b3 ----------------
__global__ __launch_bounds__(256) void k_epi(const float* __restrict__ z3, const float* __restrict__ w1,
                                             const float* __restrict__ w2,
                                             const double* __restrict__ M, const double* __restrict__ u,
                                             const double* __restrict__ v, const float* __restrict__ b3,
                                             float* __restrict__ H) {
  int gid = blockIdx.x * 256 + threadIdx.x;
  if (gid >= NT * 32) return;
  int i = gid >> 5, o = gid & 31;
  const float* zr = z3 + (size_t)i * 16;
  double acc = (double)b3[o] + (double)w2[i] * u[o] + (double)w1[i] * v[o];
  #pragma unroll
  for (int k = 0; k < 16; ++k) acc += (double)zr[k] * M[k * 32 + o];
  H[gid] = (float)acc;
}

// ---------------- heads / softmax / sampling ----------------
template <int HID>
__global__ __launch_bounds__(256) void k_head(const float* __restrict__ H, const int* __restrict__ sn,
                                              int nrows,
                                              const float* __restrict__ Wa, const float* __restrict__ ba,
                                              const float* __restrict__ Wb, const float* __restrict__ bb,
                                              float* __restrict__ logits) {
  int i = blockIdx.x * 256 + threadIdx.x;
  if (i >= nrows) return;
  int row = (i < NT) ? i : sn[i - NT];
  const float* hr = H + (size_t)row * 32;
  float h[32];
  #pragma unroll
  for (int k = 0; k < 32; ++k) h[k] = hr[k];
  double hid[HID];
  for (int j = 0; j < HID; ++j) {
    double a = (double)ba[j];
    #pragma unroll
    for (int k = 0; k < 32; ++k) a += (double)h[k] * (double)Wa[k * HID + j];
    hid[j] = fmin(fmax(a, 0.0), 6.0);  // relu6
  }
  for (int t = 0; t < NTYPES; ++t) {
    double l = (double)bb[t];
    #pragma unroll
    for (int j = 0; j < HID; ++j) l += hid[j] * (double)Wb[j * NTYPES + t];
    logits[(size_t)i * NTYPES + t] = (float)l;
  }
}

__global__ __launch_bounds__(256) void k_colmax(const float* __restrict__ L, int nrows,
                                                uint32_t* __restrict__ mb) {
  __shared__ float sm[256][NTYPES];
  float m[NTYPES];
  #pragma unroll
  for (int t = 0; t < NTYPES; ++t) m[t] = -3.402823466e38f;
  for (int r = blockIdx.x * 256 + threadIdx.x; r < nrows; r += gridDim.x * 256) {
    #pragma unroll
    for (int t = 0; t < NTYPES; ++t) m[t] = fmaxf(m[t], L[(size_t)r * NTYPES + t]);
  }
  #pragma unroll
  for (int t = 0; t < NTYPES; ++t) sm[threadIdx.x][t] = m[t];
  __syncthreads();
  for (int s = 128; s > 0; s >>= 1) {
    if (threadIdx.x < s)
      for (int t = 0; t < NTYPES; ++t)
        sm[threadIdx.x][t] = fmaxf(sm[threadIdx.x][t], sm[threadIdx.x + s][t]);
    __syncthreads();
  }
  if (threadIdx.x < NTYPES) atomicMax(&mb[threadIdx.x], encf(sm[0][threadIdx.x]));
}

__global__ __launch_bounds__(256) void k_colsum(const float* __restrict__ L, int nrows,
                                                const uint32_t* __restrict__ mb,
                                                double* __restrict__ sums) {
  __shared__ double sm[256][NTYPES];
  float mx[NTYPES];
  #pragma unroll
  for (int t = 0; t < NTYPES; ++t) mx[t] = decf(mb[t]);
  double s[NTYPES];
  #pragma unroll
  for (int t = 0; t < NTYPES; ++t) s[t] = 0.0;
  for (int r = blockIdx.x * 256 + threadIdx.x; r < nrows; r += gridDim.x * 256) {
    #pragma unroll
    for (int t = 0; t < NTYPES; ++t)
      s[t] += exp((double)L[(size_t)r * NTYPES + t] - (double)mx[t]);
  }
  #pragma unroll
  for (int t = 0; t < NTYPES; ++t) sm[threadIdx.x][t] = s[t];
  __syncthreads();
  for (int st = 128; st > 0; st >>= 1) {
    if (threadIdx.x < st)
      for (int t = 0; t < NTYPES; ++t)
        sm[threadIdx.x][t] += sm[threadIdx.x + st][t];
    __syncthreads();
  }
  if (threadIdx.x < NTYPES) atomicAdd(&sums[threadIdx.x], sm[0][threadIdx.x]);
}

__global__ __launch_bounds__(256) void k_probs_start(const float* __restrict__ L,
                                                     const uint32_t* __restrict__ mb,
                                                     const double* __restrict__ sums,
                                                     float* __restrict__ P) {
  int gid = blockIdx.x * 256 + threadIdx.x;
  if (gid >= NT * NTYPES) return;
  int i = gid / NTYPES, t = gid - i * NTYPES;
  double p = exp((double)L[gid] - (double)decf(mb[t])) / sums[t];
  float pf = (float)p;
  if (i >= N_GRAPH || pf == 0.0f) pf = 1e-10f;
  P[gid] = pf;
}

__global__ __launch_bounds__(256) void k_probs_end(const float* __restrict__ L,
                                                   const uint32_t* __restrict__ mb,
                                                   const double* __restrict__ sums,
                                                   const int* __restrict__ flags,
                                                   float* __restrict__ P) {
  int gid = blockIdx.x * 256 + threadIdx.x;
  if (gid >= 2 * NT * NTYPES) return;
  int j = gid / NTYPES, t = gid - j * NTYPES;
  double p = exp((double)L[gid] - (double)decf(mb[t])) / sums[t];
  float pf = (float)p;
  if ((j < NTYPES && flags[j]) || pf == 0.0f) pf = 1e-10f;
  P[gid] = pf;
}

__global__ __launch_bounds__(256) void k_sample_start(const float* __restrict__ probs,
                                                      float* __restrict__ outSN,
                                                      int* __restrict__ sn, int* __restrict__ flags) {
  int i = blockIdx.x * 256 + threadIdx.x;
  if (i >= NT) return;
  uint32_t a0, a1, b0, b1; derive_keys(a0, a1, b0, b1);
  double best = -1e300; int bi = 0;
  #pragma unroll
  for (int t = 0; t < NTYPES; ++t) {
    uint32_t bits = rng_bits(a0, a1, (uint32_t)(i * NTYPES + t), (uint32_t)(NT * NTYPES));
    double v = log((double)probs[(size_t)i * NTYPES + t]) + gumbel_from_bits(bits);
    if (v > best) { best = v; bi = t; }
  }
  sn[i] = bi;
  outSN[i] = (float)bi;
  flags[bi] = 1;   // benign race: all writers store 1
}

__global__ __launch_bounds__(256) void k_sample_end(const float* __restrict__ probs,
                                                    float* __restrict__ outEN) {
  int j = blockIdx.x * 256 + threadIdx.x;
  if (j >= 2 * NT) return;
  uint32_t a0, a1, b0, b1; derive_keys(a0, a1, b0, b1);
  double best = -1e300; int bi = 0;
  #pragma unroll
  for (int t = 0; t < NTYPES; ++t) {
    uint32_t bits = rng_bits(b0, b1, (uint32_t)(j * NTYPES + t), (uint32_t)(2 * NT * NTYPES));
    double v = log((double)probs[(size_t)j * NTYPES + t]) + gumbel_from_bits(bits);
    if (v > best) { best = v; bi = t; }
  }
  outEN[j] = (float)bi;
}

// ---------------- host ----------------
extern "C" void kernel_launch(void* const* d_in, const int* in_sizes, int n_in,
                              void* d_out, int out_size, void* d_ws, size_t ws_size,
                              hipStream_t stream) {
  const float* x    = (const float*)d_in[0];
  const float* cand = (const float*)d_in[1];
  const int*   ei   = (const int*)d_in[2];
  const float* W1 = (const float*)d_in[4];  const float* b1 = (const float*)d_in[5];
  const float* W2 = (const float*)d_in[6];  const float* b2 = (const float*)d_in[7];
  const float* W3 = (const float*)d_in[8];  const float* b3 = (const float*)d_in[9];
  const float* Ws1 = (const float*)d_in[10]; const float* bs1 = (const float*)d_in[11];
  const float* Ws2 = (const float*)d_in[12]; const float* bs2 = (const float*)d_in[13];
  const float* We1 = (const float*)d_in[14]; const float* be1 = (const float*)d_in[15];
  const float* We2 = (const float*)d_in[16]; const float* be2 = (const float*)d_in[17];
  float* out = (float*)d_out;
  float* outSN = out;
  float* outEN = out + NT;
  float* outPS = out + 3 * NT;
  float* outPE = out + 13 * NT;

  char* ws = (char*)d_ws;
  size_t off = 0;
  auto alloc = [&](size_t bytes) -> void* {
    void* p = ws + off;
    off += (bytes + 511) & ~(size_t)511;
    return p;
  };
  float*    dinv    = (float*)alloc((size_t)NT * 4);
  int*      rowptr  = (int*)alloc((size_t)(NT + 1) * 4);
  int*      cnt     = (int*)alloc((size_t)NBK2 * 4);
  int*      rowbase = (int*)alloc((size_t)NBK2 * 4);
  int*      cmat    = (int*)alloc((size_t)(NMAT + 1) * 4);
  int*      partial = (int*)alloc(512 * 4);
  int*      col     = (int*)alloc((size_t)NE * 4);
  // tmpent (~31.6 MB) aliases zsA + zsB + Ha (all dead until after k_place)
  char*     ublk    = (char*)alloc((size_t)TMPENT_CAP * 4);
  uint32_t* tmpent  = (uint32_t*)ublk;
  float*    zsA     = (float*)ublk;                                    // 6.4 MB
  float*    zsB     = (float*)(ublk + (size_t)NT * 16 * 4);            // 6.4 MB
  float*    Ha      = (float*)(ublk + (size_t)NT * 16 * 4 * 2);        // 12.8 MB
  float*    logitsS = (float*)alloc((size_t)NT * NTYPES * 4);
  float*    logitsE = (float*)alloc((size_t)2 * NT * NTYPES * 4);
  float*    w1v     = (float*)alloc((size_t)NT * 4);
  float*    ws1v    = (float*)alloc((size_t)NT * 4);
  float*    w2v     = (float*)alloc((size_t)NT * 4);
  float*    wsd     = (float*)alloc((size_t)NT * 4);   // dummy scaled-out of prop2
  double*   Md      = (double*)alloc(512 * 8);
  double*   ud      = (double*)alloc(32 * 8);
  double*   vd      = (double*)alloc(32 * 8);
  int*      sn      = (int*)alloc((size_t)NT * 4);
  uint32_t* maxS    = (uint32_t*)alloc(64);
  double*   sumS    = (double*)alloc(128);
  uint32_t* maxE    = (uint32_t*)alloc(64);
  double*   sumE    = (double*)alloc(128);
  int*      flags   = (int*)alloc(64);
  (void)ws_size; (void)in_sizes; (void)n_in; (void)out_size;

  const int* srcA = ei;
  const int* dstA = ei + NE;

  const int B = 256;
  auto blocks = [](long long nthreads) { return (int)((nthreads + 255) / 256); };

  // CSR build: count -> scan -> barrier-free scatter -> place (also produces dinv)
  hipMemsetAsync(cnt, 0, (size_t)NBK2 * 4, stream);
  k_bcount<<<SB, 512, 0, stream>>>(dstA, cmat, cnt);
  k_s1<<<NSCAN_B, 256, 0, stream>>>(cmat, partial);
  k_s2<<<1, 512, 0, stream>>>(partial, cmat);
  k_s3<<<NSCAN_B, 256, 0, stream>>>(cmat, partial);
  k_rowscan<<<1, 256, 0, stream>>>(cnt, rowbase);
  k_scatter2<<<SB, 512, 0, stream>>>(srcA, dstA, cmat, tmpent);
  k_place<<<NBK2, 512, 0, stream>>>(tmpent, cmat, rowbase, rowptr, dinv, col);

  // linear GCN stack folded to three F=16 propagations + scalar w-props + dense epilogue
  k_small<<<1, 512, 0, stream>>>(W2, b2, W3, b1, Md, ud, vd);
  k_mm1<<<blocks((long long)NT * 4), B, 0, stream>>>(x, cand, W1, dinv, zsA);
  const int PR = 64, PBLK = (NT + PR - 1) / PR;
  k_prop<true,  true,  PR><<<PBLK, dim3(4, PR), 0, stream>>>(rowptr, col, zsA, dinv, dinv, zsB, w1v, ws1v);
  k_prop<true,  true,  PR><<<PBLK, dim3(4, PR), 0, stream>>>(rowptr, col, zsB, ws1v, dinv, zsA, w2v, wsd);
  k_prop<false, false, PR><<<PBLK, dim3(4, PR), 0, stream>>>(rowptr, col, zsA, nullptr, dinv, zsB, nullptr, nullptr);
  k_epi<<<blocks((long long)NT * 32), B, 0, stream>>>(zsB, w1v, w2v, Md, ud, vd, b3, Ha);
  // H3 = Ha

  // start head
  k_head<16><<<blocks(NT), B, 0, stream>>>(Ha, sn, NT, Ws1, bs1, Ws2, bs2, logitsS);
  hipMemsetAsync(maxS, 0, (size_t)((char*)flags - (char*)maxS) + 512, stream);
  k_colmax<<<512, B, 0, stream>>>(logitsS, NT, maxS);
  k_colsum<<<512, B, 0, stream>>>(logitsS, NT, maxS, sumS);
  k_probs_start<<<blocks((long long)NT * NTYPES), B, 0, stream>>>(logitsS, maxS, sumS, outPS);
  k_sample_start<<<blocks(NT), B, 0, stream>>>(outPS, outSN, sn, flags);

  // end head (rows: [H3; H3[sn]])
  k_head<24><<<blocks(2 * NT), B, 0, stream>>>(Ha, sn, 2 * NT, We1, be1, We2, be2, logitsE);
  k_colmax<<<512, B, 0, stream>>>(logitsE, 2 * NT, maxE);
  k_colsum<<<512, B, 0, stream>>>(logitsE, 2 * NT, maxE, sumE);
  k_probs_end<<<blocks((long long)2 * NT * NTYPES), B, 0, stream>>>(logitsE, maxE, sumE, flags, outPE);
  k_sample_end<<<blocks(2 * NT), B, 0, stream>>>(outPE, outEN);
}